// Round 1
// baseline (2651.669 us; speedup 1.0000x reference)
//
#include <hip/hip_runtime.h>
#include <math.h>

#define DD 512
#define AA 64
#define NB 32
#define SENC 1024
#define SDEC 256
#define VOUT 32000
#define EPSL 1e-6f
#define SCALE 0.044194173824159216f   /* 1/sqrt(512) */
#define SQRTD 22.627416997969522f     /* sqrt(512) */

__device__ __forceinline__ float wsum(float v){
  #pragma unroll
  for (int o = 32; o; o >>= 1) v += __shfl_xor(v, o, 64);
  return v;
}

/* ---------------- Qa = enc_key_W @ enc_Wq^T + enc_bq  [64,512] ---------------- */
__global__ void __launch_bounds__(512) qa_kernel(const float* __restrict__ keyW,
    const float* __restrict__ Wq, const float* __restrict__ bq, float* __restrict__ Qa){
  int a = blockIdx.x, i = threadIdx.x;
  __shared__ float key[DD];
  key[i] = keyW[a*DD + i];
  __syncthreads();
  const float4* w4 = (const float4*)(Wq + (size_t)i*DD);
  const float4* k4 = (const float4*)key;
  float s = 0.f;
  #pragma unroll 4
  for (int j = 0; j < DD/4; j++){
    float4 w = w4[j], k = k4[j];
    s = fmaf(w.x,k.x, fmaf(w.y,k.y, fmaf(w.z,k.z, fmaf(w.w,k.w, s))));
  }
  Qa[a*DD + i] = s + bq[i];
}

/* ------------- Menc = Qa @ enc_Wk  [64,512],  cenc = Qa @ enc_bk [64] ---------- */
__global__ void __launch_bounds__(512) menc_kernel(const float* __restrict__ Qa,
    const float* __restrict__ Wk, const float* __restrict__ bk,
    float* __restrict__ Menc, float* __restrict__ cenc){
  int a = blockIdx.x, j = threadIdx.x;
  __shared__ float qa[DD];
  qa[j] = Qa[a*DD + j];
  __syncthreads();
  float s = 0.f;
  #pragma unroll 4
  for (int i = 0; i < DD; i++) s = fmaf(qa[i], Wk[(size_t)i*DD + j], s);
  Menc[a*DD + j] = s;
  if (j == 0){
    float c = 0.f;
    for (int i = 0; i < DD; i++) c = fmaf(qa[i], bk[i], c);
    cenc[a] = c;
  }
}

/* --------- encoder z-scan: 1 wave per batch, z_t = LN(z_{t-1} + sqrtD*x_t) ------ */
__global__ void __launch_bounds__(64) zscan_kernel(const int* __restrict__ toks,
    const float* __restrict__ emb, const float* __restrict__ n1g,
    const float* __restrict__ n1b, float* __restrict__ Z){
  int b = blockIdx.x, lane = threadIdx.x;
  int bd = lane*8;
  float z[8], g1[8], b1[8];
  #pragma unroll
  for (int k = 0; k < 8; k++) z[k] = 0.f;
  *(float4*)&g1[0] = *(const float4*)(n1g+bd); *(float4*)&g1[4] = *(const float4*)(n1g+bd+4);
  *(float4*)&b1[0] = *(const float4*)(n1b+bd); *(float4*)&b1[4] = *(const float4*)(n1b+bd+4);
  const int* tb = toks + b*SENC;
  float* Zb = Z + (size_t)b*SENC*DD + bd;
  int tok = tb[0];
  float4 xa = *(const float4*)(emb + (size_t)tok*DD + bd);
  float4 xb = *(const float4*)(emb + (size_t)tok*DD + bd + 4);
  for (int t = 0; t < SENC; t++){
    float x[8] = {xa.x,xa.y,xa.z,xa.w,xb.x,xb.y,xb.z,xb.w};
    int tn = tb[(t+1 < SENC) ? t+1 : t];              /* prefetch next token row */
    xa = *(const float4*)(emb + (size_t)tn*DD + bd);
    xb = *(const float4*)(emb + (size_t)tn*DD + bd + 4);
    float y[8], s = 0.f, q = 0.f;
    #pragma unroll
    for (int k = 0; k < 8; k++){ y[k] = fmaf(SQRTD, x[k], z[k]); s += y[k]; q = fmaf(y[k], y[k], q); }
    #pragma unroll
    for (int o = 32; o; o >>= 1){ s += __shfl_xor(s,o,64); q += __shfl_xor(q,o,64); }
    float mean = s * (1.f/DD);
    float var  = fmaxf((q - (float)DD*mean*mean) * (1.f/(DD-1)), 0.f);   /* ddof=1 */
    float r = 1.f/(sqrtf(var) + EPSL);
    #pragma unroll
    for (int k = 0; k < 8; k++) z[k] = fmaf(g1[k]*r, y[k]-mean, b1[k]);
    float4 o1 = {z[0],z[1],z[2],z[3]}, o2 = {z[4],z[5],z[6],z[7]};
    *(float4*)(Zb + (size_t)t*DD)     = o1;
    *(float4*)(Zb + (size_t)t*DD + 4) = o2;
  }
}

/* ---- encoder av-scan: 1 wave per (b,a) row; 4 same-batch rows share a block ---- */
__global__ void __launch_bounds__(256) avscan_kernel(const float* __restrict__ Z,
    const float* __restrict__ Menc, const float* __restrict__ cenc,
    const float* __restrict__ n1g, const float* __restrict__ n1b, float* __restrict__ avout){
  int b = blockIdx.x >> 4;
  int a = ((blockIdx.x & 15) << 2) + (threadIdx.x >> 6);
  int lane = threadIdx.x & 63;
  int bd = lane*8;
  float m[8], g1[8], b1[8], av[8];
  *(float4*)&m[0]  = *(const float4*)(Menc + (size_t)a*DD + bd);
  *(float4*)&m[4]  = *(const float4*)(Menc + (size_t)a*DD + bd + 4);
  *(float4*)&g1[0] = *(const float4*)(n1g+bd); *(float4*)&g1[4] = *(const float4*)(n1g+bd+4);
  *(float4*)&b1[0] = *(const float4*)(n1b+bd); *(float4*)&b1[4] = *(const float4*)(n1b+bd+4);
  float ce = cenc[a];
  #pragma unroll
  for (int k = 0; k < 8; k++) av[k] = 0.f;
  const float* Zb = Z + (size_t)b*SENC*DD + bd;
  float4 za = *(const float4*)Zb, zb = *(const float4*)(Zb + 4);
  for (int t = 0; t < SENC; t++){
    float z[8] = {za.x,za.y,za.z,za.w,zb.x,zb.y,zb.z,zb.w};
    int tn = (t+1 < SENC) ? t+1 : t;                  /* prefetch next z row */
    za = *(const float4*)(Zb + (size_t)tn*DD);
    zb = *(const float4*)(Zb + (size_t)tn*DD + 4);
    float dot = 0.f;
    #pragma unroll
    for (int k = 0; k < 8; k++) dot = fmaf(m[k], z[k], dot);
    dot = wsum(dot);
    float g = 1.f/(1.f + expf(-(dot + ce)*SCALE));    /* sigmoid gate */
    float y[8], s = 0.f, q = 0.f;
    #pragma unroll
    for (int k = 0; k < 8; k++){ y[k] = fmaf(g, z[k]-av[k], av[k]); s += y[k]; q = fmaf(y[k], y[k], q); }
    #pragma unroll
    for (int o = 32; o; o >>= 1){ s += __shfl_xor(s,o,64); q += __shfl_xor(q,o,64); }
    float mean = s * (1.f/DD);
    float var  = fmaxf((q - (float)DD*mean*mean) * (1.f/(DD-1)), 0.f);
    float r = 1.f/(sqrtf(var) + EPSL);
    #pragma unroll
    for (int k = 0; k < 8; k++) av[k] = fmaf(g1[k]*r, y[k]-mean, b1[k]);
  }
  float* o = avout + ((size_t)(b*AA + a))*DD + bd;
  float4 o1 = {av[0],av[1],av[2],av[3]}, o2 = {av[4],av[5],av[6],av[7]};
  *(float4*)o = o1; *(float4*)(o+4) = o2;
}

/* ------------- f32 GEMM, C[m,n] = sum_k A[m,k]*Bw[n,k] (+bias[n]), N=K=512 ------ */
/* tstore=1 scatters to Vrt[b][n][a] layout (m = b*64+a)                           */
__global__ void __launch_bounds__(256) gemm_nt_kernel(const float* __restrict__ Aa,
    const float* __restrict__ Bw, const float* __restrict__ bias,
    float* __restrict__ C, int tstore){
  __shared__ float As[32][64];
  __shared__ float Bs[32][64];
  int tid = threadIdx.x;
  int m0 = blockIdx.x*64, n0 = blockIdx.y*64;
  int ty = tid >> 4, tx = tid & 15;
  float acc[4][4] = {{0.f}};
  for (int k0 = 0; k0 < 512; k0 += 32){
    #pragma unroll
    for (int p = 0; p < 2; p++){
      int row = (tid>>3) + p*32, col = (tid&7)*4;
      float4 va = *(const float4*)(Aa + (size_t)(m0+row)*512 + k0 + col);
      As[col][row]=va.x; As[col+1][row]=va.y; As[col+2][row]=va.z; As[col+3][row]=va.w;
      float4 vb = *(const float4*)(Bw + (size_t)(n0+row)*512 + k0 + col);
      Bs[col][row]=vb.x; Bs[col+1][row]=vb.y; Bs[col+2][row]=vb.z; Bs[col+3][row]=vb.w;
    }
    __syncthreads();
    #pragma unroll
    for (int kk = 0; kk < 32; kk++){
      float4 a4 = *(const float4*)&As[kk][ty*4];
      float4 b4 = *(const float4*)&Bs[kk][tx*4];
      float au[4] = {a4.x,a4.y,a4.z,a4.w}, bv[4] = {b4.x,b4.y,b4.z,b4.w};
      #pragma unroll
      for (int u = 0; u < 4; u++)
        #pragma unroll
        for (int v = 0; v < 4; v++) acc[u][v] = fmaf(au[u], bv[v], acc[u][v]);
    }
    __syncthreads();
  }
  float bv4[4] = {0.f,0.f,0.f,0.f};
  if (bias){ 
    #pragma unroll
    for (int v = 0; v < 4; v++) bv4[v] = bias[n0 + tx*4 + v];
  }
  if (!tstore){
    #pragma unroll
    for (int u = 0; u < 4; u++){
      float4 st = {acc[u][0]+bv4[0], acc[u][1]+bv4[1], acc[u][2]+bv4[2], acc[u][3]+bv4[3]};
      *(float4*)(C + (size_t)(m0+ty*4+u)*512 + n0 + tx*4) = st;
    }
  } else {
    #pragma unroll
    for (int u = 0; u < 4; u++){
      int mm = m0 + ty*4 + u; int bb = mm >> 6, a2 = mm & 63;
      #pragma unroll
      for (int v = 0; v < 4; v++)
        C[((size_t)bb*512 + n0 + tx*4 + v)*64 + a2] = acc[u][v] + bv4[v];
    }
  }
}

/* ---------------------- C[m,n] = sum_k A[m,k]*B[k,n], N=K=512 ------------------- */
__global__ void __launch_bounds__(256) gemm_nn_kernel(const float* __restrict__ Aa,
    const float* __restrict__ Bw, float* __restrict__ C){
  __shared__ float As[32][64];
  __shared__ float Bs[32][64];
  int tid = threadIdx.x;
  int m0 = blockIdx.x*64, n0 = blockIdx.y*64;
  int ty = tid >> 4, tx = tid & 15;
  float acc[4][4] = {{0.f}};
  for (int k0 = 0; k0 < 512; k0 += 32){
    #pragma unroll
    for (int p = 0; p < 2; p++){
      int row = (tid>>3) + p*32, col = (tid&7)*4;
      float4 va = *(const float4*)(Aa + (size_t)(m0+row)*512 + k0 + col);
      As[col][row]=va.x; As[col+1][row]=va.y; As[col+2][row]=va.z; As[col+3][row]=va.w;
      int brow = (tid>>4) + p*16, bcol = (tid&15)*4;
      float4 vb = *(const float4*)(Bw + (size_t)(k0+brow)*512 + n0 + bcol);
      *(float4*)&Bs[brow][bcol] = vb;
    }
    __syncthreads();
    #pragma unroll
    for (int kk = 0; kk < 32; kk++){
      float4 a4 = *(const float4*)&As[kk][ty*4];
      float4 b4 = *(const float4*)&Bs[kk][tx*4];
      float au[4] = {a4.x,a4.y,a4.z,a4.w}, bv[4] = {b4.x,b4.y,b4.z,b4.w};
      #pragma unroll
      for (int u = 0; u < 4; u++)
        #pragma unroll
        for (int v = 0; v < 4; v++) acc[u][v] = fmaf(au[u], bv[v], acc[u][v]);
    }
    __syncthreads();
  }
  #pragma unroll
  for (int u = 0; u < 4; u++){
    float4 st = {acc[u][0], acc[u][1], acc[u][2], acc[u][3]};
    *(float4*)(C + (size_t)(m0+ty*4+u)*512 + n0 + tx*4) = st;
  }
}

/* --------------------------- cdec[m] = Kr[m,:] . rdr_bq ------------------------- */
__global__ void __launch_bounds__(256) cdec_kernel(const float* __restrict__ Kr,
    const float* __restrict__ bq, float* __restrict__ cdec){
  int m = blockIdx.x*4 + (threadIdx.x >> 6);
  int lane = threadIdx.x & 63;
  const float* kr = Kr + (size_t)m*DD + lane*8;
  const float* bb = bq + lane*8;
  float s = 0.f;
  #pragma unroll
  for (int k = 0; k < 8; k++) s = fmaf(kr[k], bb[k], s);
  s = wsum(s);
  if (lane == 0) cdec[m] = s;
}

/* ------------------------------- decoder scan ----------------------------------- */
__global__ void __launch_bounds__(256) dec_kernel(const float* __restrict__ Z,
    const float* __restrict__ P, const float* __restrict__ Vrt,
    const float* __restrict__ cdec, const float* __restrict__ n2g,
    const float* __restrict__ n2b, float* __restrict__ zfinT){
  int b = blockIdx.x, tid = threadIdx.x;
  __shared__ float zL[DD];
  __shared__ float att[AA];
  __shared__ float part[4][AA];
  __shared__ float red[8];
  zL[tid]       = Z[((size_t)b*SENC + SENC-1)*DD + tid];
  zL[tid + 256] = Z[((size_t)b*SENC + SENC-1)*DD + tid + 256];
  int aid = tid & 63, pid = tid >> 6;
  const float4* Prow = (const float4*)(P + ((size_t)(b*AA + aid))*DD + pid*128);
  float cd = (tid < AA) ? cdec[b*AA + tid] : 0.f;
  int d0 = tid*2;
  float g2a = n2g[d0], g2b = n2g[d0+1], b2a = n2b[d0], b2b = n2b[d0+1];
  const float4* Vr0 = (const float4*)(Vrt + ((size_t)b*DD + d0)*AA);
  const float4* Vr1 = (const float4*)(Vrt + ((size_t)b*DD + d0 + 1)*AA);
  __syncthreads();
  for (int t = 0; t < SDEC; t++){
    /* phase 1: partial attention logits (P[b] @ z), split over 4 d-chunks */
    float s = 0.f;
    #pragma unroll
    for (int j = 0; j < 32; j++){
      float4 p = Prow[j];
      int dd = pid*128 + j*4;
      s = fmaf(p.x, zL[dd], s);   s = fmaf(p.y, zL[dd+1], s);
      s = fmaf(p.z, zL[dd+2], s); s = fmaf(p.w, zL[dd+3], s);
    }
    part[pid][aid] = s;
    __syncthreads();
    /* phase 2: softmax over 64 anchors (wave 0) */
    if (tid < AA){
      float l = (part[0][tid] + part[1][tid] + part[2][tid] + part[3][tid] + cd) * SCALE;
      float mx = l;
      #pragma unroll
      for (int o = 32; o; o >>= 1) mx = fmaxf(mx, __shfl_xor(mx,o,64));
      float e = expf(l - mx);
      float se = e;
      #pragma unroll
      for (int o = 32; o; o >>= 1) se += __shfl_xor(se,o,64);
      att[tid] = e / se;
    }
    __syncthreads();
    /* phase 3: dg2 = att @ Vr (two d's per thread) + LN stats */
    float a0 = 0.f, a1 = 0.f;
    #pragma unroll
    for (int j = 0; j < 16; j++){
      float4 w  = ((const float4*)att)[j];
      float4 v0 = Vr0[j], v1 = Vr1[j];
      a0 = fmaf(v0.x,w.x, fmaf(v0.y,w.y, fmaf(v0.z,w.z, fmaf(v0.w,w.w, a0))));
      a1 = fmaf(v1.x,w.x, fmaf(v1.y,w.y, fmaf(v1.z,w.z, fmaf(v1.w,w.w, a1))));
    }
    float y0 = zL[d0] + a0, y1 = zL[d0+1] + a1;
    float s2 = y0 + y1, q2 = fmaf(y0,y0, y1*y1);
    #pragma unroll
    for (int o = 32; o; o >>= 1){ s2 += __shfl_xor(s2,o,64); q2 += __shfl_xor(q2,o,64); }
    if ((tid & 63) == 0){ red[tid>>6] = s2; red[4 + (tid>>6)] = q2; }
    __syncthreads();
    /* phase 4: every thread finalizes stats (no extra barrier) and writes z */
    float ssum = red[0]+red[1]+red[2]+red[3];
    float qsum = red[4]+red[5]+red[6]+red[7];
    float mean = ssum * (1.f/DD);
    float var  = fmaxf((qsum - (float)DD*mean*mean) * (1.f/(DD-1)), 0.f);
    float rr = 1.f/(sqrtf(var) + EPSL);
    zL[d0]   = fmaf(g2a*rr, y0-mean, b2a);
    zL[d0+1] = fmaf(g2b*rr, y1-mean, b2b);
    __syncthreads();
  }
  zfinT[(size_t)d0*NB + b]     = zL[d0];
  zfinT[(size_t)(d0+1)*NB + b] = zL[d0+1];
}

/* ---------------- logits = zfin @ voc_W^T + voc_b  (write into d_out) ----------- */
__global__ void __launch_bounds__(256) logits_kernel(const float* __restrict__ zfinT,
    const float* __restrict__ vocW, const float* __restrict__ vocb, float* __restrict__ out){
  __shared__ float zT[DD*NB];
  int tid = threadIdx.x;
  const float4* src = (const float4*)zfinT;
  float4* dst = (float4*)zT;
  #pragma unroll
  for (int i = 0; i < 16; i++) dst[tid + i*256] = src[tid + i*256];
  __syncthreads();
  int rj = tid & 7, bb = tid >> 3;
  int r = blockIdx.x*8 + rj;
  const float* wr = vocW + (size_t)r*DD;
  float acc = vocb[r];
  #pragma unroll 8
  for (int d = 0; d < DD; d++) acc = fmaf(wr[d], zT[d*NB + bb], acc);
  out[(size_t)bb*VOUT + r] = acc;
}

/* --------------------------- in-place log_softmax ------------------------------- */
__global__ void __launch_bounds__(256) lsm_kernel(float* __restrict__ out){
  int b = blockIdx.x, tid = threadIdx.x;
  float* row = out + (size_t)b*VOUT;
  __shared__ float red[4];
  __shared__ float bcast;
  float mx = -3.4e38f;
  for (int i = tid; i < VOUT; i += 256) mx = fmaxf(mx, row[i]);
  #pragma unroll
  for (int o = 32; o; o >>= 1) mx = fmaxf(mx, __shfl_xor(mx,o,64));
  if ((tid & 63) == 0) red[tid>>6] = mx;
  __syncthreads();
  if (tid == 0) bcast = fmaxf(fmaxf(red[0],red[1]), fmaxf(red[2],red[3]));
  __syncthreads();
  mx = bcast;
  float sm = 0.f;
  for (int i = tid; i < VOUT; i += 256) sm += expf(row[i] - mx);
  #pragma unroll
  for (int o = 32; o; o >>= 1) sm += __shfl_xor(sm,o,64);
  if ((tid & 63) == 0) red[tid>>6] = sm;
  __syncthreads();
  if (tid == 0) bcast = logf(red[0]+red[1]+red[2]+red[3]) + mx;
  __syncthreads();
  float c = bcast;
  for (int i = tid; i < VOUT; i += 256) row[i] -= c;
}

extern "C" void kernel_launch(void* const* d_in, const int* in_sizes, int n_in,
                              void* d_out, int out_size, void* d_ws, size_t ws_size,
                              hipStream_t stream){
  (void)in_sizes; (void)n_in; (void)out_size; (void)ws_size;
  const int*   toks      = (const int*)  d_in[0];
  const float* emb_in    = (const float*)d_in[2];
  const float* enc_key_W = (const float*)d_in[4];
  const float* enc_Wq    = (const float*)d_in[5];
  const float* enc_bq    = (const float*)d_in[6];
  const float* enc_Wk    = (const float*)d_in[7];
  const float* enc_bk    = (const float*)d_in[8];
  const float* n1g       = (const float*)d_in[9];
  const float* n1b       = (const float*)d_in[10];
  const float* rdr_Wq    = (const float*)d_in[12];
  const float* rdr_bq    = (const float*)d_in[13];
  const float* rdr_Wk    = (const float*)d_in[14];
  const float* rdr_bk    = (const float*)d_in[15];
  const float* rdr_Wv    = (const float*)d_in[16];
  const float* rdr_bv    = (const float*)d_in[17];
  const float* n2g       = (const float*)d_in[22];
  const float* n2b       = (const float*)d_in[23];
  const float* vocW      = (const float*)d_in[26];
  const float* vocb      = (const float*)d_in[27];
  float* outp = (float*)d_out;

  float* ws = (float*)d_ws;
  size_t off = 0;
  float* Z    = ws + off; off += (size_t)NB*SENC*DD;   /* 64 MB  */
  float* av   = ws + off; off += (size_t)NB*AA*DD;     /* 4 MB   */
  float* Kr   = ws + off; off += (size_t)NB*AA*DD;
  float* P    = ws + off; off += (size_t)NB*AA*DD;
  float* Vrt  = ws + off; off += (size_t)NB*AA*DD;
  float* Qa   = ws + off; off += (size_t)AA*DD;
  float* Menc = ws + off; off += (size_t)AA*DD;
  float* cenc = ws + off; off += AA;
  float* cdec = ws + off; off += (size_t)NB*AA;
  float* zfinT= ws + off; off += (size_t)DD*NB;

  qa_kernel  <<<AA, 512, 0, stream>>>(enc_key_W, enc_Wq, enc_bq, Qa);
  menc_kernel<<<AA, 512, 0, stream>>>(Qa, enc_Wk, enc_bk, Menc, cenc);
  zscan_kernel<<<NB, 64, 0, stream>>>(toks, emb_in, n1g, n1b, Z);
  avscan_kernel<<<NB*16, 256, 0, stream>>>(Z, Menc, cenc, n1g, n1b, av);
  gemm_nt_kernel<<<dim3(NB*AA/64, DD/64), 256, 0, stream>>>(av, rdr_Wk, rdr_bk, Kr, 0);
  gemm_nn_kernel<<<dim3(NB*AA/64, DD/64), 256, 0, stream>>>(Kr, rdr_Wq, P);
  gemm_nt_kernel<<<dim3(NB*AA/64, DD/64), 256, 0, stream>>>(av, rdr_Wv, rdr_bv, Vrt, 1);
  cdec_kernel<<<NB*AA/4, 256, 0, stream>>>(Kr, rdr_bq, cdec);
  dec_kernel<<<NB, 256, 0, stream>>>(Z, P, Vrt, cdec, n2g, n2b, zfinT);
  logits_kernel<<<VOUT/8, 256, 0, stream>>>(zfinT, vocW, vocb, outp);
  lsm_kernel<<<NB, 256, 0, stream>>>(outp);
}

// Round 3
// 1906.706 us; speedup vs baseline: 1.3907x; 1.3907x over previous
//
#include <hip/hip_runtime.h>
#include <math.h>

#define DD 512
#define AA 64
#define NB 32
#define SENC 1024
#define SDEC 256
#define VOUT 32000
#define EPSL 1e-6f
#define SCALE 0.044194173824159216f   /* 1/sqrt(512) */
#define SQRTD 22.627416997969522f     /* sqrt(512) */

typedef _Float16 h2 __attribute__((ext_vector_type(2)));

/* ---------------- DPP wave reduction helpers (VALU-only, no ds_swizzle) -------- */
/* ctrl/row_mask must be compile-time constants -> template parameters            */
template<int C, int R>
__device__ __forceinline__ float dppz(float v){   /* old=0, bound_ctrl=1 */
  return __int_as_float(__builtin_amdgcn_update_dpp(0, __float_as_int(v), C, R, 0xf, true));
}
template<int C, int R>
__device__ __forceinline__ float dppself(float v){ /* old=self, bound_ctrl=0 */
  return __int_as_float(__builtin_amdgcn_update_dpp(__float_as_int(v), __float_as_int(v), C, R, 0xf, false));
}
__device__ __forceinline__ float rlane63(float v){
  return __int_as_float(__builtin_amdgcn_readlane(__float_as_int(v), 63));
}
/* two interleaved full-wave sums; results broadcast to all lanes */
__device__ __forceinline__ void wred2(float &a, float &b){
  a += dppz<0x111,0xf>(a); b += dppz<0x111,0xf>(b);
  a += dppz<0x112,0xf>(a); b += dppz<0x112,0xf>(b);
  a += dppz<0x114,0xf>(a); b += dppz<0x114,0xf>(b);
  a += dppz<0x118,0xf>(a); b += dppz<0x118,0xf>(b);
  a += dppz<0x142,0xa>(a); b += dppz<0x142,0xa>(b);
  a += dppz<0x143,0xc>(a); b += dppz<0x143,0xc>(b);
  a = rlane63(a); b = rlane63(b);
}
__device__ __forceinline__ float wredsum(float a){
  a += dppz<0x111,0xf>(a); a += dppz<0x112,0xf>(a);
  a += dppz<0x114,0xf>(a); a += dppz<0x118,0xf>(a);
  a += dppz<0x142,0xa>(a); a += dppz<0x143,0xc>(a);
  return rlane63(a);
}
__device__ __forceinline__ float wredmax(float a){
  a = fmaxf(a, dppself<0x111,0xf>(a));
  a = fmaxf(a, dppself<0x112,0xf>(a));
  a = fmaxf(a, dppself<0x114,0xf>(a));
  a = fmaxf(a, dppself<0x118,0xf>(a));
  a = fmaxf(a, dppself<0x142,0xa>(a));
  a = fmaxf(a, dppself<0x143,0xc>(a));
  return rlane63(a);
}
__device__ __forceinline__ unsigned int pk16(float x, float y){
  return __builtin_bit_cast(unsigned int, __builtin_amdgcn_cvt_pkrtz(x, y));
}
__device__ __forceinline__ float fd2(unsigned int a, unsigned int b, float c){
#if __has_builtin(__builtin_amdgcn_fdot2)
  return __builtin_amdgcn_fdot2(__builtin_bit_cast(h2, a), __builtin_bit_cast(h2, b), c, false);
#else
  h2 x = __builtin_bit_cast(h2, a), y = __builtin_bit_cast(h2, b);
  return c + (float)x[0]*(float)y[0] + (float)x[1]*(float)y[1];
#endif
}

/* ---------------- Qa = enc_key_W @ enc_Wq^T + enc_bq  [64,512] ---------------- */
__global__ void __launch_bounds__(512) qa_kernel(const float* __restrict__ keyW,
    const float* __restrict__ Wq, const float* __restrict__ bq, float* __restrict__ Qa){
  int a = blockIdx.x, i = threadIdx.x;
  __shared__ float key[DD];
  key[i] = keyW[a*DD + i];
  __syncthreads();
  const float4* w4 = (const float4*)(Wq + (size_t)i*DD);
  const float4* k4 = (const float4*)key;
  float s = 0.f;
  #pragma unroll 4
  for (int j = 0; j < DD/4; j++){
    float4 w = w4[j], k = k4[j];
    s = fmaf(w.x,k.x, fmaf(w.y,k.y, fmaf(w.z,k.z, fmaf(w.w,k.w, s))));
  }
  Qa[a*DD + i] = s + bq[i];
}

/* ------------- Menc = Qa @ enc_Wk  [64,512] ----------------------------------- */
__global__ void __launch_bounds__(512) menc_kernel(const float* __restrict__ Qa,
    const float* __restrict__ Wk, float* __restrict__ Menc){
  int a = blockIdx.x, j = threadIdx.x;
  __shared__ float qa[DD];
  qa[j] = Qa[a*DD + j];
  __syncthreads();
  float s = 0.f;
  #pragma unroll 4
  for (int i = 0; i < DD; i++) s = fmaf(qa[i], Wk[(size_t)i*DD + j], s);
  Menc[a*DD + j] = s;
}

/* ------------- out[m] = X[m,:] . v  (4 rows per block) ------------------------- */
__global__ void __launch_bounds__(256) dotb_kernel(const float* __restrict__ X,
    const float* __restrict__ v, float* __restrict__ out){
  int m = blockIdx.x*4 + (threadIdx.x >> 6);
  int lane = threadIdx.x & 63;
  const float4* x4 = (const float4*)(X + (size_t)m*DD + lane*8);
  const float4* v4 = (const float4*)(v + lane*8);
  float4 a = x4[0], b4 = x4[1], c = v4[0], d = v4[1];
  float s = a.x*c.x;
  s = fmaf(a.y,c.y, s); s = fmaf(a.z,c.z, s); s = fmaf(a.w,c.w, s);
  s = fmaf(b4.x,d.x, s); s = fmaf(b4.y,d.y, s); s = fmaf(b4.z,d.z, s); s = fmaf(b4.w,d.w, s);
  s = wredsum(s);
  if (lane == 0) out[m] = s;
}

/* --------- encoder z-scan: 1 wave per batch, z_t = LN(z_{t-1} + sqrtD*x_t) ------ */
__global__ void __launch_bounds__(64) zscan_kernel(const int* __restrict__ toks,
    const float* __restrict__ emb, const float* __restrict__ n1g,
    const float* __restrict__ n1b, float* __restrict__ Z){
  int b = blockIdx.x, lane = threadIdx.x;
  int bd = lane*8;
  float z[8], g1[8], b1[8];
  #pragma unroll
  for (int k = 0; k < 8; k++) z[k] = 0.f;
  *(float4*)&g1[0] = *(const float4*)(n1g+bd); *(float4*)&g1[4] = *(const float4*)(n1g+bd+4);
  *(float4*)&b1[0] = *(const float4*)(n1b+bd); *(float4*)&b1[4] = *(const float4*)(n1b+bd+4);
  const int* tb = toks + b*SENC;
  float* Zb = Z + (size_t)b*SENC*DD + bd;
  int tok = tb[0];
  float4 xa = *(const float4*)(emb + (size_t)tok*DD + bd);
  float4 xb = *(const float4*)(emb + (size_t)tok*DD + bd + 4);
  for (int t = 0; t < SENC; t++){
    float x[8] = {xa.x,xa.y,xa.z,xa.w,xb.x,xb.y,xb.z,xb.w};
    int tn = tb[(t+1 < SENC) ? t+1 : t];              /* prefetch next token row */
    xa = *(const float4*)(emb + (size_t)tn*DD + bd);
    xb = *(const float4*)(emb + (size_t)tn*DD + bd + 4);
    float y[8], s = 0.f, q = 0.f;
    #pragma unroll
    for (int k = 0; k < 8; k++){ y[k] = fmaf(SQRTD, x[k], z[k]); s += y[k]; q = fmaf(y[k], y[k], q); }
    wred2(s, q);
    float mean = s * (1.f/DD);
    float var  = fmaxf((q - (float)DD*mean*mean) * (1.f/(DD-1)), 0.f);   /* ddof=1 */
    float r = 1.f/(sqrtf(var) + EPSL);
    #pragma unroll
    for (int k = 0; k < 8; k++) z[k] = fmaf(g1[k]*r, y[k]-mean, b1[k]);
    float4 o1 = {z[0],z[1],z[2],z[3]}, o2 = {z[4],z[5],z[6],z[7]};
    *(float4*)(Zb + (size_t)t*DD)     = o1;
    *(float4*)(Zb + (size_t)t*DD + 4) = o2;
  }
}

/* -------- per-row (b,t) stats of Z: ZSQ[row] = (sum z, sum z^2) ----------------- */
__global__ void __launch_bounds__(256) zstats_kernel(const float* __restrict__ Z,
    float* __restrict__ ZSQ){
  int row = blockIdx.x*4 + (threadIdx.x >> 6);
  int lane = threadIdx.x & 63;
  const float4* z4 = (const float4*)(Z + (size_t)row*DD + lane*8);
  float4 a = z4[0], b4 = z4[1];
  float s = a.x+a.y+a.z+a.w + b4.x+b4.y+b4.z+b4.w;
  float q = a.x*a.x;
  q = fmaf(a.y,a.y,q); q = fmaf(a.z,a.z,q); q = fmaf(a.w,a.w,q);
  q = fmaf(b4.x,b4.x,q); q = fmaf(b4.y,b4.y,q); q = fmaf(b4.z,b4.z,q); q = fmaf(b4.w,b4.w,q);
  wred2(s, q);
  if (lane == 0){ float2 o = {s, q}; *(float2*)(ZSQ + (size_t)row*2) = o; }
}

/* ---- encoder av-scan: 1 wave per (b,a); 8 same-batch waves per block; XCD swz --- */
__global__ void __launch_bounds__(512) avscan_kernel(const float* __restrict__ Z,
    const float* __restrict__ ZSQ, const float* __restrict__ Menc,
    const float* __restrict__ cenc, const float* __restrict__ n1g,
    const float* __restrict__ n1b, float* __restrict__ avout){
  int bx = blockIdx.x;
  int b = (bx & 7)*4 + ((bx >> 3) & 3);          /* all blocks of batch b on one XCD */
  int a = (bx >> 5)*8 + (threadIdx.x >> 6);
  int lane = threadIdx.x & 63;
  int bd = lane*8;
  float m[8], g1[8], b1[8], av[8];
  *(float4*)&m[0]  = *(const float4*)(Menc + (size_t)a*DD + bd);
  *(float4*)&m[4]  = *(const float4*)(Menc + (size_t)a*DD + bd + 4);
  *(float4*)&g1[0] = *(const float4*)(n1g+bd); *(float4*)&g1[4] = *(const float4*)(n1g+bd+4);
  *(float4*)&b1[0] = *(const float4*)(n1b+bd); *(float4*)&b1[4] = *(const float4*)(n1b+bd+4);
  float ce = cenc[a];
  #pragma unroll
  for (int k = 0; k < 8; k++) av[k] = 0.f;
  float Sav = 0.f, Qav = 0.f;
  const float* Zb = Z + (size_t)b*SENC*DD + bd;
  const float* SQb = ZSQ + (size_t)b*SENC*2;
  float4 za = *(const float4*)Zb, zb = *(const float4*)(Zb + 4);
  float2 sq = *(const float2*)SQb;
  for (int t = 0; t < SENC; t++){
    float z[8] = {za.x,za.y,za.z,za.w,zb.x,zb.y,zb.z,zb.w};
    float Szt = sq.x, Qzt = sq.y;
    int tn = (t+1 < SENC) ? t+1 : t;                  /* prefetch next */
    za = *(const float4*)(Zb + (size_t)tn*DD);
    zb = *(const float4*)(Zb + (size_t)tn*DD + 4);
    sq = *(const float2*)(SQb + (size_t)tn*2);
    float dot = 0.f, cav = 0.f;
    #pragma unroll
    for (int k = 0; k < 8; k++){ dot = fmaf(m[k], z[k], dot); cav = fmaf(av[k], z[k], cav); }
    wred2(dot, cav);
    float g = 1.f/(1.f + __expf(-(dot + ce)*SCALE));
    float omg = 1.f - g;
    float Sy = omg*Sav + g*Szt;
    float Qy = omg*omg*Qav + 2.f*g*omg*cav + g*g*Qzt;
    float mean = Sy * (1.f/DD);
    float var  = fmaxf((Qy - (float)DD*mean*mean) * (1.f/(DD-1)), 0.f);
    float r = 1.f/(sqrtf(var) + EPSL);
    float sn = 0.f, qn = 0.f;
    #pragma unroll
    for (int k = 0; k < 8; k++){
      float y = fmaf(g, z[k]-av[k], av[k]);
      float nv = fmaf(g1[k]*r, y-mean, b1[k]);
      av[k] = nv; sn += nv; qn = fmaf(nv, nv, qn);
    }
    wred2(sn, qn);                                    /* feeds NEXT step only */
    Sav = sn; Qav = qn;
  }
  float* o = avout + ((size_t)(b*AA + a))*DD + bd;
  float4 o1 = {av[0],av[1],av[2],av[3]}, o2 = {av[4],av[5],av[6],av[7]};
  *(float4*)o = o1; *(float4*)(o+4) = o2;
}

/* ------------- f32 GEMM, C[m,n] = sum_k A[m,k]*Bw[n,k] (+bias[n]) --------------- */
/* mode 0: f32 [m][n] store (Kr); mode 1: f16 scatter to V16[b][n][a] ------------- */
__global__ void __launch_bounds__(256) gemm_nt_kernel(const float* __restrict__ Aa,
    const float* __restrict__ Bw, const float* __restrict__ bias,
    void* __restrict__ Cout, int mode){
  __shared__ float As[32][64];
  __shared__ float Bs[32][64];
  int tid = threadIdx.x;
  int m0 = blockIdx.x*64, n0 = blockIdx.y*64;
  int ty = tid >> 4, tx = tid & 15;
  float acc[4][4] = {{0.f}};
  for (int k0 = 0; k0 < 512; k0 += 32){
    #pragma unroll
    for (int p = 0; p < 2; p++){
      int row = (tid>>3) + p*32, col = (tid&7)*4;
      float4 va = *(const float4*)(Aa + (size_t)(m0+row)*512 + k0 + col);
      As[col][row]=va.x; As[col+1][row]=va.y; As[col+2][row]=va.z; As[col+3][row]=va.w;
      float4 vb = *(const float4*)(Bw + (size_t)(n0+row)*512 + k0 + col);
      Bs[col][row]=vb.x; Bs[col+1][row]=vb.y; Bs[col+2][row]=vb.z; Bs[col+3][row]=vb.w;
    }
    __syncthreads();
    #pragma unroll
    for (int kk = 0; kk < 32; kk++){
      float4 a4 = *(const float4*)&As[kk][ty*4];
      float4 b4 = *(const float4*)&Bs[kk][tx*4];
      float au[4] = {a4.x,a4.y,a4.z,a4.w}, bv[4] = {b4.x,b4.y,b4.z,b4.w};
      #pragma unroll
      for (int u = 0; u < 4; u++)
        #pragma unroll
        for (int v = 0; v < 4; v++) acc[u][v] = fmaf(au[u], bv[v], acc[u][v]);
    }
    __syncthreads();
  }
  float bv4[4];
  #pragma unroll
  for (int v = 0; v < 4; v++) bv4[v] = bias ? bias[n0 + tx*4 + v] : 0.f;
  if (mode == 0){
    float* C = (float*)Cout;
    #pragma unroll
    for (int u = 0; u < 4; u++){
      float4 st = {acc[u][0]+bv4[0], acc[u][1]+bv4[1], acc[u][2]+bv4[2], acc[u][3]+bv4[3]};
      *(float4*)(C + (size_t)(m0+ty*4+u)*512 + n0 + tx*4) = st;
    }
  } else {
    unsigned short* C = (unsigned short*)Cout;
    #pragma unroll
    for (int u = 0; u < 4; u++){
      int mm = m0 + ty*4 + u; int bb = mm >> 6, a2 = mm & 63;
      #pragma unroll
      for (int v = 0; v < 4; v++){
        _Float16 hv = (_Float16)(acc[u][v] + bv4[v]);
        C[((size_t)bb*512 + n0 + tx*4 + v)*64 + a2] = __builtin_bit_cast(unsigned short, hv);
      }
    }
  }
}

/* ------------- P16[m][n] (f16) = sum_k A[m,k]*B[k,n] --------------------------- */
__global__ void __launch_bounds__(256) gemm_nn_kernel(const float* __restrict__ Aa,
    const float* __restrict__ Bw, unsigned int* __restrict__ Cout){
  __shared__ float As[32][64];
  __shared__ float Bs[32][64];
  int tid = threadIdx.x;
  int m0 = blockIdx.x*64, n0 = blockIdx.y*64;
  int ty = tid >> 4, tx = tid & 15;
  float acc[4][4] = {{0.f}};
  for (int k0 = 0; k0 < 512; k0 += 32){
    #pragma unroll
    for (int p = 0; p < 2; p++){
      int row = (tid>>3) + p*32, col = (tid&7)*4;
      float4 va = *(const float4*)(Aa + (size_t)(m0+row)*512 + k0 + col);
      As[col][row]=va.x; As[col+1][row]=va.y; As[col+2][row]=va.z; As[col+3][row]=va.w;
      int brow = (tid>>4) + p*16, bcol = (tid&15)*4;
      float4 vb = *(const float4*)(Bw + (size_t)(k0+brow)*512 + n0 + bcol);
      *(float4*)&Bs[brow][bcol] = vb;
    }
    __syncthreads();
    #pragma unroll
    for (int kk = 0; kk < 32; kk++){
      float4 a4 = *(const float4*)&As[kk][ty*4];
      float4 b4 = *(const float4*)&Bs[kk][tx*4];
      float au[4] = {a4.x,a4.y,a4.z,a4.w}, bv[4] = {b4.x,b4.y,b4.z,b4.w};
      #pragma unroll
      for (int u = 0; u < 4; u++)
        #pragma unroll
        for (int v = 0; v < 4; v++) acc[u][v] = fmaf(au[u], bv[v], acc[u][v]);
    }
    __syncthreads();
  }
  #pragma unroll
  for (int u = 0; u < 4; u++){
    uint2 st = { pk16(acc[u][0], acc[u][1]), pk16(acc[u][2], acc[u][3]) };
    *(uint2*)(Cout + (size_t)(m0+ty*4+u)*256 + (n0 + tx*4)/2) = st;
  }
}

/* ------------------------------- decoder scan ----------------------------------- */
/* P16 [64][512] f16 and V16 [512][64] f16 staged in 128KB LDS (swizzled);          */
/* 3 barriers/step; per-wave redundant softmax (DPP); fdot2 inner products.         */
__global__ void __launch_bounds__(256) dec_kernel(const float* __restrict__ Z,
    const unsigned int* __restrict__ Pg, const unsigned int* __restrict__ Vg,
    const float* __restrict__ cdec, const float* __restrict__ n2g,
    const float* __restrict__ n2b, float* __restrict__ zfin){
  __shared__ __align__(16) unsigned char Pl[65536];
  __shared__ __align__(16) unsigned char Vl[65536];
  __shared__ float zL[DD];
  __shared__ unsigned int zh[256];
  __shared__ float part[AA][4];
  __shared__ unsigned int att4h[4][32];
  __shared__ float2 red2[4];
  int b = blockIdx.x, tid = threadIdx.x;
  int lane = tid & 63, w = tid >> 6;

  /* stage P (swizzle key = (a&7)<<4 within 1KB row) */
  const uint4* Pg4 = (const uint4*)(Pg + (size_t)b*16384);
  #pragma unroll
  for (int j = 0; j < 16; j++){
    int fb = j*1024 + tid*4;                       /* u32 index */
    uint4 v = Pg4[j*256 + tid];
    int a = fb >> 8;
    int off = (fb & 255) * 4;
    *(uint4*)(Pl + a*1024 + (off ^ ((a&7)<<4))) = v;
  }
  /* stage V (swizzle key = ((d>>1)&7)<<4 within 128B row) */
  const uint4* Vg4 = (const uint4*)(Vg + (size_t)b*16384);
  #pragma unroll
  for (int j = 0; j < 16; j++){
    int fb = j*1024 + tid*4;
    uint4 v = Vg4[j*256 + tid];
    int d = fb >> 5;
    int off = (fb & 31) * 4;
    *(uint4*)(Vl + d*128 + (off ^ (((d>>1)&7)<<4))) = v;
  }
  zL[tid]       = Z[((size_t)b*SENC + SENC-1)*DD + tid];
  zL[tid + 256] = Z[((size_t)b*SENC + SENC-1)*DD + tid + 256];
  float cdv = cdec[b*AA + lane];
  int d0 = tid*2;
  float g2a = n2g[d0], g2b = n2g[d0+1], b2a = n2b[d0], b2b = n2b[d0+1];
  int pk = (lane&7)<<4;
  int vk = (tid&7)<<4;
  __syncthreads();
  zh[tid] = pk16(zL[2*tid], zL[2*tid+1]);
  __syncthreads();

  float z0r = zL[d0], z1r = zL[d0+1];
  for (int t = 0; t < SDEC; t++){
    /* ph1: logit partial for anchor=lane over d-quarter w (LDS f16 dot) */
    float s = 0.f;
    #pragma unroll
    for (int j = 0; j < 16; j++){
      uint4 pv = *(const uint4*)(Pl + lane*1024 + ((w*256 + j*16) ^ pk));
      uint4 zv = *(const uint4*)&zh[w*64 + j*4];
      s = fd2(pv.x, zv.x, s); s = fd2(pv.y, zv.y, s);
      s = fd2(pv.z, zv.z, s); s = fd2(pv.w, zv.w, s);
    }
    part[lane][w] = s;
    __syncthreads();                               /* A */
    /* ph2: redundant per-wave softmax over 64 anchors */
    float4 pp = *(const float4*)&part[lane][0];
    float l = (pp.x + pp.y + pp.z + pp.w + cdv) * SCALE;
    float mx = wredmax(l);
    float e = __expf(l - mx);
    float se = wredsum(e);
    float attv = e / se;
    float attn = dppself<0x101,0xf>(attv);         /* row_shl:1 -> lane i gets att[i+1] */
    if ((lane & 1) == 0) att4h[w][lane>>1] = pk16(attv, attn);
    asm volatile("s_waitcnt lgkmcnt(0)" ::: "memory");
    /* ph3: dg2 for d0,d0+1 + LN stats */
    float a0 = 0.f, a1 = 0.f;
    #pragma unroll
    for (int j = 0; j < 8; j++){
      uint4 ah = *(const uint4*)&att4h[w][j*4];
      uint4 v0 = *(const uint4*)(Vl + d0*128 + ((j*16) ^ vk));
      uint4 v1 = *(const uint4*)(Vl + (d0+1)*128 + ((j*16) ^ vk));
      a0 = fd2(v0.x, ah.x, a0); a0 = fd2(v0.y, ah.y, a0);
      a0 = fd2(v0.z, ah.z, a0); a0 = fd2(v0.w, ah.w, a0);
      a1 = fd2(v1.x, ah.x, a1); a1 = fd2(v1.y, ah.y, a1);
      a1 = fd2(v1.z, ah.z, a1); a1 = fd2(v1.w, ah.w, a1);
    }
    float y0 = z0r + a0, y1 = z1r + a1;
    float s2 = y0 + y1, q2 = fmaf(y0, y0, y1*y1);
    wred2(s2, q2);
    if (lane == 0){ float2 o = {s2, q2}; red2[w] = o; }
    __syncthreads();                               /* B */
    float2 rA = red2[0], rB = red2[1], rC = red2[2], rD = red2[3];
    float Sy = rA.x+rB.x+rC.x+rD.x, Qy = rA.y+rB.y+rC.y+rD.y;
    float mean = Sy * (1.f/DD);
    float var  = fmaxf((Qy - (float)DD*mean*mean) * (1.f/(DD-1)), 0.f);
    float r = 1.f/(sqrtf(var) + EPSL);
    z0r = fmaf(g2a*r, y0-mean, b2a);
    z1r = fmaf(g2b*r, y1-mean, b2b);
    zL[d0] = z0r; zL[d0+1] = z1r;
    zh[tid] = pk16(z0r, z1r);
    __syncthreads();                               /* C */
  }
  zfin[(size_t)b*DD + d0]     = z0r;
  zfin[(size_t)b*DD + d0 + 1] = z1r;
}

/* ---------------- logits = zfin @ voc_W^T + voc_b ------------------------------- */
/* block: 256 thr = 4 waves; wave: 32 rows; lane: (rp, kq); z staged in 64KB LDS.   */
__global__ void __launch_bounds__(256) logits_kernel(const float* __restrict__ zfin,
    const float* __restrict__ vocW, const float* __restrict__ vocb, float* __restrict__ out){
  __shared__ float zS[NB*DD];
  int tid = threadIdx.x;
  const float4* src = (const float4*)zfin;
  float4* dst = (float4*)zS;
  #pragma unroll
  for (int i = 0; i < 16; i++) dst[tid + i*256] = src[tid + i*256];
  __syncthreads();
  int w = tid >> 6, lane = tid & 63;
  int kq = lane & 3, rp = lane >> 2;
  int r0 = blockIdx.x*128 + w*32 + rp*2, r1 = r0 + 1;
  float acc0[NB], acc1[NB];
  #pragma unroll
  for (int bq = 0; bq < NB; bq++){ acc0[bq] = 0.f; acc1[bq] = 0.f; }
  const float* w0p = vocW + (size_t)r0*DD;
  const float* w1p = vocW + (size_t)r1*DD;
  for (int ks = 0; ks < 32; ks++){
    int koff = ks*16 + kq*4;
    float4 w0 = *(const float4*)(w0p + koff);
    float4 w1 = *(const float4*)(w1p + koff);
    #pragma unroll
    for (int bq = 0; bq < NB; bq++){
      float4 z4 = *(const float4*)&zS[bq*DD + koff];
      acc0[bq] = fmaf(w0.x,z4.x, fmaf(w0.y,z4.y, fmaf(w0.z,z4.z, fmaf(w0.w,z4.w, acc0[bq]))));
      acc1[bq] = fmaf(w1.x,z4.x, fmaf(w1.y,z4.y, fmaf(w1.z,z4.z, fmaf(w1.w,z4.w, acc1[bq]))));
    }
  }
  /* quad reduction over kq (quad_perm xor1=0xB1, xor2=0x4E) */
  #pragma unroll
  for (int bq = 0; bq < NB; bq++){
    acc0[bq] += dppz<0xB1,0xf>(acc0[bq]); acc0[bq] += dppz<0x4E,0xf>(acc0[bq]);
    acc1[bq] += dppz<0xB1,0xf>(acc1[bq]); acc1[bq] += dppz<0x4E,0xf>(acc1[bq]);
  }
  if (kq == 0){
    float vb0 = vocb[r0], vb1 = vocb[r1];
    #pragma unroll
    for (int bq = 0; bq < NB; bq++){
      out[(size_t)bq*VOUT + r0] = acc0[bq] + vb0;
      out[(size_t)bq*VOUT + r1] = acc1[bq] + vb1;
    }
  }
}

/* --------------------------- split log_softmax ---------------------------------- */
__global__ void __launch_bounds__(256) lsm1_kernel(const float* __restrict__ out,
    float2* __restrict__ partb){
  int b = blockIdx.x >> 3, c = blockIdx.x & 7;
  const float* row = out + (size_t)b*VOUT + c*4000;
  int tid = threadIdx.x;
  __shared__ float rm[4]; __shared__ float rs[4];
  float mx = -3.4e38f;
  for (int i = tid; i < 4000; i += 256) mx = fmaxf(mx, row[i]);
  mx = wredmax(mx);
  if ((tid & 63) == 0) rm[tid>>6] = mx;
  __syncthreads();
  mx = fmaxf(fmaxf(rm[0],rm[1]), fmaxf(rm[2],rm[3]));
  float sm = 0.f;
  for (int i = tid; i < 4000; i += 256) sm += __expf(row[i] - mx);
  sm = wredsum(sm);
  if ((tid & 63) == 0) rs[tid>>6] = sm;
  __syncthreads();
  if (tid == 0){ float2 o = {mx, rs[0]+rs[1]+rs[2]+rs[3]}; partb[blockIdx.x] = o; }
}
__global__ void __launch_bounds__(256) lsm2_kernel(float* __restrict__ out,
    const float2* __restrict__ partb){
  int b = blockIdx.x >> 3, c = blockIdx.x & 7;
  float M = -3.4e38f, S = 0.f;
  #pragma unroll
  for (int j = 0; j < 8; j++) M = fmaxf(M, partb[b*8+j].x);
  #pragma unroll
  for (int j = 0; j < 8; j++){ float2 p = partb[b*8+j]; S += p.y * __expf(p.x - M); }
  float cns = M + logf(S);
  float* row = out + (size_t)b*VOUT + c*4000;
  for (int i = threadIdx.x; i < 4000; i += 256) row[i] -= cns;
}

extern "C" void kernel_launch(void* const* d_in, const int* in_sizes, int n_in,
                              void* d_out, int out_size, void* d_ws, size_t ws_size,
                              hipStream_t stream){
  (void)in_sizes; (void)n_in; (void)out_size; (void)ws_size;
  const int*   toks      = (const int*)  d_in[0];
  const float* emb_in    = (const float*)d_in[2];
  const float* enc_key_W = (const float*)d_in[4];
  const float* enc_Wq    = (const float*)d_in[5];
  const float* enc_bq    = (const float*)d_in[6];
  const float* enc_Wk    = (const float*)d_in[7];
  const float* enc_bk    = (const float*)d_in[8];
  const float* n1g       = (const float*)d_in[9];
  const float* n1b       = (const float*)d_in[10];
  const float* rdr_Wq    = (const float*)d_in[12];
  const float* rdr_bq    = (const float*)d_in[13];
  const float* rdr_Wk    = (const float*)d_in[14];
  const float* rdr_bk    = (const float*)d_in[15];
  const float* rdr_Wv    = (const float*)d_in[16];
  const float* rdr_bv    = (const float*)d_in[17];
  const float* n2g       = (const float*)d_in[22];
  const float* n2b       = (const float*)d_in[23];
  const float* vocW      = (const float*)d_in[26];
  const float* vocb      = (const float*)d_in[27];
  float* outp = (float*)d_out;

  float* ws = (float*)d_ws;
  size_t off = 0;
  float* Z    = ws + off; off += (size_t)NB*SENC*DD;      /* 64 MB */
  float* ZSQ  = ws + off; off += (size_t)NB*SENC*2;
  float* av   = ws + off; off += (size_t)NB*AA*DD;
  float* Kr   = ws + off; off += (size_t)NB*AA*DD;
  unsigned int* P16 = (unsigned int*)(ws + off); off += (size_t)NB*AA*DD/2;
  unsigned int* V16 = (unsigned int*)(ws + off); off += (size_t)NB*AA*DD/2;
  float* Qa   = ws + off; off += (size_t)AA*DD;
  float* Menc = ws + off; off += (size_t)AA*DD;
  float* cenc = ws + off; off += AA;
  float* cdec = ws + off; off += (size_t)NB*AA;
  float* zfin = ws + off; off += (size_t)NB*DD;
  float2* lsp = (float2*)(ws + off); off += 512;

  qa_kernel   <<<AA, 512, 0, stream>>>(enc_key_W, enc_Wq, enc_bq, Qa);
  menc_kernel <<<AA, 512, 0, stream>>>(Qa, enc_Wk, Menc);
  dotb_kernel <<<AA/4, 256, 0, stream>>>(Qa, enc_bk, cenc);
  zscan_kernel<<<NB, 64, 0, stream>>>(toks, emb_in, n1g, n1b, Z);
  zstats_kernel<<<NB*SENC/4, 256, 0, stream>>>(Z, ZSQ);
  avscan_kernel<<<256, 512, 0, stream>>>(Z, ZSQ, Menc, cenc, n1g, n1b, av);
  gemm_nt_kernel<<<dim3(NB*AA/64, DD/64), 256, 0, stream>>>(av, rdr_Wk, rdr_bk, Kr, 0);
  gemm_nn_kernel<<<dim3(NB*AA/64, DD/64), 256, 0, stream>>>(Kr, rdr_Wq, P16);
  gemm_nt_kernel<<<dim3(NB*AA/64, DD/64), 256, 0, stream>>>(av, rdr_Wv, rdr_bv, V16, 1);
  dotb_kernel <<<NB*AA/4, 256, 0, stream>>>(Kr, rdr_bq, cdec);
  dec_kernel  <<<NB, 256, 0, stream>>>(Z, P16, V16, cdec, n2g, n2b, zfin);
  logits_kernel<<<VOUT/128, 256, 0, stream>>>(zfin, vocW, vocb, outp);
  lsm1_kernel <<<NB*8, 256, 0, stream>>>(outp, lsp);
  lsm2_kernel <<<NB*8, 256, 0, stream>>>(outp, lsp);
}

// Round 4
// 1663.780 us; speedup vs baseline: 1.5938x; 1.1460x over previous
//
#include <hip/hip_runtime.h>
#include <math.h>

#define DD 512
#define AA 64
#define NB 32
#define SENC 1024
#define SDEC 256
#define VOUT 32000
#define EPSL 1e-6f
#define SCALE 0.044194173824159216f   /* 1/sqrt(512) */
#define SQRTD 22.627416997969522f     /* sqrt(512) */

typedef _Float16 h2 __attribute__((ext_vector_type(2)));

/* ---------------- DPP wave reduction helpers (VALU-only) ----------------------- */
template<int C, int R>
__device__ __forceinline__ float dppz(float v){   /* old=0, bound_ctrl=1 */
  return __int_as_float(__builtin_amdgcn_update_dpp(0, __float_as_int(v), C, R, 0xf, true));
}
template<int C, int R>
__device__ __forceinline__ float dppself(float v){ /* old=self, bound_ctrl=0 */
  return __int_as_float(__builtin_amdgcn_update_dpp(__float_as_int(v), __float_as_int(v), C, R, 0xf, false));
}
__device__ __forceinline__ float rlane63(float v){
  return __int_as_float(__builtin_amdgcn_readlane(__float_as_int(v), 63));
}
__device__ __forceinline__ void wred2(float &a, float &b){
  a += dppz<0x111,0xf>(a); b += dppz<0x111,0xf>(b);
  a += dppz<0x112,0xf>(a); b += dppz<0x112,0xf>(b);
  a += dppz<0x114,0xf>(a); b += dppz<0x114,0xf>(b);
  a += dppz<0x118,0xf>(a); b += dppz<0x118,0xf>(b);
  a += dppz<0x142,0xa>(a); b += dppz<0x142,0xa>(b);
  a += dppz<0x143,0xc>(a); b += dppz<0x143,0xc>(b);
  a = rlane63(a); b = rlane63(b);
}
__device__ __forceinline__ float wredsum(float a){
  a += dppz<0x111,0xf>(a); a += dppz<0x112,0xf>(a);
  a += dppz<0x114,0xf>(a); a += dppz<0x118,0xf>(a);
  a += dppz<0x142,0xa>(a); a += dppz<0x143,0xc>(a);
  return rlane63(a);
}
__device__ __forceinline__ float wredmax(float a){
  a = fmaxf(a, dppself<0x111,0xf>(a));
  a = fmaxf(a, dppself<0x112,0xf>(a));
  a = fmaxf(a, dppself<0x114,0xf>(a));
  a = fmaxf(a, dppself<0x118,0xf>(a));
  a = fmaxf(a, dppself<0x142,0xa>(a));
  a = fmaxf(a, dppself<0x143,0xc>(a));
  return rlane63(a);
}
__device__ __forceinline__ unsigned int pk16(float x, float y){
  return __builtin_bit_cast(unsigned int, __builtin_amdgcn_cvt_pkrtz(x, y));
}
__device__ __forceinline__ float fd2(unsigned int a, unsigned int b, float c){
#if __has_builtin(__builtin_amdgcn_fdot2)
  return __builtin_amdgcn_fdot2(__builtin_bit_cast(h2, a), __builtin_bit_cast(h2, b), c, false);
#else
  h2 x = __builtin_bit_cast(h2, a), y = __builtin_bit_cast(h2, b);
  return c + (float)x[0]*(float)y[0] + (float)x[1]*(float)y[1];
#endif
}

/* ---------------- Qa = enc_key_W @ enc_Wq^T + enc_bq  [64,512] ---------------- */
__global__ void __launch_bounds__(512) qa_kernel(const float* __restrict__ keyW,
    const float* __restrict__ Wq, const float* __restrict__ bq, float* __restrict__ Qa){
  int a = blockIdx.x, i = threadIdx.x;
  __shared__ float key[DD];
  key[i] = keyW[a*DD + i];
  __syncthreads();
  const float4* w4 = (const float4*)(Wq + (size_t)i*DD);
  const float4* k4 = (const float4*)key;
  float s = 0.f;
  #pragma unroll 4
  for (int j = 0; j < DD/4; j++){
    float4 w = w4[j], k = k4[j];
    s = fmaf(w.x,k.x, fmaf(w.y,k.y, fmaf(w.z,k.z, fmaf(w.w,k.w, s))));
  }
  Qa[a*DD + i] = s + bq[i];
}

/* ------------- Menc = Qa @ enc_Wk  [64,512] ----------------------------------- */
__global__ void __launch_bounds__(512) menc_kernel(const float* __restrict__ Qa,
    const float* __restrict__ Wk, float* __restrict__ Menc){
  int a = blockIdx.x, j = threadIdx.x;
  __shared__ float qa[DD];
  qa[j] = Qa[a*DD + j];
  __syncthreads();
  float s = 0.f;
  #pragma unroll 4
  for (int i = 0; i < DD; i++) s = fmaf(qa[i], Wk[(size_t)i*DD + j], s);
  Menc[a*DD + j] = s;
}

/* ------------- out[m] = X[m,:] . v  (4 rows per block) ------------------------- */
__global__ void __launch_bounds__(256) dotb_kernel(const float* __restrict__ X,
    const float* __restrict__ v, float* __restrict__ out){
  int m = blockIdx.x*4 + (threadIdx.x >> 6);
  int lane = threadIdx.x & 63;
  const float4* x4 = (const float4*)(X + (size_t)m*DD + lane*8);
  const float4* v4 = (const float4*)(v + lane*8);
  float4 a = x4[0], b4 = x4[1], c = v4[0], d = v4[1];
  float s = a.x*c.x;
  s = fmaf(a.y,c.y, s); s = fmaf(a.z,c.z, s); s = fmaf(a.w,c.w, s);
  s = fmaf(b4.x,d.x, s); s = fmaf(b4.y,d.y, s); s = fmaf(b4.z,d.z, s); s = fmaf(b4.w,d.w, s);
  s = wredsum(s);
  if (lane == 0) out[m] = s;
}

/* ------------- flag = all(n1g==1) && all(n1b==0) ------------------------------- */
__global__ void __launch_bounds__(512) flag_kernel(const float* __restrict__ g,
    const float* __restrict__ b, int* __restrict__ flag){
  __shared__ int s;
  if (threadIdx.x == 0) s = 1;
  __syncthreads();
  bool ok = (g[threadIdx.x] == 1.0f) && (b[threadIdx.x] == 0.0f);
  if (!ok) atomicAnd(&s, 0);
  __syncthreads();
  if (threadIdx.x == 0) flag[0] = s;
}

/* --------- encoder z-scan: 1 wave per batch, z_t = LN(z_{t-1} + sqrtD*x_t) ------ */
__global__ void __launch_bounds__(64) zscan_kernel(const int* __restrict__ toks,
    const float* __restrict__ emb, const float* __restrict__ n1g,
    const float* __restrict__ n1b, float* __restrict__ Z){
  int b = blockIdx.x, lane = threadIdx.x;
  int bd = lane*8;
  float z[8], g1[8], b1[8];
  #pragma unroll
  for (int k = 0; k < 8; k++) z[k] = 0.f;
  *(float4*)&g1[0] = *(const float4*)(n1g+bd); *(float4*)&g1[4] = *(const float4*)(n1g+bd+4);
  *(float4*)&b1[0] = *(const float4*)(n1b+bd); *(float4*)&b1[4] = *(const float4*)(n1b+bd+4);
  const int* tb = toks + b*SENC;
  float* Zb = Z + (size_t)b*SENC*DD + bd;
  int tok = tb[0];
  float4 xa = *(const float4*)(emb + (size_t)tok*DD + bd);
  float4 xb = *(const float4*)(emb + (size_t)tok*DD + bd + 4);
  for (int t = 0; t < SENC; t++){
    float x[8] = {xa.x,xa.y,xa.z,xa.w,xb.x,xb.y,xb.z,xb.w};
    int tn = tb[(t+1 < SENC) ? t+1 : t];              /* prefetch next token row */
    xa = *(const float4*)(emb + (size_t)tn*DD + bd);
    xb = *(const float4*)(emb + (size_t)tn*DD + bd + 4);
    float y[8], s = 0.f, q = 0.f;
    #pragma unroll
    for (int k = 0; k < 8; k++){ y[k] = fmaf(SQRTD, x[k], z[k]); s += y[k]; q = fmaf(y[k], y[k], q); }
    wred2(s, q);
    float mean = s * (1.f/DD);
    float var  = fmaxf((q - (float)DD*mean*mean) * (1.f/(DD-1)), 0.f);   /* ddof=1 */
    float r = 1.f/(sqrtf(var) + EPSL);
    #pragma unroll
    for (int k = 0; k < 8; k++) z[k] = fmaf(g1[k]*r, y[k]-mean, b1[k]);
    float4 o1 = {z[0],z[1],z[2],z[3]}, o2 = {z[4],z[5],z[6],z[7]};
    *(float4*)(Zb + (size_t)t*DD)     = o1;
    *(float4*)(Zb + (size_t)t*DD + 4) = o2;
  }
}

/* -------- per-row (b,t) stats of Z: ZSQ[row] = (sum z, sum z^2) ----------------- */
__global__ void __launch_bounds__(256) zstats_kernel(const float* __restrict__ Z,
    float* __restrict__ ZSQ){
  int row = blockIdx.x*4 + (threadIdx.x >> 6);
  int lane = threadIdx.x & 63;
  const float4* z4 = (const float4*)(Z + (size_t)row*DD + lane*8);
  float4 a = z4[0], b4 = z4[1];
  float s = a.x+a.y+a.z+a.w + b4.x+b4.y+b4.z+b4.w;
  float q = a.x*a.x;
  q = fmaf(a.y,a.y,q); q = fmaf(a.z,a.z,q); q = fmaf(a.w,a.w,q);
  q = fmaf(b4.x,b4.x,q); q = fmaf(b4.y,b4.y,q); q = fmaf(b4.z,b4.z,q); q = fmaf(b4.w,b4.w,q);
  wred2(s, q);
  if (lane == 0){ float2 o = {s, q}; *(float2*)(ZSQ + (size_t)row*2) = o; }
}

/* -------- gates[bt][a] = sigmoid((Z[bt,:].Menc[a,:] + cenc[a])*SCALE) ----------- */
__global__ void __launch_bounds__(256) gates_kernel(const float* __restrict__ Zin,
    const float* __restrict__ Menc, const float* __restrict__ cenc,
    float* __restrict__ gates){
  __shared__ float As[32][64];
  __shared__ float Bs[32][64];
  int tid = threadIdx.x;
  int m0 = blockIdx.x*64;
  int ty = tid >> 4, tx = tid & 15;
  float acc[4][4] = {{0.f}};
  for (int k0 = 0; k0 < 512; k0 += 32){
    #pragma unroll
    for (int p = 0; p < 2; p++){
      int row = (tid>>3) + p*32, col = (tid&7)*4;
      float4 va = *(const float4*)(Zin + (size_t)(m0+row)*512 + k0 + col);
      As[col][row]=va.x; As[col+1][row]=va.y; As[col+2][row]=va.z; As[col+3][row]=va.w;
      float4 vb = *(const float4*)(Menc + (size_t)row*512 + k0 + col);
      Bs[col][row]=vb.x; Bs[col+1][row]=vb.y; Bs[col+2][row]=vb.z; Bs[col+3][row]=vb.w;
    }
    __syncthreads();
    #pragma unroll
    for (int kk = 0; kk < 32; kk++){
      float4 a4 = *(const float4*)&As[kk][ty*4];
      float4 b4 = *(const float4*)&Bs[kk][tx*4];
      float au[4] = {a4.x,a4.y,a4.z,a4.w}, bv[4] = {b4.x,b4.y,b4.z,b4.w};
      #pragma unroll
      for (int u = 0; u < 4; u++)
        #pragma unroll
        for (int v = 0; v < 4; v++) acc[u][v] = fmaf(au[u], bv[v], acc[u][v]);
    }
    __syncthreads();
  }
  float cv[4];
  #pragma unroll
  for (int v = 0; v < 4; v++) cv[v] = cenc[tx*4 + v];
  #pragma unroll
  for (int u = 0; u < 4; u++){
    float4 st;
    st.x = 1.f/(1.f + __expf(-(acc[u][0]+cv[0])*SCALE));
    st.y = 1.f/(1.f + __expf(-(acc[u][1]+cv[1])*SCALE));
    st.z = 1.f/(1.f + __expf(-(acc[u][2]+cv[2])*SCALE));
    st.w = 1.f/(1.f + __expf(-(acc[u][3]+cv[3])*SCALE));
    *(float4*)(gates + (size_t)(m0+ty*4+u)*AA + tx*4) = st;
  }
}

/* ---- encoder av-scan: gates precomputed; FAST path uses analytic LN stats ------ */
template<bool FAST>
__device__ __forceinline__ void avscan_body(const float* __restrict__ Z,
    const float* __restrict__ ZSQ, const float* __restrict__ gates,
    const float* __restrict__ n1g, const float* __restrict__ n1b,
    float* __restrict__ avout){
  int bx = blockIdx.x;
  int b = (bx & 7)*4 + ((bx >> 3) & 3);          /* all blocks of batch b on one XCD */
  int a = ((bx >> 5)<<3) + (threadIdx.x >> 6);
  int lane = threadIdx.x & 63;
  int bd = lane*8;
  float g1[8], b1[8], av[8];
  if (!FAST){
    *(float4*)&g1[0] = *(const float4*)(n1g+bd); *(float4*)&g1[4] = *(const float4*)(n1g+bd+4);
    *(float4*)&b1[0] = *(const float4*)(n1b+bd); *(float4*)&b1[4] = *(const float4*)(n1b+bd+4);
  }
  #pragma unroll
  for (int k = 0; k < 8; k++) av[k] = 0.f;
  float Sav = 0.f, Qav = 0.f;
  const float*  zp = Z + (size_t)b*SENC*DD + bd;
  const float2* sp = (const float2*)ZSQ + (size_t)b*SENC;
  const float*  gp = gates + (size_t)b*SENC*AA + a;
  float4 za = *(const float4*)zp, zb = *(const float4*)(zp + 4);
  float2 sq = *sp;
  float  gt = *gp;
  for (int t = 0; t < SENC; t++){
    float z[8] = {za.x,za.y,za.z,za.w,zb.x,zb.y,zb.z,zb.w};
    float Szt = sq.x, Qzt = sq.y, g = gt;
    if (t + 1 < SENC){                              /* uniform branch: prefetch */
      zp += DD; sp += 1; gp += AA;
      za = *(const float4*)zp; zb = *(const float4*)(zp + 4);
      sq = *sp; gt = *gp;
    }
    float cav = 0.f;
    #pragma unroll
    for (int k = 0; k < 8; k++) cav = fmaf(av[k], z[k], cav);
    cav = wredsum(cav);
    float omg = 1.f - g;
    float Sy = fmaf(g, Szt - Sav, Sav);
    float Qy = omg*omg*Qav + 2.f*g*omg*cav + g*g*Qzt;
    float mean = Sy * (1.f/DD);
    float var  = fmaxf((Qy - (float)DD*mean*mean) * (1.f/(DD-1)), 0.f);
    float r = 1.f/(sqrtf(var) + EPSL);
    if (FAST){
      #pragma unroll
      for (int k = 0; k < 8; k++){
        float y = fmaf(g, z[k]-av[k], av[k]);
        av[k] = (y - mean) * r;
      }
      Sav = 0.f;
      Qav = (float)(DD-1) * var * r * r;            /* analytic: exact closure for g1=1,b1=0 */
    } else {
      float sn = 0.f, qn = 0.f;
      #pragma unroll
      for (int k = 0; k < 8; k++){
        float y = fmaf(g, z[k]-av[k], av[k]);
        float nv = fmaf(g1[k]*r, y-mean, b1[k]);
        av[k] = nv; sn += nv; qn = fmaf(nv, nv, qn);
      }
      wred2(sn, qn);
      Sav = sn; Qav = qn;
    }
  }
  float* o = avout + ((size_t)(b*AA + a))*DD + bd;
  float4 o1 = {av[0],av[1],av[2],av[3]}, o2 = {av[4],av[5],av[6],av[7]};
  *(float4*)o = o1; *(float4*)(o+4) = o2;
}

__global__ void __launch_bounds__(512) avscan_kernel(const float* __restrict__ Z,
    const float* __restrict__ ZSQ, const float* __restrict__ gates,
    const float* __restrict__ n1g, const float* __restrict__ n1b,
    const int* __restrict__ flag, float* __restrict__ avout){
  if (flag[0]) avscan_body<true >(Z, ZSQ, gates, n1g, n1b, avout);
  else         avscan_body<false>(Z, ZSQ, gates, n1g, n1b, avout);
}

/* ------------- f32 GEMM, C[m,n] = sum_k A[m,k]*Bw[n,k] (+bias[n]) --------------- */
__global__ void __launch_bounds__(256) gemm_nt_kernel(const float* __restrict__ Aa,
    const float* __restrict__ Bw, const float* __restrict__ bias,
    void* __restrict__ Cout, int mode){
  __shared__ float As[32][64];
  __shared__ float Bs[32][64];
  int tid = threadIdx.x;
  int m0 = blockIdx.x*64, n0 = blockIdx.y*64;
  int ty = tid >> 4, tx = tid & 15;
  float acc[4][4] = {{0.f}};
  for (int k0 = 0; k0 < 512; k0 += 32){
    #pragma unroll
    for (int p = 0; p < 2; p++){
      int row = (tid>>3) + p*32, col = (tid&7)*4;
      float4 va = *(const float4*)(Aa + (size_t)(m0+row)*512 + k0 + col);
      As[col][row]=va.x; As[col+1][row]=va.y; As[col+2][row]=va.z; As[col+3][row]=va.w;
      float4 vb = *(const float4*)(Bw + (size_t)(n0+row)*512 + k0 + col);
      Bs[col][row]=vb.x; Bs[col+1][row]=vb.y; Bs[col+2][row]=vb.z; Bs[col+3][row]=vb.w;
    }
    __syncthreads();
    #pragma unroll
    for (int kk = 0; kk < 32; kk++){
      float4 a4 = *(const float4*)&As[kk][ty*4];
      float4 b4 = *(const float4*)&Bs[kk][tx*4];
      float au[4] = {a4.x,a4.y,a4.z,a4.w}, bv[4] = {b4.x,b4.y,b4.z,b4.w};
      #pragma unroll
      for (int u = 0; u < 4; u++)
        #pragma unroll
        for (int v = 0; v < 4; v++) acc[u][v] = fmaf(au[u], bv[v], acc[u][v]);
    }
    __syncthreads();
  }
  float bv4[4];
  #pragma unroll
  for (int v = 0; v < 4; v++) bv4[v] = bias ? bias[n0 + tx*4 + v] : 0.f;
  if (mode == 0){
    float* C = (float*)Cout;
    #pragma unroll
    for (int u = 0; u < 4; u++){
      float4 st = {acc[u][0]+bv4[0], acc[u][1]+bv4[1], acc[u][2]+bv4[2], acc[u][3]+bv4[3]};
      *(float4*)(C + (size_t)(m0+ty*4+u)*512 + n0 + tx*4) = st;
    }
  } else {
    unsigned short* C = (unsigned short*)Cout;
    #pragma unroll
    for (int u = 0; u < 4; u++){
      int mm = m0 + ty*4 + u; int bb = mm >> 6, a2 = mm & 63;
      #pragma unroll
      for (int v = 0; v < 4; v++){
        _Float16 hv = (_Float16)(acc[u][v] + bv4[v]);
        C[((size_t)bb*512 + n0 + tx*4 + v)*64 + a2] = __builtin_bit_cast(unsigned short, hv);
      }
    }
  }
}

/* ------------- P16[m][n] (f16) = sum_k A[m,k]*B[k,n] --------------------------- */
__global__ void __launch_bounds__(256) gemm_nn_kernel(const float* __restrict__ Aa,
    const float* __restrict__ Bw, unsigned int* __restrict__ Cout){
  __shared__ float As[32][64];
  __shared__ float Bs[32][64];
  int tid = threadIdx.x;
  int m0 = blockIdx.x*64, n0 = blockIdx.y*64;
  int ty = tid >> 4, tx = tid & 15;
  float acc[4][4] = {{0.f}};
  for (int k0 = 0; k0 < 512; k0 += 32){
    #pragma unroll
    for (int p = 0; p < 2; p++){
      int row = (tid>>3) + p*32, col = (tid&7)*4;
      float4 va = *(const float4*)(Aa + (size_t)(m0+row)*512 + k0 + col);
      As[col][row]=va.x; As[col+1][row]=va.y; As[col+2][row]=va.z; As[col+3][row]=va.w;
      int brow = (tid>>4) + p*16, bcol = (tid&15)*4;
      float4 vb = *(const float4*)(Bw + (size_t)(k0+brow)*512 + n0 + bcol);
      *(float4*)&Bs[brow][bcol] = vb;
    }
    __syncthreads();
    #pragma unroll
    for (int kk = 0; kk < 32; kk++){
      float4 a4 = *(const float4*)&As[kk][ty*4];
      float4 b4 = *(const float4*)&Bs[kk][tx*4];
      float au[4] = {a4.x,a4.y,a4.z,a4.w}, bv[4] = {b4.x,b4.y,b4.z,b4.w};
      #pragma unroll
      for (int u = 0; u < 4; u++)
        #pragma unroll
        for (int v = 0; v < 4; v++) acc[u][v] = fmaf(au[u], bv[v], acc[u][v]);
    }
    __syncthreads();
  }
  #pragma unroll
  for (int u = 0; u < 4; u++){
    uint2 st = { pk16(acc[u][0], acc[u][1]), pk16(acc[u][2], acc[u][3]) };
    *(uint2*)(Cout + (size_t)(m0+ty*4+u)*256 + (n0 + tx*4)/2) = st;
  }
}

/* ------------------------------- decoder scan ----------------------------------- */
__global__ void __launch_bounds__(256) dec_kernel(const float* __restrict__ Z,
    const unsigned int* __restrict__ Pg, const unsigned int* __restrict__ Vg,
    const float* __restrict__ cdec, const float* __restrict__ n2g,
    const float* __restrict__ n2b, float* __restrict__ zfin){
  __shared__ __align__(16) unsigned char Pl[65536];
  __shared__ __align__(16) unsigned char Vl[65536];
  __shared__ float zL[DD];
  __shared__ unsigned int zh[256];
  __shared__ float part[AA][4];
  __shared__ unsigned int att4h[4][32];
  __shared__ float2 red2[4];
  int b = blockIdx.x, tid = threadIdx.x;
  int lane = tid & 63, w = tid >> 6;

  const uint4* Pg4 = (const uint4*)(Pg + (size_t)b*16384);
  #pragma unroll
  for (int j = 0; j < 16; j++){
    int fb = j*1024 + tid*4;
    uint4 v = Pg4[j*256 + tid];
    int a = fb >> 8;
    int off = (fb & 255) * 4;
    *(uint4*)(Pl + a*1024 + (off ^ ((a&7)<<4))) = v;
  }
  const uint4* Vg4 = (const uint4*)(Vg + (size_t)b*16384);
  #pragma unroll
  for (int j = 0; j < 16; j++){
    int fb = j*1024 + tid*4;
    uint4 v = Vg4[j*256 + tid];
    int d = fb >> 5;
    int off = (fb & 31) * 4;
    *(uint4*)(Vl + d*128 + (off ^ (((d>>1)&7)<<4))) = v;
  }
  zL[tid]       = Z[((size_t)b*SENC + SENC-1)*DD + tid];
  zL[tid + 256] = Z[((size_t)b*SENC + SENC-1)*DD + tid + 256];
  float cdv = cdec[b*AA + lane];
  int d0 = tid*2;
  float g2a = n2g[d0], g2b = n2g[d0+1], b2a = n2b[d0], b2b = n2b[d0+1];
  int pk = (lane&7)<<4;
  int vk = (tid&7)<<4;
  __syncthreads();
  zh[tid] = pk16(zL[2*tid], zL[2*tid+1]);
  __syncthreads();

  float z0r = zL[d0], z1r = zL[d0+1];
  for (int t = 0; t < SDEC; t++){
    float s = 0.f;
    #pragma unroll
    for (int j = 0; j < 16; j++){
      uint4 pv = *(const uint4*)(Pl + lane*1024 + ((w*256 + j*16) ^ pk));
      uint4 zv = *(const uint4*)&zh[w*64 + j*4];
      s = fd2(pv.x, zv.x, s); s = fd2(pv.y, zv.y, s);
      s = fd2(pv.z, zv.z, s); s = fd2(pv.w, zv.w, s);
    }
    part[lane][w] = s;
    __syncthreads();                               /* A */
    float4 pp = *(const float4*)&part[lane][0];
    float l = (pp.x + pp.y + pp.z + pp.w + cdv) * SCALE;
    float mx = wredmax(l);
    float e = __expf(l - mx);
    float se = wredsum(e);
    float attv = e / se;
    float attn = dppself<0x101,0xf>(attv);         /* row_shl:1 -> lane i gets att[i+1] */
    if ((lane & 1) == 0) att4h[w][lane>>1] = pk16(attv, attn);
    asm volatile("s_waitcnt lgkmcnt(0)" ::: "memory");
    float a0 = 0.f, a1 = 0.f;
    #pragma unroll
    for (int j = 0; j < 8; j++){
      uint4 ah = *(const uint4*)&att4h[w][j*4];
      uint4 v0 = *(const uint4*)(Vl + d0*128 + ((j*16) ^ vk));
      uint4 v1 = *(const uint4*)(Vl + (d0+1)*128 + ((j*16) ^ vk));
      a0 = fd2(v0.x, ah.x, a0); a0 = fd2(v0.y, ah.y, a0);
      a0 = fd2(v0.z, ah.z, a0); a0 = fd2(v0.w, ah.w, a0);
      a1 = fd2(v1.x, ah.x, a1); a1 = fd2(v1.y, ah.y, a1);
      a1 = fd2(v1.z, ah.z, a1); a1 = fd2(v1.w, ah.w, a1);
    }
    float y0 = z0r + a0, y1 = z1r + a1;
    float s2 = y0 + y1, q2 = fmaf(y0, y0, y1*y1);
    wred2(s2, q2);
    if (lane == 0){ float2 o = {s2, q2}; red2[w] = o; }
    __syncthreads();                               /* B */
    float2 rA = red2[0], rB = red2[1], rC = red2[2], rD = red2[3];
    float Sy = rA.x+rB.x+rC.x+rD.x, Qy = rA.y+rB.y+rC.y+rD.y;
    float mean = Sy * (1.f/DD);
    float var  = fmaxf((Qy - (float)DD*mean*mean) * (1.f/(DD-1)), 0.f);
    float r = 1.f/(sqrtf(var) + EPSL);
    z0r = fmaf(g2a*r, y0-mean, b2a);
    z1r = fmaf(g2b*r, y1-mean, b2b);
    zL[d0] = z0r; zL[d0+1] = z1r;
    zh[tid] = pk16(z0r, z1r);
    __syncthreads();                               /* C */
  }
  zfin[(size_t)b*DD + d0]     = z0r;
  zfin[(size_t)b*DD + d0 + 1] = z1r;
}

/* ---------------- logits = zfin @ voc_W^T + voc_b ------------------------------- */
__global__ void __launch_bounds__(256) logits_kernel(const float* __restrict__ zfin,
    const float* __restrict__ vocW, const float* __restrict__ vocb, float* __restrict__ out){
  __shared__ float zS[NB*DD];
  int tid = threadIdx.x;
  const float4* src = (const float4*)zfin;
  float4* dst = (float4*)zS;
  #pragma unroll
  for (int i = 0; i < 16; i++) dst[tid + i*256] = src[tid + i*256];
  __syncthreads();
  int w = tid >> 6, lane = tid & 63;
  int kq = lane & 3, rp = lane >> 2;
  int r0 = blockIdx.x*128 + w*32 + rp*2, r1 = r0 + 1;
  float acc0[NB], acc1[NB];
  #pragma unroll
  for (int bq = 0; bq < NB; bq++){ acc0[bq] = 0.f; acc1[bq] = 0.f; }
  const float* w0p = vocW + (size_t)r0*DD;
  const float* w1p = vocW + (size_t)r1*DD;
  for (int ks = 0; ks < 32; ks++){
    int koff = ks*16 + kq*4;
    float4 w0 = *(const float4*)(w0p + koff);
    float4 w1 = *(const float4*)(w1p + koff);
    #pragma unroll
    for (int bq = 0; bq < NB; bq++){
      float4 z4 = *(const float4*)&zS[bq*DD + koff];
      acc0[bq] = fmaf(w0.x,z4.x, fmaf(w0.y,z4.y, fmaf(w0.z,z4.z, fmaf(w0.w,z4.w, acc0[bq]))));
      acc1[bq] = fmaf(w1.x,z4.x, fmaf(w1.y,z4.y, fmaf(w1.z,z4.z, fmaf(w1.w,z4.w, acc1[bq]))));
    }
  }
  #pragma unroll
  for (int bq = 0; bq < NB; bq++){
    acc0[bq] += dppz<0xB1,0xf>(acc0[bq]); acc0[bq] += dppz<0x4E,0xf>(acc0[bq]);
    acc1[bq] += dppz<0xB1,0xf>(acc1[bq]); acc1[bq] += dppz<0x4E,0xf>(acc1[bq]);
  }
  if (kq == 0){
    float vb0 = vocb[r0], vb1 = vocb[r1];
    #pragma unroll
    for (int bq = 0; bq < NB; bq++){
      out[(size_t)bq*VOUT + r0] = acc0[bq] + vb0;
      out[(size_t)bq*VOUT + r1] = acc1[bq] + vb1;
    }
  }
}

/* --------------------------- split log_softmax ---------------------------------- */
__global__ void __launch_bounds__(256) lsm1_kernel(const float* __restrict__ out,
    float2* __restrict__ partb){
  int b = blockIdx.x >> 3, c = blockIdx.x & 7;
  const float* row = out + (size_t)b*VOUT + c*4000;
  int tid = threadIdx.x;
  __shared__ float rm[4]; __shared__ float rs[4];
  float mx = -3.4e38f;
  for (int i = tid; i < 4000; i += 256) mx = fmaxf(mx, row[i]);
  mx = wredmax(mx);
  if ((tid & 63) == 0) rm[tid>>6] = mx;
  __syncthreads();
  mx = fmaxf(fmaxf(rm[0],rm[1]), fmaxf(rm[2],rm[3]));
  float sm = 0.f;
  for (int i = tid; i < 4000; i += 256) sm += __expf(row[i] - mx);
  sm = wredsum(sm);
  if ((tid & 63) == 0) rs[tid>>6] = sm;
  __syncthreads();
  if (tid == 0){ float2 o = {mx, rs[0]+rs[1]+rs[2]+rs[3]}; partb[blockIdx.x] = o; }
}
__global__ void __launch_bounds__(256) lsm2_kernel(float* __restrict__ out,
    const float2* __restrict__ partb){
  int b = blockIdx.x >> 3, c = blockIdx.x & 7;
  float M = -3.4e38f, S = 0.f;
  #pragma unroll
  for (int j = 0; j < 8; j++) M = fmaxf(M, partb[b*8+j].x);
  #pragma unroll
  for (int j = 0; j < 8; j++){ float2 p = partb[b*8+j]; S += p.y * __expf(p.x - M); }
  float cns = M + logf(S);
  float* row = out + (size_t)b*VOUT + c*4000;
  for (int i = threadIdx.x; i < 4000; i += 256) row[i] -= cns;
}

extern "C" void kernel_launch(void* const* d_in, const int* in_sizes, int n_in,
                              void* d_out, int out_size, void* d_ws, size_t ws_size,
                              hipStream_t stream){
  (void)in_sizes; (void)n_in; (void)out_size; (void)ws_size;
  const int*   toks      = (const int*)  d_in[0];
  const float* emb_in    = (const float*)d_in[2];
  const float* enc_key_W = (const float*)d_in[4];
  const float* enc_Wq    = (const float*)d_in[5];
  const float* enc_bq    = (const float*)d_in[6];
  const float* enc_Wk    = (const float*)d_in[7];
  const float* enc_bk    = (const float*)d_in[8];
  const float* n1g       = (const float*)d_in[9];
  const float* n1b       = (const float*)d_in[10];
  const float* rdr_Wq    = (const float*)d_in[12];
  const float* rdr_bq    = (const float*)d_in[13];
  const float* rdr_Wk    = (const float*)d_in[14];
  const float* rdr_bk    = (const float*)d_in[15];
  const float* rdr_Wv    = (const float*)d_in[16];
  const float* rdr_bv    = (const float*)d_in[17];
  const float* n2g       = (const float*)d_in[22];
  const float* n2b       = (const float*)d_in[23];
  const float* vocW      = (const float*)d_in[26];
  const float* vocb      = (const float*)d_in[27];
  float* outp = (float*)d_out;

  float* ws = (float*)d_ws;
  size_t off = 0;
  float* Z    = ws + off; off += (size_t)NB*SENC*DD;      /* 64 MB */
  float* ZSQ  = ws + off; off += (size_t)NB*SENC*2;
  float* av   = ws + off; off += (size_t)NB*AA*DD;
  /* gates [B*SENC][AA] f32 (8MB) aliases Kr+P16+V16 (all written after avscan) */
  float* Kr   = ws + off; float* gates = Kr; off += (size_t)NB*AA*DD;
  unsigned int* P16 = (unsigned int*)(ws + off); off += (size_t)NB*AA*DD/2;
  unsigned int* V16 = (unsigned int*)(ws + off); off += (size_t)NB*AA*DD/2;
  float* Qa   = ws + off; off += (size_t)AA*DD;
  float* Menc = ws + off; off += (size_t)AA*DD;
  float* cenc = ws + off; off += AA;
  float* cdec = ws + off; off += (size_t)NB*AA;
  float* zfin = ws + off; off += (size_t)NB*DD;
  float2* lsp = (float2*)(ws + off); off += 512;
  int*  flag  = (int*)(ws + off); off += 1;

  qa_kernel    <<<AA, 512, 0, stream>>>(enc_key_W, enc_Wq, enc_bq, Qa);
  menc_kernel  <<<AA, 512, 0, stream>>>(Qa, enc_Wk, Menc);
  dotb_kernel  <<<AA/4, 256, 0, stream>>>(Qa, enc_bk, cenc);
  flag_kernel  <<<1, 512, 0, stream>>>(n1g, n1b, flag);
  zscan_kernel <<<NB, 64, 0, stream>>>(toks, emb_in, n1g, n1b, Z);
  zstats_kernel<<<NB*SENC/4, 256, 0, stream>>>(Z, ZSQ);
  gates_kernel <<<NB*SENC/64, 256, 0, stream>>>(Z, Menc, cenc, gates);
  avscan_kernel<<<256, 512, 0, stream>>>(Z, ZSQ, gates, n1g, n1b, flag, av);
  gemm_nt_kernel<<<dim3(NB*AA/64, DD/64), 256, 0, stream>>>(av, rdr_Wk, rdr_bk, Kr, 0);
  gemm_nn_kernel<<<dim3(NB*AA/64, DD/64), 256, 0, stream>>>(Kr, rdr_Wq, P16);
  gemm_nt_kernel<<<dim3(NB*AA/64, DD/64), 256, 0, stream>>>(av, rdr_Wv, rdr_bv, V16, 1);
  dotb_kernel  <<<NB*AA/4, 256, 0, stream>>>(Kr, rdr_bq, cdec);
  dec_kernel   <<<NB, 256, 0, stream>>>(Z, P16, V16, cdec, n2g, n2b, zfin);
  logits_kernel<<<VOUT/128, 256, 0, stream>>>(zfin, vocW, vocb, outp);
  lsm1_kernel  <<<NB*8, 256, 0, stream>>>(outp, lsp);
  lsm2_kernel  <<<NB*8, 256, 0, stream>>>(outp, lsp);
}

// Round 5
// 1470.011 us; speedup vs baseline: 1.8038x; 1.1318x over previous
//
#include <hip/hip_runtime.h>
#include <math.h>

#define DD 512
#define AA 64
#define NB 32
#define SENC 1024
#define SDEC 256
#define VOUT 32000
#define EPSL 1e-6f
#define SCALE 0.044194173824159216f   /* 1/sqrt(512) */
#define SQRTD 22.627416997969522f     /* sqrt(512) */

typedef _Float16 h2 __attribute__((ext_vector_type(2)));

/* ---------------- DPP wave reduction helpers (VALU-only) ----------------------- */
template<int C, int R>
__device__ __forceinline__ float dppz(float v){   /* old=0, bound_ctrl=1 */
  return __int_as_float(__builtin_amdgcn_update_dpp(0, __float_as_int(v), C, R, 0xf, true));
}
template<int C, int R>
__device__ __forceinline__ float dppself(float v){ /* old=self, bound_ctrl=0 */
  return __int_as_float(__builtin_amdgcn_update_dpp(__float_as_int(v), __float_as_int(v), C, R, 0xf, false));
}
__device__ __forceinline__ float rlane63(float v){
  return __int_as_float(__builtin_amdgcn_readlane(__float_as_int(v), 63));
}
__device__ __forceinline__ void wred2(float &a, float &b){
  a += dppz<0x111,0xf>(a); b += dppz<0x111,0xf>(b);
  a += dppz<0x112,0xf>(a); b += dppz<0x112,0xf>(b);
  a += dppz<0x114,0xf>(a); b += dppz<0x114,0xf>(b);
  a += dppz<0x118,0xf>(a); b += dppz<0x118,0xf>(b);
  a += dppz<0x142,0xa>(a); b += dppz<0x142,0xa>(b);
  a += dppz<0x143,0xc>(a); b += dppz<0x143,0xc>(b);
  a = rlane63(a); b = rlane63(b);
}
__device__ __forceinline__ float wredsum(float a){
  a += dppz<0x111,0xf>(a); a += dppz<0x112,0xf>(a);
  a += dppz<0x114,0xf>(a); a += dppz<0x118,0xf>(a);
  a += dppz<0x142,0xa>(a); a += dppz<0x143,0xc>(a);
  return rlane63(a);
}
__device__ __forceinline__ float wredmax(float a){
  a = fmaxf(a, dppself<0x111,0xf>(a));
  a = fmaxf(a, dppself<0x112,0xf>(a));
  a = fmaxf(a, dppself<0x114,0xf>(a));
  a = fmaxf(a, dppself<0x118,0xf>(a));
  a = fmaxf(a, dppself<0x142,0xa>(a));
  a = fmaxf(a, dppself<0x143,0xc>(a));
  return rlane63(a);
}
__device__ __forceinline__ unsigned int pk16(float x, float y){
  return __builtin_bit_cast(unsigned int, __builtin_amdgcn_cvt_pkrtz(x, y));
}
__device__ __forceinline__ float fd2(unsigned int a, unsigned int b, float c){
#if __has_builtin(__builtin_amdgcn_fdot2)
  return __builtin_amdgcn_fdot2(__builtin_bit_cast(h2, a), __builtin_bit_cast(h2, b), c, false);
#else
  h2 x = __builtin_bit_cast(h2, a), y = __builtin_bit_cast(h2, b);
  return c + (float)x[0]*(float)y[0] + (float)x[1]*(float)y[1];
#endif
}

/* ---------------- Qa = enc_key_W @ enc_Wq^T + enc_bq  [64,512] ---------------- */
__global__ void __launch_bounds__(512) qa_kernel(const float* __restrict__ keyW,
    const float* __restrict__ Wq, const float* __restrict__ bq, float* __restrict__ Qa){
  int a = blockIdx.x, i = threadIdx.x;
  __shared__ float key[DD];
  key[i] = keyW[a*DD + i];
  __syncthreads();
  const float4* w4 = (const float4*)(Wq + (size_t)i*DD);
  const float4* k4 = (const float4*)key;
  float s = 0.f;
  #pragma unroll 4
  for (int j = 0; j < DD/4; j++){
    float4 w = w4[j], k = k4[j];
    s = fmaf(w.x,k.x, fmaf(w.y,k.y, fmaf(w.z,k.z, fmaf(w.w,k.w, s))));
  }
  Qa[a*DD + i] = s + bq[i];
}

/* ------------- Menc = Qa @ enc_Wk  [64,512] ----------------------------------- */
__global__ void __launch_bounds__(512) menc_kernel(const float* __restrict__ Qa,
    const float* __restrict__ Wk, float* __restrict__ Menc){
  int a = blockIdx.x, j = threadIdx.x;
  __shared__ float qa[DD];
  qa[j] = Qa[a*DD + j];
  __syncthreads();
  float s = 0.f;
  #pragma unroll 4
  for (int i = 0; i < DD; i++) s = fmaf(qa[i], Wk[(size_t)i*DD + j], s);
  Menc[a*DD + j] = s;
}

/* ------------- out[m] = X[m,:] . v  (4 rows per block) ------------------------- */
__global__ void __launch_bounds__(256) dotb_kernel(const float* __restrict__ X,
    const float* __restrict__ v, float* __restrict__ out){
  int m = blockIdx.x*4 + (threadIdx.x >> 6);
  int lane = threadIdx.x & 63;
  const float4* x4 = (const float4*)(X + (size_t)m*DD + lane*8);
  const float4* v4 = (const float4*)(v + lane*8);
  float4 a = x4[0], b4 = x4[1], c = v4[0], d = v4[1];
  float s = a.x*c.x;
  s = fmaf(a.y,c.y, s); s = fmaf(a.z,c.z, s); s = fmaf(a.w,c.w, s);
  s = fmaf(b4.x,d.x, s); s = fmaf(b4.y,d.y, s); s = fmaf(b4.z,d.z, s); s = fmaf(b4.w,d.w, s);
  s = wredsum(s);
  if (lane == 0) out[m] = s;
}

/* ------------- flag = all(n1g==1) && all(n1b==0) ------------------------------- */
__global__ void __launch_bounds__(512) flag_kernel(const float* __restrict__ g,
    const float* __restrict__ b, int* __restrict__ flag){
  __shared__ int s;
  if (threadIdx.x == 0) s = 1;
  __syncthreads();
  bool ok = (g[threadIdx.x] == 1.0f) && (b[threadIdx.x] == 0.0f);
  if (!ok) atomicAnd(&s, 0);
  __syncthreads();
  if (threadIdx.x == 0) flag[0] = s;
}

/* -------- X[b,t,:] = emb[tok[b,t],:] * sqrtD  (pre-gather, fully parallel) ------ */
__global__ void __launch_bounds__(256) xgather_kernel(const int* __restrict__ toks,
    const float* __restrict__ emb, float* __restrict__ X){
  int row = blockIdx.x*4 + (threadIdx.x >> 6);
  int lane = threadIdx.x & 63;
  int tok = toks[row];
  const float4* src = (const float4*)(emb + (size_t)tok*DD + lane*8);
  float4 a = src[0], b = src[1];
  a.x*=SQRTD; a.y*=SQRTD; a.z*=SQRTD; a.w*=SQRTD;
  b.x*=SQRTD; b.y*=SQRTD; b.z*=SQRTD; b.w*=SQRTD;
  float4* dst = (float4*)(X + (size_t)row*DD + lane*8);
  dst[0] = a; dst[1] = b;
}

/* --------- encoder z-scan: in-place X -> Z, 4-deep prefetch, fused ZSQ ---------- */
template<bool FAST>
__device__ __forceinline__ void zscan_body(float* __restrict__ XZ,
    const float* __restrict__ n1g, const float* __restrict__ n1b,
    float* __restrict__ ZSQ){
  int b = blockIdx.x, lane = threadIdx.x;
  int bd = lane*8;
  float z[8], g1[8], b1[8];
  #pragma unroll
  for (int k = 0; k < 8; k++) z[k] = 0.f;
  if (!FAST){
    *(float4*)&g1[0] = *(const float4*)(n1g+bd); *(float4*)&g1[4] = *(const float4*)(n1g+bd+4);
    *(float4*)&b1[0] = *(const float4*)(n1b+bd); *(float4*)&b1[4] = *(const float4*)(n1b+bd+4);
  }
  float* xp = XZ + (size_t)b*SENC*DD + bd;
  float2* sqp = (float2*)ZSQ + (size_t)b*SENC;
  float4 xa0 = *(const float4*)(xp         ), xb0 = *(const float4*)(xp          + 4);
  float4 xa1 = *(const float4*)(xp +   DD  ), xb1 = *(const float4*)(xp +   DD   + 4);
  float4 xa2 = *(const float4*)(xp + 2*DD  ), xb2 = *(const float4*)(xp + 2*DD   + 4);
  float4 xa3 = *(const float4*)(xp + 3*DD  ), xb3 = *(const float4*)(xp + 3*DD   + 4);
  for (int t = 0; t < SENC; t += 4){
#define ZSTEP(XA, XB, OFS, PFO, TI) {                                              \
    float y0=z[0]+XA.x, y1=z[1]+XA.y, y2=z[2]+XA.z, y3=z[3]+XA.w;                  \
    float y4=z[4]+XB.x, y5=z[5]+XB.y, y6=z[6]+XB.z, y7=z[7]+XB.w;                  \
    float s = ((y0+y1)+(y2+y3)) + ((y4+y5)+(y6+y7));                               \
    float qa = fmaf(y1,y1, y0*y0), qb = fmaf(y3,y3, y2*y2);                        \
    float qc = fmaf(y5,y5, y4*y4), qd = fmaf(y7,y7, y6*y6);                        \
    float q = (qa+qb)+(qc+qd);                                                     \
    wred2(s, q);                                                                   \
    float mean = s * (1.f/DD);                                                     \
    float qc2  = fmaf(-(float)DD*mean, mean, q);                                   \
    float var  = fmaxf(qc2 * (1.f/(DD-1)), 0.f);                                   \
    float r = 1.f/(sqrtf(var) + EPSL);                                             \
    if (FAST){                                                                     \
      float mr = mean*r;                                                           \
      z[0]=fmaf(y0,r,-mr); z[1]=fmaf(y1,r,-mr); z[2]=fmaf(y2,r,-mr);               \
      z[3]=fmaf(y3,r,-mr); z[4]=fmaf(y4,r,-mr); z[5]=fmaf(y5,r,-mr);               \
      z[6]=fmaf(y6,r,-mr); z[7]=fmaf(y7,r,-mr);                                    \
      if (lane == 0){ float2 o = {0.f, qc2*r*r}; sqp[TI] = o; }                    \
    } else {                                                                       \
      z[0]=fmaf(g1[0]*r, y0-mean, b1[0]); z[1]=fmaf(g1[1]*r, y1-mean, b1[1]);      \
      z[2]=fmaf(g1[2]*r, y2-mean, b1[2]); z[3]=fmaf(g1[3]*r, y3-mean, b1[3]);      \
      z[4]=fmaf(g1[4]*r, y4-mean, b1[4]); z[5]=fmaf(g1[5]*r, y5-mean, b1[5]);      \
      z[6]=fmaf(g1[6]*r, y6-mean, b1[6]); z[7]=fmaf(g1[7]*r, y7-mean, b1[7]);      \
      float sz = ((z[0]+z[1])+(z[2]+z[3])) + ((z[4]+z[5])+(z[6]+z[7]));            \
      float za_ = fmaf(z[1],z[1], z[0]*z[0]), zb_ = fmaf(z[3],z[3], z[2]*z[2]);    \
      float zc_ = fmaf(z[5],z[5], z[4]*z[4]), zd_ = fmaf(z[7],z[7], z[6]*z[6]);    \
      float qz = (za_+zb_)+(zc_+zd_);                                              \
      wred2(sz, qz);                                                               \
      if (lane == 0){ float2 o = {sz, qz}; sqp[TI] = o; }                          \
    }                                                                              \
    float4 o1 = {z[0],z[1],z[2],z[3]}, o2 = {z[4],z[5],z[6],z[7]};                 \
    *(float4*)(xp + OFS) = o1; *(float4*)(xp + OFS + 4) = o2;                      \
    XA = *(const float4*)(xp + PFO); XB = *(const float4*)(xp + PFO + 4); }
    ZSTEP(xa0, xb0, 0,    4*DD, 0)
    ZSTEP(xa1, xb1, DD,   5*DD, 1)
    ZSTEP(xa2, xb2, 2*DD, 6*DD, 2)
    ZSTEP(xa3, xb3, 3*DD, 7*DD, 3)
#undef ZSTEP
    xp += 4*DD; sqp += 4;
  }
}

__global__ void __launch_bounds__(64) zscan_kernel(float* __restrict__ XZ,
    const float* __restrict__ n1g, const float* __restrict__ n1b,
    const int* __restrict__ flag, float* __restrict__ ZSQ){
  if (flag[0]) zscan_body<true >(XZ, n1g, n1b, ZSQ);
  else         zscan_body<false>(XZ, n1g, n1b, ZSQ);
}

/* -------- gates[bt][a] = sigmoid((Z[bt,:].Menc[a,:] + cenc[a])*SCALE) ----------- */
__global__ void __launch_bounds__(256) gates_kernel(const float* __restrict__ Zin,
    const float* __restrict__ Menc, const float* __restrict__ cenc,
    float* __restrict__ gates){
  __shared__ float As[32][64];
  __shared__ float Bs[32][64];
  int tid = threadIdx.x;
  int m0 = blockIdx.x*64;
  int ty = tid >> 4, tx = tid & 15;
  float acc[4][4] = {{0.f}};
  for (int k0 = 0; k0 < 512; k0 += 32){
    #pragma unroll
    for (int p = 0; p < 2; p++){
      int row = (tid>>3) + p*32, col = (tid&7)*4;
      float4 va = *(const float4*)(Zin + (size_t)(m0+row)*512 + k0 + col);
      As[col][row]=va.x; As[col+1][row]=va.y; As[col+2][row]=va.z; As[col+3][row]=va.w;
      float4 vb = *(const float4*)(Menc + (size_t)row*512 + k0 + col);
      Bs[col][row]=vb.x; Bs[col+1][row]=vb.y; Bs[col+2][row]=vb.z; Bs[col+3][row]=vb.w;
    }
    __syncthreads();
    #pragma unroll
    for (int kk = 0; kk < 32; kk++){
      float4 a4 = *(const float4*)&As[kk][ty*4];
      float4 b4 = *(const float4*)&Bs[kk][tx*4];
      float au[4] = {a4.x,a4.y,a4.z,a4.w}, bv[4] = {b4.x,b4.y,b4.z,b4.w};
      #pragma unroll
      for (int u = 0; u < 4; u++)
        #pragma unroll
        for (int v = 0; v < 4; v++) acc[u][v] = fmaf(au[u], bv[v], acc[u][v]);
    }
    __syncthreads();
  }
  float cv[4];
  #pragma unroll
  for (int v = 0; v < 4; v++) cv[v] = cenc[tx*4 + v];
  #pragma unroll
  for (int u = 0; u < 4; u++){
    float4 st;
    st.x = 1.f/(1.f + __expf(-(acc[u][0]+cv[0])*SCALE));
    st.y = 1.f/(1.f + __expf(-(acc[u][1]+cv[1])*SCALE));
    st.z = 1.f/(1.f + __expf(-(acc[u][2]+cv[2])*SCALE));
    st.w = 1.f/(1.f + __expf(-(acc[u][3]+cv[3])*SCALE));
    *(float4*)(gates + (size_t)(m0+ty*4+u)*AA + tx*4) = st;
  }
}

/* ---- encoder av-scan: gates precomputed; FAST path uses analytic LN stats ------ */
template<bool FAST>
__device__ __forceinline__ void avscan_body(const float* __restrict__ Z,
    const float* __restrict__ ZSQ, const float* __restrict__ gates,
    const float* __restrict__ n1g, const float* __restrict__ n1b,
    float* __restrict__ avout){
  int bx = blockIdx.x;
  int b = (bx & 7)*4 + ((bx >> 3) & 3);          /* all blocks of batch b on one XCD */
  int a = ((bx >> 5)<<3) + (threadIdx.x >> 6);
  int lane = threadIdx.x & 63;
  int bd = lane*8;
  float g1[8], b1[8], av[8];
  if (!FAST){
    *(float4*)&g1[0] = *(const float4*)(n1g+bd); *(float4*)&g1[4] = *(const float4*)(n1g+bd+4);
    *(float4*)&b1[0] = *(const float4*)(n1b+bd); *(float4*)&b1[4] = *(const float4*)(n1b+bd+4);
  }
  #pragma unroll
  for (int k = 0; k < 8; k++) av[k] = 0.f;
  float Sav = 0.f, Qav = 0.f;
  const float*  zp = Z + (size_t)b*SENC*DD + bd;
  const float2* sp = (const float2*)ZSQ + (size_t)b*SENC;
  const float*  gp = gates + (size_t)b*SENC*AA + a;
  float4 za = *(const float4*)zp, zb = *(const float4*)(zp + 4);
  float2 sq = *sp;
  float  gt = *gp;
  for (int t = 0; t < SENC; t++){
    float z[8] = {za.x,za.y,za.z,za.w,zb.x,zb.y,zb.z,zb.w};
    float Szt = sq.x, Qzt = sq.y, g = gt;
    if (t + 1 < SENC){                              /* uniform branch: prefetch */
      zp += DD; sp += 1; gp += AA;
      za = *(const float4*)zp; zb = *(const float4*)(zp + 4);
      sq = *sp; gt = *gp;
    }
    float cav = 0.f;
    #pragma unroll
    for (int k = 0; k < 8; k++) cav = fmaf(av[k], z[k], cav);
    cav = wredsum(cav);
    float omg = 1.f - g;
    float Sy = fmaf(g, Szt - Sav, Sav);
    float Qy = omg*omg*Qav + 2.f*g*omg*cav + g*g*Qzt;
    float mean = Sy * (1.f/DD);
    float var  = fmaxf((Qy - (float)DD*mean*mean) * (1.f/(DD-1)), 0.f);
    float r = 1.f/(sqrtf(var) + EPSL);
    if (FAST){
      #pragma unroll
      for (int k = 0; k < 8; k++){
        float y = fmaf(g, z[k]-av[k], av[k]);
        av[k] = (y - mean) * r;
      }
      Sav = 0.f;
      Qav = (float)(DD-1) * var * r * r;            /* analytic: exact closure for g1=1,b1=0 */
    } else {
      float sn = 0.f, qn = 0.f;
      #pragma unroll
      for (int k = 0; k < 8; k++){
        float y = fmaf(g, z[k]-av[k], av[k]);
        float nv = fmaf(g1[k]*r, y-mean, b1[k]);
        av[k] = nv; sn += nv; qn = fmaf(nv, nv, qn);
      }
      wred2(sn, qn);
      Sav = sn; Qav = qn;
    }
  }
  float* o = avout + ((size_t)(b*AA + a))*DD + bd;
  float4 o1 = {av[0],av[1],av[2],av[3]}, o2 = {av[4],av[5],av[6],av[7]};
  *(float4*)o = o1; *(float4*)(o+4) = o2;
}

__global__ void __launch_bounds__(512) avscan_kernel(const float* __restrict__ Z,
    const float* __restrict__ ZSQ, const float* __restrict__ gates,
    const float* __restrict__ n1g, const float* __restrict__ n1b,
    const int* __restrict__ flag, float* __restrict__ avout){
  if (flag[0]) avscan_body<true >(Z, ZSQ, gates, n1g, n1b, avout);
  else         avscan_body<false>(Z, ZSQ, gates, n1g, n1b, avout);
}

/* ------------- f32 GEMM, C[m,n] = sum_k A[m,k]*Bw[n,k] (+bias[n]) --------------- */
__global__ void __launch_bounds__(256) gemm_nt_kernel(const float* __restrict__ Aa,
    const float* __restrict__ Bw, const float* __restrict__ bias,
    void* __restrict__ Cout, int mode){
  __shared__ float As[32][64];
  __shared__ float Bs[32][64];
  int tid = threadIdx.x;
  int m0 = blockIdx.x*64, n0 = blockIdx.y*64;
  int ty = tid >> 4, tx = tid & 15;
  float acc[4][4] = {{0.f}};
  for (int k0 = 0; k0 < 512; k0 += 32){
    #pragma unroll
    for (int p = 0; p < 2; p++){
      int row = (tid>>3) + p*32, col = (tid&7)*4;
      float4 va = *(const float4*)(Aa + (size_t)(m0+row)*512 + k0 + col);
      As[col][row]=va.x; As[col+1][row]=va.y; As[col+2][row]=va.z; As[col+3][row]=va.w;
      float4 vb = *(const float4*)(Bw + (size_t)(n0+row)*512 + k0 + col);
      Bs[col][row]=vb.x; Bs[col+1][row]=vb.y; Bs[col+2][row]=vb.z; Bs[col+3][row]=vb.w;
    }
    __syncthreads();
    #pragma unroll
    for (int kk = 0; kk < 32; kk++){
      float4 a4 = *(const float4*)&As[kk][ty*4];
      float4 b4 = *(const float4*)&Bs[kk][tx*4];
      float au[4] = {a4.x,a4.y,a4.z,a4.w}, bv[4] = {b4.x,b4.y,b4.z,b4.w};
      #pragma unroll
      for (int u = 0; u < 4; u++)
        #pragma unroll
        for (int v = 0; v < 4; v++) acc[u][v] = fmaf(au[u], bv[v], acc[u][v]);
    }
    __syncthreads();
  }
  float bv4[4];
  #pragma unroll
  for (int v = 0; v < 4; v++) bv4[v] = bias ? bias[n0 + tx*4 + v] : 0.f;
  if (mode == 0){
    float* C = (float*)Cout;
    #pragma unroll
    for (int u = 0; u < 4; u++){
      float4 st = {acc[u][0]+bv4[0], acc[u][1]+bv4[1], acc[u][2]+bv4[2], acc[u][3]+bv4[3]};
      *(float4*)(C + (size_t)(m0+ty*4+u)*512 + n0 + tx*4) = st;
    }
  } else {
    unsigned short* C = (unsigned short*)Cout;
    #pragma unroll
    for (int u = 0; u < 4; u++){
      int mm = m0 + ty*4 + u; int bb = mm >> 6, a2 = mm & 63;
      #pragma unroll
      for (int v = 0; v < 4; v++){
        _Float16 hv = (_Float16)(acc[u][v] + bv4[v]);
        C[((size_t)bb*512 + n0 + tx*4 + v)*64 + a2] = __builtin_bit_cast(unsigned short, hv);
      }
    }
  }
}

/* ------------- P16[m][n] (f16) = sum_k A[m,k]*B[k,n] --------------------------- */
__global__ void __launch_bounds__(256) gemm_nn_kernel(const float* __restrict__ Aa,
    const float* __restrict__ Bw, unsigned int* __restrict__ Cout){
  __shared__ float As[32][64];
  __shared__ float Bs[32][64];
  int tid = threadIdx.x;
  int m0 = blockIdx.x*64, n0 = blockIdx.y*64;
  int ty = tid >> 4, tx = tid & 15;
  float acc[4][4] = {{0.f}};
  for (int k0 = 0; k0 < 512; k0 += 32){
    #pragma unroll
    for (int p = 0; p < 2; p++){
      int row = (tid>>3) + p*32, col = (tid&7)*4;
      float4 va = *(const float4*)(Aa + (size_t)(m0+row)*512 + k0 + col);
      As[col][row]=va.x; As[col+1][row]=va.y; As[col+2][row]=va.z; As[col+3][row]=va.w;
      int brow = (tid>>4) + p*16, bcol = (tid&15)*4;
      float4 vb = *(const float4*)(Bw + (size_t)(k0+brow)*512 + n0 + bcol);
      *(float4*)&Bs[brow][bcol] = vb;
    }
    __syncthreads();
    #pragma unroll
    for (int kk = 0; kk < 32; kk++){
      float4 a4 = *(const float4*)&As[kk][ty*4];
      float4 b4 = *(const float4*)&Bs[kk][tx*4];
      float au[4] = {a4.x,a4.y,a4.z,a4.w}, bv[4] = {b4.x,b4.y,b4.z,b4.w};
      #pragma unroll
      for (int u = 0; u < 4; u++)
        #pragma unroll
        for (int v = 0; v < 4; v++) acc[u][v] = fmaf(au[u], bv[v], acc[u][v]);
    }
    __syncthreads();
  }
  #pragma unroll
  for (int u = 0; u < 4; u++){
    uint2 st = { pk16(acc[u][0], acc[u][1]), pk16(acc[u][2], acc[u][3]) };
    *(uint2*)(Cout + (size_t)(m0+ty*4+u)*256 + (n0 + tx*4)/2) = st;
  }
}

/* ------------------------------- decoder scan ----------------------------------- */
__global__ void __launch_bounds__(256) dec_kernel(const float* __restrict__ Z,
    const unsigned int* __restrict__ Pg, const unsigned int* __restrict__ Vg,
    const float* __restrict__ cdec, const float* __restrict__ n2g,
    const float* __restrict__ n2b, float* __restrict__ zfin){
  __shared__ __align__(16) unsigned char Pl[65536];
  __shared__ __align__(16) unsigned char Vl[65536];
  __shared__ float zL[DD];
  __shared__ unsigned int zh[256];
  __shared__ float part[AA][4];
  __shared__ unsigned int att4h[4][32];
  __shared__ float2 red2[4];
  int b = blockIdx.x, tid = threadIdx.x;
  int lane = tid & 63, w = tid >> 6;

  const uint4* Pg4 = (const uint4*)(Pg + (size_t)b*16384);
  #pragma unroll
  for (int j = 0; j < 16; j++){
    int fb = j*1024 + tid*4;
    uint4 v = Pg4[j*256 + tid];
    int a = fb >> 8;
    int off = (fb & 255) * 4;
    *(uint4*)(Pl + a*1024 + (off ^ ((a&7)<<4))) = v;
  }
  const uint4* Vg4 = (const uint4*)(Vg + (size_t)b*16384);
  #pragma unroll
  for (int j = 0; j < 16; j++){
    int fb = j*1024 + tid*4;
    uint4 v = Vg4[j*256 + tid];
    int d = fb >> 5;
    int off = (fb & 31) * 4;
    *(uint4*)(Vl + d*128 + (off ^ (((d>>1)&7)<<4))) = v;
  }
  zL[tid]       = Z[((size_t)b*SENC + SENC-1)*DD + tid];
  zL[tid + 256] = Z[((size_t)b*SENC + SENC-1)*DD + tid + 256];
  float cdv = cdec[b*AA + lane];
  int d0 = tid*2;
  float g2a = n2g[d0], g2b = n2g[d0+1], b2a = n2b[d0], b2b = n2b[d0+1];
  int pk = (lane&7)<<4;
  int vk = (tid&7)<<4;
  __syncthreads();
  zh[tid] = pk16(zL[2*tid], zL[2*tid+1]);
  __syncthreads();

  float z0r = zL[d0], z1r = zL[d0+1];
  for (int t = 0; t < SDEC; t++){
    float s = 0.f;
    #pragma unroll
    for (int j = 0; j < 16; j++){
      uint4 pv = *(const uint4*)(Pl + lane*1024 + ((w*256 + j*16) ^ pk));
      uint4 zv = *(const uint4*)&zh[w*64 + j*4];
      s = fd2(pv.x, zv.x, s); s = fd2(pv.y, zv.y, s);
      s = fd2(pv.z, zv.z, s); s = fd2(pv.w, zv.w, s);
    }
    part[lane][w] = s;
    __syncthreads();                               /* A */
    float4 pp = *(const float4*)&part[lane][0];
    float l = (pp.x + pp.y + pp.z + pp.w + cdv) * SCALE;
    float mx = wredmax(l);
    float e = __expf(l - mx);
    float se = wredsum(e);
    float attv = e / se;
    float attn = dppself<0x101,0xf>(attv);         /* row_shl:1 -> lane i gets att[i+1] */
    if ((lane & 1) == 0) att4h[w][lane>>1] = pk16(attv, attn);
    asm volatile("s_waitcnt lgkmcnt(0)" ::: "memory");
    float a0 = 0.f, a1 = 0.f;
    #pragma unroll
    for (int j = 0; j < 8; j++){
      uint4 ah = *(const uint4*)&att4h[w][j*4];
      uint4 v0 = *(const uint4*)(Vl + d0*128 + ((j*16) ^ vk));
      uint4 v1 = *(const uint4*)(Vl + (d0+1)*128 + ((j*16) ^ vk));
      a0 = fd2(v0.x, ah.x, a0); a0 = fd2(v0.y, ah.y, a0);
      a0 = fd2(v0.z, ah.z, a0); a0 = fd2(v0.w, ah.w, a0);
      a1 = fd2(v1.x, ah.x, a1); a1 = fd2(v1.y, ah.y, a1);
      a1 = fd2(v1.z, ah.z, a1); a1 = fd2(v1.w, ah.w, a1);
    }
    float y0 = z0r + a0, y1 = z1r + a1;
    float s2 = y0 + y1, q2 = fmaf(y0, y0, y1*y1);
    wred2(s2, q2);
    if (lane == 0){ float2 o = {s2, q2}; red2[w] = o; }
    __syncthreads();                               /* B */
    float2 rA = red2[0], rB = red2[1], rC = red2[2], rD = red2[3];
    float Sy = rA.x+rB.x+rC.x+rD.x, Qy = rA.y+rB.y+rC.y+rD.y;
    float mean = Sy * (1.f/DD);
    float var  = fmaxf((Qy - (float)DD*mean*mean) * (1.f/(DD-1)), 0.f);
    float r = 1.f/(sqrtf(var) + EPSL);
    z0r = fmaf(g2a*r, y0-mean, b2a);
    z1r = fmaf(g2b*r, y1-mean, b2b);
    zL[d0] = z0r; zL[d0+1] = z1r;
    zh[tid] = pk16(z0r, z1r);
    __syncthreads();                               /* C */
  }
  zfin[(size_t)b*DD + d0]     = z0r;
  zfin[(size_t)b*DD + d0 + 1] = z1r;
}

/* ---------------- logits = zfin @ voc_W^T + voc_b ------------------------------- */
__global__ void __launch_bounds__(256) logits_kernel(const float* __restrict__ zfin,
    const float* __restrict__ vocW, const float* __restrict__ vocb, float* __restrict__ out){
  __shared__ float zS[NB*DD];
  int tid = threadIdx.x;
  const float4* src = (const float4*)zfin;
  float4* dst = (float4*)zS;
  #pragma unroll
  for (int i = 0; i < 16; i++) dst[tid + i*256] = src[tid + i*256];
  __syncthreads();
  int w = tid >> 6, lane = tid & 63;
  int kq = lane & 3, rp = lane >> 2;
  int r0 = blockIdx.x*128 + w*32 + rp*2, r1 = r0 + 1;
  float acc0[NB], acc1[NB];
  #pragma unroll
  for (int bq = 0; bq < NB; bq++){ acc0[bq] = 0.f; acc1[bq] = 0.f; }
  const float* w0p = vocW + (size_t)r0*DD;
  const float* w1p = vocW + (size_t)r1*DD;
  for (int ks = 0; ks < 32; ks++){
    int koff = ks*16 + kq*4;
    float4 w0 = *(const float4*)(w0p + koff);
    float4 w1 = *(const float4*)(w1p + koff);
    #pragma unroll
    for (int bq = 0; bq < NB; bq++){
      float4 z4 = *(const float4*)&zS[bq*DD + koff];
      acc0[bq] = fmaf(w0.x,z4.x, fmaf(w0.y,z4.y, fmaf(w0.z,z4.z, fmaf(w0.w,z4.w, acc0[bq]))));
      acc1[bq] = fmaf(w1.x,z4.x, fmaf(w1.y,z4.y, fmaf(w1.z,z4.z, fmaf(w1.w,z4.w, acc1[bq]))));
    }
  }
  #pragma unroll
  for (int bq = 0; bq < NB; bq++){
    acc0[bq] += dppz<0xB1,0xf>(acc0[bq]); acc0[bq] += dppz<0x4E,0xf>(acc0[bq]);
    acc1[bq] += dppz<0xB1,0xf>(acc1[bq]); acc1[bq] += dppz<0x4E,0xf>(acc1[bq]);
  }
  if (kq == 0){
    float vb0 = vocb[r0], vb1 = vocb[r1];
    #pragma unroll
    for (int bq = 0; bq < NB; bq++){
      out[(size_t)bq*VOUT + r0] = acc0[bq] + vb0;
      out[(size_t)bq*VOUT + r1] = acc1[bq] + vb1;
    }
  }
}

/* --------------------------- split log_softmax ---------------------------------- */
__global__ void __launch_bounds__(256) lsm1_kernel(const float* __restrict__ out,
    float2* __restrict__ partb){
  int b = blockIdx.x >> 3, c = blockIdx.x & 7;
  const float* row = out + (size_t)b*VOUT + c*4000;
  int tid = threadIdx.x;
  __shared__ float rm[4]; __shared__ float rs[4];
  float mx = -3.4e38f;
  for (int i = tid; i < 4000; i += 256) mx = fmaxf(mx, row[i]);
  mx = wredmax(mx);
  if ((tid & 63) == 0) rm[tid>>6] = mx;
  __syncthreads();
  mx = fmaxf(fmaxf(rm[0],rm[1]), fmaxf(rm[2],rm[3]));
  float sm = 0.f;
  for (int i = tid; i < 4000; i += 256) sm += __expf(row[i] - mx);
  sm = wredsum(sm);
  if ((tid & 63) == 0) rs[tid>>6] = sm;
  __syncthreads();
  if (tid == 0){ float2 o = {mx, rs[0]+rs[1]+rs[2]+rs[3]}; partb[blockIdx.x] = o; }
}
__global__ void __launch_bounds__(256) lsm2_kernel(float* __restrict__ out,
    const float2* __restrict__ partb){
  int b = blockIdx.x >> 3, c = blockIdx.x & 7;
  float M = -3.4e38f, S = 0.f;
  #pragma unroll
  for (int j = 0; j < 8; j++) M = fmaxf(M, partb[b*8+j].x);
  #pragma unroll
  for (int j = 0; j < 8; j++){ float2 p = partb[b*8+j]; S += p.y * __expf(p.x - M); }
  float cns = M + logf(S);
  float* row = out + (size_t)b*VOUT + c*4000;
  for (int i = threadIdx.x; i < 4000; i += 256) row[i] -= cns;
}

extern "C" void kernel_launch(void* const* d_in, const int* in_sizes, int n_in,
                              void* d_out, int out_size, void* d_ws, size_t ws_size,
                              hipStream_t stream){
  (void)in_sizes; (void)n_in; (void)out_size; (void)ws_size;
  const int*   toks      = (const int*)  d_in[0];
  const float* emb_in    = (const float*)d_in[2];
  const float* enc_key_W = (const float*)d_in[4];
  const float* enc_Wq    = (const float*)d_in[5];
  const float* enc_bq    = (const float*)d_in[6];
  const float* enc_Wk    = (const float*)d_in[7];
  const float* enc_bk    = (const float*)d_in[8];
  const float* n1g       = (const float*)d_in[9];
  const float* n1b       = (const float*)d_in[10];
  const float* rdr_Wq    = (const float*)d_in[12];
  const float* rdr_bq    = (const float*)d_in[13];
  const float* rdr_Wk    = (const float*)d_in[14];
  const float* rdr_bk    = (const float*)d_in[15];
  const float* rdr_Wv    = (const float*)d_in[16];
  const float* rdr_bv    = (const float*)d_in[17];
  const float* n2g       = (const float*)d_in[22];
  const float* n2b       = (const float*)d_in[23];
  const float* vocW      = (const float*)d_in[26];
  const float* vocb      = (const float*)d_in[27];
  float* outp = (float*)d_out;

  float* ws = (float*)d_ws;
  size_t off = 0;
  float* Z    = ws + off; off += (size_t)NB*SENC*DD + 4*DD;  /* X/Z in place + slack */
  float* ZSQ  = ws + off; off += (size_t)NB*SENC*2;
  float* av   = ws + off; off += (size_t)NB*AA*DD;
  /* gates [B*SENC][AA] f32 (8MB) aliases Kr+P16+V16 (all written after avscan) */
  float* Kr   = ws + off; float* gates = Kr; off += (size_t)NB*AA*DD;
  unsigned int* P16 = (unsigned int*)(ws + off); off += (size_t)NB*AA*DD/2;
  unsigned int* V16 = (unsigned int*)(ws + off); off += (size_t)NB*AA*DD/2;
  float* Qa   = ws + off; off += (size_t)AA*DD;
  float* Menc = ws + off; off += (size_t)AA*DD;
  float* cenc = ws + off; off += AA;
  float* cdec = ws + off; off += (size_t)NB*AA;
  float* zfin = ws + off; off += (size_t)NB*DD;
  float2* lsp = (float2*)(ws + off); off += 512;
  int*  flag  = (int*)(ws + off); off += 1;

  qa_kernel     <<<AA, 512, 0, stream>>>(enc_key_W, enc_Wq, enc_bq, Qa);
  menc_kernel   <<<AA, 512, 0, stream>>>(Qa, enc_Wk, Menc);
  dotb_kernel   <<<AA/4, 256, 0, stream>>>(Qa, enc_bk, cenc);
  flag_kernel   <<<1, 512, 0, stream>>>(n1g, n1b, flag);
  xgather_kernel<<<NB*SENC/4, 256, 0, stream>>>(toks, emb_in, Z);
  zscan_kernel  <<<NB, 64, 0, stream>>>(Z, n1g, n1b, flag, ZSQ);
  gates_kernel  <<<NB*SENC/64, 256, 0, stream>>>(Z, Menc, cenc, gates);
  avscan_kernel <<<256, 512, 0, stream>>>(Z, ZSQ, gates, n1g, n1b, flag, av);
  gemm_nt_kernel<<<dim3(NB*AA/64, DD/64), 256, 0, stream>>>(av, rdr_Wk, rdr_bk, Kr, 0);
  gemm_nn_kernel<<<dim3(NB*AA/64, DD/64), 256, 0, stream>>>(Kr, rdr_Wq, P16);
  gemm_nt_kernel<<<dim3(NB*AA/64, DD/64), 256, 0, stream>>>(av, rdr_Wv, rdr_bv, V16, 1);
  dotb_kernel   <<<NB*AA/4, 256, 0, stream>>>(Kr, rdr_bq, cdec);
  dec_kernel    <<<NB, 256, 0, stream>>>(Z, P16, V16, cdec, n2g, n2b, zfin);
  logits_kernel <<<VOUT/128, 256, 0, stream>>>(zfin, vocW, vocb, outp);
  lsm1_kernel   <<<NB*8, 256, 0, stream>>>(outp, lsp);
  lsm2_kernel   <<<NB*8, 256, 0, stream>>>(outp, lsp);
}

// Round 6
// 1250.328 us; speedup vs baseline: 2.1208x; 1.1757x over previous
//
#include <hip/hip_runtime.h>
#include <math.h>

#define DD 512
#define AA 64
#define NB 32
#define SENC 1024
#define SDEC 256
#define VOUT 32000
#define EPSL 1e-6f
#define SCALE 0.044194173824159216f   /* 1/sqrt(512) */
#define SQRTD 22.627416997969522f     /* sqrt(512) */

typedef _Float16 h2 __attribute__((ext_vector_type(2)));
typedef float f32x2 __attribute__((ext_vector_type(2)));

/* ---------------- DPP wave reduction helpers (VALU-only) ----------------------- */
template<int C, int R>
__device__ __forceinline__ float dppz(float v){   /* old=0, bound_ctrl=1 */
  return __int_as_float(__builtin_amdgcn_update_dpp(0, __float_as_int(v), C, R, 0xf, true));
}
template<int C, int R>
__device__ __forceinline__ float dppself(float v){ /* old=self, bound_ctrl=0 */
  return __int_as_float(__builtin_amdgcn_update_dpp(__float_as_int(v), __float_as_int(v), C, R, 0xf, false));
}
__device__ __forceinline__ float rlane63(float v){
  return __int_as_float(__builtin_amdgcn_readlane(__float_as_int(v), 63));
}
__device__ __forceinline__ void wred2(float &a, float &b){
  a += dppz<0x111,0xf>(a); b += dppz<0x111,0xf>(b);
  a += dppz<0x112,0xf>(a); b += dppz<0x112,0xf>(b);
  a += dppz<0x114,0xf>(a); b += dppz<0x114,0xf>(b);
  a += dppz<0x118,0xf>(a); b += dppz<0x118,0xf>(b);
  a += dppz<0x142,0xa>(a); b += dppz<0x142,0xa>(b);
  a += dppz<0x143,0xc>(a); b += dppz<0x143,0xc>(b);
  a = rlane63(a); b = rlane63(b);
}
__device__ __forceinline__ float wredsum(float a){
  a += dppz<0x111,0xf>(a); a += dppz<0x112,0xf>(a);
  a += dppz<0x114,0xf>(a); a += dppz<0x118,0xf>(a);
  a += dppz<0x142,0xa>(a); a += dppz<0x143,0xc>(a);
  return rlane63(a);
}
__device__ __forceinline__ float wredmax(float a){
  a = fmaxf(a, dppself<0x111,0xf>(a));
  a = fmaxf(a, dppself<0x112,0xf>(a));
  a = fmaxf(a, dppself<0x114,0xf>(a));
  a = fmaxf(a, dppself<0x118,0xf>(a));
  a = fmaxf(a, dppself<0x142,0xa>(a));
  a = fmaxf(a, dppself<0x143,0xc>(a));
  return rlane63(a);
}
__device__ __forceinline__ unsigned int pk16(float x, float y){
  return __builtin_bit_cast(unsigned int, __builtin_amdgcn_cvt_pkrtz(x, y));
}
__device__ __forceinline__ float fd2(unsigned int a, unsigned int b, float c){
#if __has_builtin(__builtin_amdgcn_fdot2)
  return __builtin_amdgcn_fdot2(__builtin_bit_cast(h2, a), __builtin_bit_cast(h2, b), c, false);
#else
  h2 x = __builtin_bit_cast(h2, a), y = __builtin_bit_cast(h2, b);
  return c + (float)x[0]*(float)y[0] + (float)x[1]*(float)y[1];
#endif
}
/* fast transcendentals: ~1ulp HW ops, cuts ~40-60cy of serial chain per LN step */
__device__ __forceinline__ float frcp(float x){ float r; asm("v_rcp_f32 %0, %1" : "=v"(r) : "v"(x)); return r; }
__device__ __forceinline__ float fsqrt_f(float x){ float r; asm("v_sqrt_f32 %0, %1" : "=v"(r) : "v"(x)); return r; }
__device__ __forceinline__ f32x2 pkfma(f32x2 a, f32x2 b, f32x2 c){
  return __builtin_elementwise_fma(a, b, c);
}

/* ---------------- Qa = enc_key_W @ enc_Wq^T + enc_bq  [64,512] ---------------- */
__global__ void __launch_bounds__(512) qa_kernel(const float* __restrict__ keyW,
    const float* __restrict__ Wq, const float* __restrict__ bq, float* __restrict__ Qa){
  int a = blockIdx.x, i = threadIdx.x;
  __shared__ float key[DD];
  key[i] = keyW[a*DD + i];
  __syncthreads();
  const float4* w4 = (const float4*)(Wq + (size_t)i*DD);
  const float4* k4 = (const float4*)key;
  float s = 0.f;
  #pragma unroll 4
  for (int j = 0; j < DD/4; j++){
    float4 w = w4[j], k = k4[j];
    s = fmaf(w.x,k.x, fmaf(w.y,k.y, fmaf(w.z,k.z, fmaf(w.w,k.w, s))));
  }
  Qa[a*DD + i] = s + bq[i];
}

/* ------------- Menc = Qa @ enc_Wk  [64,512] ----------------------------------- */
__global__ void __launch_bounds__(512) menc_kernel(const float* __restrict__ Qa,
    const float* __restrict__ Wk, float* __restrict__ Menc){
  int a = blockIdx.x, j = threadIdx.x;
  __shared__ float qa[DD];
  qa[j] = Qa[a*DD + j];
  __syncthreads();
  float s = 0.f;
  #pragma unroll 4
  for (int i = 0; i < DD; i++) s = fmaf(qa[i], Wk[(size_t)i*DD + j], s);
  Menc[a*DD + j] = s;
}

/* ------------- out[m] = X[m,:] . v  (4 rows per block) ------------------------- */
__global__ void __launch_bounds__(256) dotb_kernel(const float* __restrict__ X,
    const float* __restrict__ v, float* __restrict__ out){
  int m = blockIdx.x*4 + (threadIdx.x >> 6);
  int lane = threadIdx.x & 63;
  const float4* x4 = (const float4*)(X + (size_t)m*DD + lane*8);
  const float4* v4 = (const float4*)(v + lane*8);
  float4 a = x4[0], b4 = x4[1], c = v4[0], d = v4[1];
  float s = a.x*c.x;
  s = fmaf(a.y,c.y, s); s = fmaf(a.z,c.z, s); s = fmaf(a.w,c.w, s);
  s = fmaf(b4.x,d.x, s); s = fmaf(b4.y,d.y, s); s = fmaf(b4.z,d.z, s); s = fmaf(b4.w,d.w, s);
  s = wredsum(s);
  if (lane == 0) out[m] = s;
}

/* ------------- flag = all(n1g==1) && all(n1b==0) ------------------------------- */
__global__ void __launch_bounds__(512) flag_kernel(const float* __restrict__ g,
    const float* __restrict__ b, int* __restrict__ flag){
  __shared__ int s;
  if (threadIdx.x == 0) s = 1;
  __syncthreads();
  bool ok = (g[threadIdx.x] == 1.0f) && (b[threadIdx.x] == 0.0f);
  if (!ok) atomicAnd(&s, 0);
  __syncthreads();
  if (threadIdx.x == 0) flag[0] = s;
}

/* -------- X[b,t,:] = emb[tok[b,t],:] * sqrtD  (pre-gather, fully parallel) ------ */
__global__ void __launch_bounds__(256) xgather_kernel(const int* __restrict__ toks,
    const float* __restrict__ emb, float* __restrict__ X){
  int row = blockIdx.x*4 + (threadIdx.x >> 6);
  int lane = threadIdx.x & 63;
  int tok = toks[row];
  const float4* src = (const float4*)(emb + (size_t)tok*DD + lane*8);
  float4 a = src[0], b = src[1];
  a.x*=SQRTD; a.y*=SQRTD; a.z*=SQRTD; a.w*=SQRTD;
  b.x*=SQRTD; b.y*=SQRTD; b.z*=SQRTD; b.w*=SQRTD;
  float4* dst = (float4*)(X + (size_t)row*DD + lane*8);
  dst[0] = a; dst[1] = b;
}

/* --------- encoder z-scan: in-place X -> Z, pk-math FAST path ------------------- */
__device__ __forceinline__ void zscan_fast(float* __restrict__ XZ, float* __restrict__ ZSQ){
  int b = blockIdx.x, lane = threadIdx.x;
  int bd = lane*8;
  f32x2 z0 = {0.f,0.f}, z1 = {0.f,0.f}, z2 = {0.f,0.f}, z3 = {0.f,0.f};
  float* xp = XZ + (size_t)b*SENC*DD + bd;
  float2* sqp = (float2*)ZSQ + (size_t)b*SENC;
  float4 xa0 = *(const float4*)(xp       ), xb0 = *(const float4*)(xp        + 4);
  float4 xa1 = *(const float4*)(xp + DD  ), xb1 = *(const float4*)(xp + DD   + 4);
  float4 xa2 = *(const float4*)(xp + 2*DD), xb2 = *(const float4*)(xp + 2*DD + 4);
  float4 xa3 = *(const float4*)(xp + 3*DD), xb3 = *(const float4*)(xp + 3*DD + 4);
  for (int t = 0; t < SENC; t += 4){
#define ZFSTEP(XA, XB, OFS, PFO, TI) {                                             \
    f32x2 y0 = z0 + f32x2{XA.x, XA.y}, y1 = z1 + f32x2{XA.z, XA.w};                \
    f32x2 y2 = z2 + f32x2{XB.x, XB.y}, y3 = z3 + f32x2{XB.z, XB.w};                \
    f32x2 t01 = y0 + y1, t23 = y2 + y3, tv = t01 + t23;                            \
    float s = tv.x + tv.y;                                                         \
    f32x2 q0 = y0*y0, q1 = y1*y1, q2 = y2*y2, q3 = y3*y3;                          \
    f32x2 q01 = q0 + q1, q23 = q2 + q3, qv = q01 + q23;                            \
    float q = qv.x + qv.y;                                                         \
    wred2(s, q);                                                                   \
    float mean = s * (1.f/DD);                                                     \
    float qc2  = fmaf(mean*(-(float)DD), mean, q);                                 \
    float var  = fmaxf(qc2 * (1.f/(DD-1)), 0.f);                                   \
    float r = frcp(fsqrt_f(var) + EPSL);                                           \
    float c3 = -(r*mean);                                                          \
    f32x2 RR = {r,r}, C3 = {c3,c3};                                                \
    z0 = pkfma(RR, y0, C3); z1 = pkfma(RR, y1, C3);                                \
    z2 = pkfma(RR, y2, C3); z3 = pkfma(RR, y3, C3);                                \
    if (lane == 0){ float2 o = {0.f, qc2*r*r}; sqp[TI] = o; }                      \
    float4 o1 = {z0.x,z0.y,z1.x,z1.y}, o2 = {z2.x,z2.y,z3.x,z3.y};                 \
    *(float4*)(xp + OFS) = o1; *(float4*)(xp + OFS + 4) = o2;                      \
    XA = *(const float4*)(xp + PFO); XB = *(const float4*)(xp + PFO + 4); }
    ZFSTEP(xa0, xb0, 0,    4*DD, 0)
    ZFSTEP(xa1, xb1, DD,   5*DD, 1)
    ZFSTEP(xa2, xb2, 2*DD, 6*DD, 2)
    ZFSTEP(xa3, xb3, 3*DD, 7*DD, 3)
#undef ZFSTEP
    xp += 4*DD; sqp += 4;
  }
}

/* general path (n1 not identity) — reference-faithful */
__device__ __forceinline__ void zscan_gen(float* __restrict__ XZ,
    const float* __restrict__ n1g, const float* __restrict__ n1b,
    float* __restrict__ ZSQ){
  int b = blockIdx.x, lane = threadIdx.x;
  int bd = lane*8;
  float z[8], g1[8], b1[8];
  #pragma unroll
  for (int k = 0; k < 8; k++) z[k] = 0.f;
  *(float4*)&g1[0] = *(const float4*)(n1g+bd); *(float4*)&g1[4] = *(const float4*)(n1g+bd+4);
  *(float4*)&b1[0] = *(const float4*)(n1b+bd); *(float4*)&b1[4] = *(const float4*)(n1b+bd+4);
  float* xp = XZ + (size_t)b*SENC*DD + bd;
  float2* sqp = (float2*)ZSQ + (size_t)b*SENC;
  for (int t = 0; t < SENC; t++){
    float4 xa = *(const float4*)xp, xb = *(const float4*)(xp + 4);
    float x[8] = {xa.x,xa.y,xa.z,xa.w,xb.x,xb.y,xb.z,xb.w};
    float y[8], s = 0.f, q = 0.f;
    #pragma unroll
    for (int k = 0; k < 8; k++){ y[k] = z[k] + x[k]; s += y[k]; q = fmaf(y[k], y[k], q); }
    wred2(s, q);
    float mean = s * (1.f/DD);
    float var  = fmaxf((q - (float)DD*mean*mean) * (1.f/(DD-1)), 0.f);
    float r = 1.f/(sqrtf(var) + EPSL);
    float sz = 0.f, qz = 0.f;
    #pragma unroll
    for (int k = 0; k < 8; k++){
      z[k] = fmaf(g1[k]*r, y[k]-mean, b1[k]);
      sz += z[k]; qz = fmaf(z[k], z[k], qz);
    }
    wred2(sz, qz);
    if (lane == 0){ float2 o = {sz, qz}; sqp[t] = o; }
    float4 o1 = {z[0],z[1],z[2],z[3]}, o2 = {z[4],z[5],z[6],z[7]};
    *(float4*)xp = o1; *(float4*)(xp + 4) = o2;
    xp += DD;
  }
}

__global__ void __launch_bounds__(64) zscan_kernel(float* __restrict__ XZ,
    const float* __restrict__ n1g, const float* __restrict__ n1b,
    const int* __restrict__ flag, float* __restrict__ ZSQ){
  if (flag[0]) zscan_fast(XZ, ZSQ);
  else         zscan_gen(XZ, n1g, n1b, ZSQ);
}

/* -------- gates[bt][a] = sigmoid((Z[bt,:].Menc[a,:] + cenc[a])*SCALE) ----------- */
__global__ void __launch_bounds__(256) gates_kernel(const float* __restrict__ Zin,
    const float* __restrict__ Menc, const float* __restrict__ cenc,
    float* __restrict__ gates){
  __shared__ float As[32][64];
  __shared__ float Bs[32][64];
  int tid = threadIdx.x;
  int m0 = blockIdx.x*64;
  int ty = tid >> 4, tx = tid & 15;
  float acc[4][4] = {{0.f}};
  for (int k0 = 0; k0 < 512; k0 += 32){
    #pragma unroll
    for (int p = 0; p < 2; p++){
      int row = (tid>>3) + p*32, col = (tid&7)*4;
      float4 va = *(const float4*)(Zin + (size_t)(m0+row)*512 + k0 + col);
      As[col][row]=va.x; As[col+1][row]=va.y; As[col+2][row]=va.z; As[col+3][row]=va.w;
      float4 vb = *(const float4*)(Menc + (size_t)row*512 + k0 + col);
      Bs[col][row]=vb.x; Bs[col+1][row]=vb.y; Bs[col+2][row]=vb.z; Bs[col+3][row]=vb.w;
    }
    __syncthreads();
    #pragma unroll
    for (int kk = 0; kk < 32; kk++){
      float4 a4 = *(const float4*)&As[kk][ty*4];
      float4 b4 = *(const float4*)&Bs[kk][tx*4];
      float au[4] = {a4.x,a4.y,a4.z,a4.w}, bv[4] = {b4.x,b4.y,b4.z,b4.w};
      #pragma unroll
      for (int u = 0; u < 4; u++)
        #pragma unroll
        for (int v = 0; v < 4; v++) acc[u][v] = fmaf(au[u], bv[v], acc[u][v]);
    }
    __syncthreads();
  }
  float cv[4];
  #pragma unroll
  for (int v = 0; v < 4; v++) cv[v] = cenc[tx*4 + v];
  #pragma unroll
  for (int u = 0; u < 4; u++){
    float4 st;
    st.x = frcp(1.f + __expf(-(acc[u][0]+cv[0])*SCALE));
    st.y = frcp(1.f + __expf(-(acc[u][1]+cv[1])*SCALE));
    st.z = frcp(1.f + __expf(-(acc[u][2]+cv[2])*SCALE));
    st.w = frcp(1.f + __expf(-(acc[u][3]+cv[3])*SCALE));
    *(float4*)(gates + (size_t)(m0+ty*4+u)*AA + tx*4) = st;
  }
}

/* ---- encoder av-scan FAST: pk-math, unroll x2, analytic LN closure ------------- */
__device__ __forceinline__ void avscan_fast(const float* __restrict__ Z,
    const float* __restrict__ ZSQ, const float* __restrict__ gates,
    float* __restrict__ avout){
  int bx = blockIdx.x;
  int b = (bx & 7)*4 + ((bx >> 3) & 3);          /* all blocks of batch b on one XCD */
  int a = ((bx >> 5)<<3) + (threadIdx.x >> 6);
  int lane = threadIdx.x & 63;
  int bd = lane*8;
  f32x2 av0 = {0.f,0.f}, av1 = {0.f,0.f}, av2v = {0.f,0.f}, av3 = {0.f,0.f};
  float Qav = 0.f;
  const float*  zp  = Z + (size_t)b*SENC*DD + bd;
  const float4* sp4 = (const float4*)(ZSQ + (size_t)b*SENC*2);
  const float*  gp  = gates + (size_t)b*SENC*AA + a;
  float4 zc0a = *(const float4*)zp,        zc0b = *(const float4*)(zp + 4);
  float4 zc1a = *(const float4*)(zp + DD), zc1b = *(const float4*)(zp + DD + 4);
  float4 sq01 = sp4[0];
  float g0 = gp[0], g1 = gp[AA];
  for (int t = 0; t < SENC; t += 2){
    /* prefetch t+2, t+3 (slack rows allocated; cross-batch touch never consumed) */
    float4 zn0a = *(const float4*)(zp + 2*DD), zn0b = *(const float4*)(zp + 2*DD + 4);
    float4 zn1a = *(const float4*)(zp + 3*DD), zn1b = *(const float4*)(zp + 3*DD + 4);
    float4 sqn = sp4[1];
    float gn0 = gp[2*AA], gn1 = gp[3*AA];
#define AVSTEP(ZA, ZB, SZT, QZT, G) {                                              \
    f32x2 z0 = {ZA.x, ZA.y}, z1 = {ZA.z, ZA.w};                                    \
    f32x2 z2 = {ZB.x, ZB.y}, z3 = {ZB.z, ZB.w};                                    \
    f32x2 p0 = av0*z0, p1 = av1*z1, p2 = av2v*z2, p3 = av3*z3;                     \
    f32x2 s01 = p0 + p1, s23 = p2 + p3, sv = s01 + s23;                            \
    float cav = wredsum(sv.x + sv.y);                                              \
    float g = (G), omg = 1.f - g;                                                  \
    float mean = (g * (1.f/DD)) * (SZT);                                           \
    float a1s = (omg*omg) * Qav;                                                   \
    float a2s = fmaf((g+g)*omg, cav, a1s);                                         \
    float Qy  = fmaf(g*g, (QZT), a2s);                                             \
    float qc2 = fmaf(mean*(-(float)DD), mean, Qy);                                 \
    float var = fmaxf(qc2 * (1.f/(DD-1)), 0.f);                                    \
    float r = frcp(fsqrt_f(var) + EPSL);                                           \
    float c1 = r*omg, c2s = r*g, c3 = -(r*mean);                                   \
    f32x2 C1 = {c1,c1}, C2 = {c2s,c2s}, C3 = {c3,c3};                              \
    av0  = pkfma(C1, av0,  pkfma(C2, z0, C3));                                     \
    av1  = pkfma(C1, av1,  pkfma(C2, z1, C3));                                     \
    av2v = pkfma(C1, av2v, pkfma(C2, z2, C3));                                     \
    av3  = pkfma(C1, av3,  pkfma(C2, z3, C3));                                     \
    Qav = qc2 * (r*r); }
    AVSTEP(zc0a, zc0b, sq01.x, sq01.y, g0)
    AVSTEP(zc1a, zc1b, sq01.z, sq01.w, g1)
#undef AVSTEP
    zc0a = zn0a; zc0b = zn0b; zc1a = zn1a; zc1b = zn1b;
    sq01 = sqn; g0 = gn0; g1 = gn1;
    zp += 2*DD; sp4 += 1; gp += 2*AA;
  }
  float* o = avout + ((size_t)(b*AA + a))*DD + bd;
  float4 o1 = {av0.x,av0.y,av1.x,av1.y}, o2 = {av2v.x,av2v.y,av3.x,av3.y};
  *(float4*)o = o1; *(float4*)(o+4) = o2;
}

/* general path — reference-faithful */
__device__ __forceinline__ void avscan_gen(const float* __restrict__ Z,
    const float* __restrict__ ZSQ, const float* __restrict__ gates,
    const float* __restrict__ n1g, const float* __restrict__ n1b,
    float* __restrict__ avout){
  int bx = blockIdx.x;
  int b = (bx & 7)*4 + ((bx >> 3) & 3);
  int a = ((bx >> 5)<<3) + (threadIdx.x >> 6);
  int lane = threadIdx.x & 63;
  int bd = lane*8;
  float g1[8], b1[8], av[8];
  *(float4*)&g1[0] = *(const float4*)(n1g+bd); *(float4*)&g1[4] = *(const float4*)(n1g+bd+4);
  *(float4*)&b1[0] = *(const float4*)(n1b+bd); *(float4*)&b1[4] = *(const float4*)(n1b+bd+4);
  #pragma unroll
  for (int k = 0; k < 8; k++) av[k] = 0.f;
  float Sav = 0.f, Qav = 0.f;
  const float*  zp = Z + (size_t)b*SENC*DD + bd;
  const float2* sp = (const float2*)ZSQ + (size_t)b*SENC;
  const float*  gp = gates + (size_t)b*SENC*AA + a;
  for (int t = 0; t < SENC; t++){
    float4 za = *(const float4*)zp, zb = *(const float4*)(zp + 4);
    float z[8] = {za.x,za.y,za.z,za.w,zb.x,zb.y,zb.z,zb.w};
    float2 sq = sp[0];
    float g = gp[0];
    float cav = 0.f;
    #pragma unroll
    for (int k = 0; k < 8; k++) cav = fmaf(av[k], z[k], cav);
    cav = wredsum(cav);
    float omg = 1.f - g;
    float Sy = fmaf(g, sq.x - Sav, Sav);
    float Qy = omg*omg*Qav + 2.f*g*omg*cav + g*g*sq.y;
    float mean = Sy * (1.f/DD);
    float var  = fmaxf((Qy - (float)DD*mean*mean) * (1.f/(DD-1)), 0.f);
    float r = 1.f/(sqrtf(var) + EPSL);
    float sn = 0.f, qn = 0.f;
    #pragma unroll
    for (int k = 0; k < 8; k++){
      float y = fmaf(g, z[k]-av[k], av[k]);
      float nv = fmaf(g1[k]*r, y-mean, b1[k]);
      av[k] = nv; sn += nv; qn = fmaf(nv, nv, qn);
    }
    wred2(sn, qn);
    Sav = sn; Qav = qn;
    zp += DD; sp += 1; gp += AA;
  }
  float* o = avout + ((size_t)(b*AA + a))*DD + bd;
  float4 o1 = {av[0],av[1],av[2],av[3]}, o2 = {av[4],av[5],av[6],av[7]};
  *(float4*)o = o1; *(float4*)(o+4) = o2;
}

__global__ void __launch_bounds__(512) avscan_kernel(const float* __restrict__ Z,
    const float* __restrict__ ZSQ, const float* __restrict__ gates,
    const float* __restrict__ n1g, const float* __restrict__ n1b,
    const int* __restrict__ flag, float* __restrict__ avout){
  if (flag[0]) avscan_fast(Z, ZSQ, gates, avout);
  else         avscan_gen(Z, ZSQ, gates, n1g, n1b, avout);
}

/* ------------- f32 GEMM, C[m,n] = sum_k A[m,k]*Bw[n,k] (+bias[n]) --------------- */
__global__ void __launch_bounds__(256) gemm_nt_kernel(const float* __restrict__ Aa,
    const float* __restrict__ Bw, const float* __restrict__ bias,
    void* __restrict__ Cout, int mode){
  __shared__ float As[32][64];
  __shared__ float Bs[32][64];
  int tid = threadIdx.x;
  int m0 = blockIdx.x*64, n0 = blockIdx.y*64;
  int ty = tid >> 4, tx = tid & 15;
  float acc[4][4] = {{0.f}};
  for (int k0 = 0; k0 < 512; k0 += 32){
    #pragma unroll
    for (int p = 0; p < 2; p++){
      int row = (tid>>3) + p*32, col = (tid&7)*4;
      float4 va = *(const float4*)(Aa + (size_t)(m0+row)*512 + k0 + col);
      As[col][row]=va.x; As[col+1][row]=va.y; As[col+2][row]=va.z; As[col+3][row]=va.w;
      float4 vb = *(const float4*)(Bw + (size_t)(n0+row)*512 + k0 + col);
      Bs[col][row]=vb.x; Bs[col+1][row]=vb.y; Bs[col+2][row]=vb.z; Bs[col+3][row]=vb.w;
    }
    __syncthreads();
    #pragma unroll
    for (int kk = 0; kk < 32; kk++){
      float4 a4 = *(const float4*)&As[kk][ty*4];
      float4 b4 = *(const float4*)&Bs[kk][tx*4];
      float au[4] = {a4.x,a4.y,a4.z,a4.w}, bv[4] = {b4.x,b4.y,b4.z,b4.w};
      #pragma unroll
      for (int u = 0; u < 4; u++)
        #pragma unroll
        for (int v = 0; v < 4; v++) acc[u][v] = fmaf(au[u], bv[v], acc[u][v]);
    }
    __syncthreads();
  }
  float bv4[4];
  #pragma unroll
  for (int v = 0; v < 4; v++) bv4[v] = bias ? bias[n0 + tx*4 + v] : 0.f;
  if (mode == 0){
    float* C = (float*)Cout;
    #pragma unroll
    for (int u = 0; u < 4; u++){
      float4 st = {acc[u][0]+bv4[0], acc[u][1]+bv4[1], acc[u][2]+bv4[2], acc[u][3]+bv4[3]};
      *(float4*)(C + (size_t)(m0+ty*4+u)*512 + n0 + tx*4) = st;
    }
  } else {
    unsigned short* C = (unsigned short*)Cout;
    #pragma unroll
    for (int u = 0; u < 4; u++){
      int mm = m0 + ty*4 + u; int bb = mm >> 6, a2 = mm & 63;
      #pragma unroll
      for (int v = 0; v < 4; v++){
        _Float16 hv = (_Float16)(acc[u][v] + bv4[v]);
        C[((size_t)bb*512 + n0 + tx*4 + v)*64 + a2] = __builtin_bit_cast(unsigned short, hv);
      }
    }
  }
}

/* ------------- P16[m][n] (f16) = sum_k A[m,k]*B[k,n] --------------------------- */
__global__ void __launch_bounds__(256) gemm_nn_kernel(const float* __restrict__ Aa,
    const float* __restrict__ Bw, unsigned int* __restrict__ Cout){
  __shared__ float As[32][64];
  __shared__ float Bs[32][64];
  int tid = threadIdx.x;
  int m0 = blockIdx.x*64, n0 = blockIdx.y*64;
  int ty = tid >> 4, tx = tid & 15;
  float acc[4][4] = {{0.f}};
  for (int k0 = 0; k0 < 512; k0 += 32){
    #pragma unroll
    for (int p = 0; p < 2; p++){
      int row = (tid>>3) + p*32, col = (tid&7)*4;
      float4 va = *(const float4*)(Aa + (size_t)(m0+row)*512 + k0 + col);
      As[col][row]=va.x; As[col+1][row]=va.y; As[col+2][row]=va.z; As[col+3][row]=va.w;
      int brow = (tid>>4) + p*16, bcol = (tid&15)*4;
      float4 vb = *(const float4*)(Bw + (size_t)(k0+brow)*512 + n0 + bcol);
      *(float4*)&Bs[brow][bcol] = vb;
    }
    __syncthreads();
    #pragma unroll
    for (int kk = 0; kk < 32; kk++){
      float4 a4 = *(const float4*)&As[kk][ty*4];
      float4 b4 = *(const float4*)&Bs[kk][tx*4];
      float au[4] = {a4.x,a4.y,a4.z,a4.w}, bv[4] = {b4.x,b4.y,b4.z,b4.w};
      #pragma unroll
      for (int u = 0; u < 4; u++)
        #pragma unroll
        for (int v = 0; v < 4; v++) acc[u][v] = fmaf(au[u], bv[v], acc[u][v]);
    }
    __syncthreads();
  }
  #pragma unroll
  for (int u = 0; u < 4; u++){
    uint2 st = { pk16(acc[u][0], acc[u][1]), pk16(acc[u][2], acc[u][3]) };
    *(uint2*)(Cout + (size_t)(m0+ty*4+u)*256 + (n0 + tx*4)/2) = st;
  }
}

/* ------------------------------- decoder scan ----------------------------------- */
/* P16/V16 in 128KB LDS; 2 barriers/step (zh is same-wave-only -> no 3rd barrier)   */
__global__ void __launch_bounds__(256) dec_kernel(const float* __restrict__ Z,
    const unsigned int* __restrict__ Pg, const unsigned int* __restrict__ Vg,
    const float* __restrict__ cdec, const float* __restrict__ n2g,
    const float* __restrict__ n2b, float* __restrict__ zfin){
  __shared__ __align__(16) unsigned char Pl[65536];
  __shared__ __align__(16) unsigned char Vl[65536];
  __shared__ unsigned int zh[256];
  __shared__ float part[AA][4];
  __shared__ unsigned int att4h[4][32];
  __shared__ float2 red2[4];
  int b = blockIdx.x, tid = threadIdx.x;
  int lane = tid & 63, w = tid >> 6;

  const uint4* Pg4 = (const uint4*)(Pg + (size_t)b*16384);
  #pragma unroll
  for (int j = 0; j < 16; j++){
    int fb = j*1024 + tid*4;
    uint4 v = Pg4[j*256 + tid];
    int a = fb >> 8;
    int off = (fb & 255) * 4;
    *(uint4*)(Pl + a*1024 + (off ^ ((a&7)<<4))) = v;
  }
  const uint4* Vg4 = (const uint4*)(Vg + (size_t)b*16384);
  #pragma unroll
  for (int j = 0; j < 16; j++){
    int fb = j*1024 + tid*4;
    uint4 v = Vg4[j*256 + tid];
    int d = fb >> 5;
    int off = (fb & 31) * 4;
    *(uint4*)(Vl + d*128 + (off ^ (((d>>1)&7)<<4))) = v;
  }
  int d0 = tid*2;
  float2 zi = *(const float2*)(Z + ((size_t)b*SENC + SENC-1)*DD + d0);
  float z0r = zi.x, z1r = zi.y;
  zh[tid] = pk16(z0r, z1r);
  float cdv = cdec[b*AA + lane];
  float g2a = n2g[d0], g2b = n2g[d0+1], b2a = n2b[d0], b2b = n2b[d0+1];
  int pk = (lane&7)<<4;
  int vk = (tid&7)<<4;
  __syncthreads();

  for (int t = 0; t < SDEC; t++){
    /* ph1: logit partial for anchor=lane over d-quarter w (reads OWN wave's zh) */
    float s = 0.f;
    #pragma unroll
    for (int j = 0; j < 16; j++){
      uint4 pv = *(const uint4*)(Pl + lane*1024 + ((w*256 + j*16) ^ pk));
      uint4 zv = *(const uint4*)&zh[w*64 + j*4];
      s = fd2(pv.x, zv.x, s); s = fd2(pv.y, zv.y, s);
      s = fd2(pv.z, zv.z, s); s = fd2(pv.w, zv.w, s);
    }
    part[lane][w] = s;
    __syncthreads();                               /* A */
    float4 pp = *(const float4*)&part[lane][0];
    float l = (pp.x + pp.y + pp.z + pp.w + cdv) * SCALE;
    float mx = wredmax(l);
    float e = __expf(l - mx);
    float se = wredsum(e);
    float attv = e * frcp(se);
    float attn = dppself<0x101,0xf>(attv);         /* row_shl:1 -> lane i gets att[i+1] */
    if ((lane & 1) == 0) att4h[w][lane>>1] = pk16(attv, attn);
    asm volatile("s_waitcnt lgkmcnt(0)" ::: "memory");
    float a0 = 0.f, a1 = 0.f;
    #pragma unroll
    for (int j = 0; j < 8; j++){
      uint4 ah = *(const uint4*)&att4h[w][j*4];
      uint4 v0 = *(const uint4*)(Vl + d0*128 + ((j*16) ^ vk));
      uint4 v1 = *(const uint4*)(Vl + (d0+1)*128 + ((j*16) ^ vk));
      a0 = fd2(v0.x, ah.x, a0); a0 = fd2(v0.y, ah.y, a0);
      a0 = fd2(v0.z, ah.z, a0); a0 = fd2(v0.w, ah.w, a0);
      a1 = fd2(v1.x, ah.x, a1); a1 = fd2(v1.y, ah.y, a1);
      a1 = fd2(v1.z, ah.z, a1); a1 = fd2(v1.w, ah.w, a1);
    }
    float y0 = z0r + a0, y1 = z1r + a1;
    float s2 = y0 + y1, q2 = fmaf(y0, y0, y1*y1);
    wred2(s2, q2);
    if (lane == 0){ float2 o = {s2, q2}; red2[w] = o; }
    __syncthreads();                               /* B */
    float2 rA = red2[0], rB = red2[1], rC = red2[2], rD = red2[3];
    float Sy = rA.x+rB.x+rC.x+rD.x, Qy = rA.y+rB.y+rC.y+rD.y;
    float mean = Sy * (1.f/DD);
    float var  = fmaxf((Qy - (float)DD*mean*mean) * (1.f/(DD-1)), 0.f);
    float r = frcp(fsqrt_f(var) + EPSL);
    z0r = fmaf(g2a*r, y0-mean, b2a);
    z1r = fmaf(g2b*r, y1-mean, b2b);
    zh[tid] = pk16(z0r, z1r);                      /* own-wave consumer only */
    asm volatile("s_waitcnt lgkmcnt(0)" ::: "memory");
  }
  zfin[(size_t)b*DD + d0]     = z0r;
  zfin[(size_t)b*DD + d0 + 1] = z1r;
}

/* ---------------- logits = zfin @ voc_W^T + voc_b ------------------------------- */
__global__ void __launch_bounds__(256) logits_kernel(const float* __restrict__ zfin,
    const float* __restrict__ vocW, const float* __restrict__ vocb, float* __restrict__ out){
  __shared__ float zS[NB*DD];
  int tid = threadIdx.x;
  const float4* src = (const float4*)zfin;
  float4* dst = (float4*)zS;
  #pragma unroll
  for (int i = 0; i < 16; i++) dst[tid + i*256] = src[tid + i*256];
  __syncthreads();
  int w = tid >> 6, lane = tid & 63;
  int kq = lane & 3, rp = lane >> 2;
  int r0 = blockIdx.x*128 + w*32 + rp*2, r1 = r0 + 1;
  float acc0[NB], acc1[NB];
  #pragma unroll
  for (int bq = 0; bq < NB; bq++){ acc0[bq] = 0.f; acc1[bq] = 0.f; }
  const float* w0p = vocW + (size_t)r0*DD;
  const float* w1p = vocW + (size_t)r1*DD;
  for (int ks = 0; ks < 32; ks++){
    int koff = ks*16 + kq*4;
    float4 w0 = *(const float4*)(w0p + koff);
    float4 w1 = *(const float4*)(w1p + koff);
    #pragma unroll
    for (int bq = 0; bq < NB; bq++){
      float4 z4 = *(const float4*)&zS[bq*DD + koff];
      acc0[bq] = fmaf(w0.x,z4.x, fmaf(w0.y,z4.y, fmaf(w0.z,z4.z, fmaf(w0.w,z4.w, acc0[bq]))));
      acc1[bq] = fmaf(w1.x,z4.x, fmaf(w1.y,z4.y, fmaf(w1.z,z4.z, fmaf(w1.w,z4.w, acc1[bq]))));
    }
  }
  #pragma unroll
  for (int bq = 0; bq < NB; bq++){
    acc0[bq] += dppz<0xB1,0xf>(acc0[bq]); acc0[bq] += dppz<0x4E,0xf>(acc0[bq]);
    acc1[bq] += dppz<0xB1,0xf>(acc1[bq]); acc1[bq] += dppz<0x4E,0xf>(acc1[bq]);
  }
  if (kq == 0){
    float vb0 = vocb[r0], vb1 = vocb[r1];
    #pragma unroll
    for (int bq = 0; bq < NB; bq++){
      out[(size_t)bq*VOUT + r0] = acc0[bq] + vb0;
      out[(size_t)bq*VOUT + r1] = acc1[bq] + vb1;
    }
  }
}

/* --------------------------- split log_softmax ---------------------------------- */
__global__ void __launch_bounds__(256) lsm1_kernel(const float* __restrict__ out,
    float2* __restrict__ partb){
  int b = blockIdx.x >> 3, c = blockIdx.x & 7;
  const float* row = out + (size_t)b*VOUT + c*4000;
  int tid = threadIdx.x;
  __shared__ float rm[4]; __shared__ float rs[4];
  float mx = -3.4e38f;
  for (int i = tid; i < 4000; i += 256) mx = fmaxf(mx, row[i]);
  mx = wredmax(mx);
  if ((tid & 63) == 0) rm[tid>>6] = mx;
  __syncthreads();
  mx = fmaxf(fmaxf(rm[0],rm[1]), fmaxf(rm[2],rm[3]));
  float sm = 0.f;
  for (int i = tid; i < 4000; i += 256) sm += __expf(row[i] - mx);
  sm = wredsum(sm);
  if ((tid & 63) == 0) rs[tid>>6] = sm;
  __syncthreads();
  if (tid == 0){ float2 o = {mx, rs[0]+rs[1]+rs[2]+rs[3]}; partb[blockIdx.x] = o; }
}
__global__ void __launch_bounds__(256) lsm2_kernel(float* __restrict__ out,
    const float2* __restrict__ partb){
  int b = blockIdx.x >> 3, c = blockIdx.x & 7;
  float M = -3.4e38f, S = 0.f;
  #pragma unroll
  for (int j = 0; j < 8; j++) M = fmaxf(M, partb[b*8+j].x);
  #pragma unroll
  for (int j = 0; j < 8; j++){ float2 p = partb[b*8+j]; S += p.y * __expf(p.x - M); }
  float cns = M + logf(S);
  float* row = out + (size_t)b*VOUT + c*4000;
  for (int i = threadIdx.x; i < 4000; i += 256) row[i] -= cns;
}

extern "C" void kernel_launch(void* const* d_in, const int* in_sizes, int n_in,
                              void* d_out, int out_size, void* d_ws, size_t ws_size,
                              hipStream_t stream){
  (void)in_sizes; (void)n_in; (void)out_size; (void)ws_size;
  const int*   toks      = (const int*)  d_in[0];
  const float* emb_in    = (const float*)d_in[2];
  const float* enc_key_W = (const float*)d_in[4];
  const float* enc_Wq    = (const float*)d_in[5];
  const float* enc_bq    = (const float*)d_in[6];
  const float* enc_Wk    = (const float*)d_in[7];
  const float* enc_bk    = (const float*)d_in[8];
  const float* n1g       = (const float*)d_in[9];
  const float* n1b       = (const float*)d_in[10];
  const float* rdr_Wq    = (const float*)d_in[12];
  const float* rdr_bq    = (const float*)d_in[13];
  const float* rdr_Wk    = (const float*)d_in[14];
  const float* rdr_bk    = (const float*)d_in[15];
  const float* rdr_Wv    = (const float*)d_in[16];
  const float* rdr_bv    = (const float*)d_in[17];
  const float* n2g       = (const float*)d_in[22];
  const float* n2b       = (const float*)d_in[23];
  const float* vocW      = (const float*)d_in[26];
  const float* vocb      = (const float*)d_in[27];
  float* outp = (float*)d_out;

  float* ws = (float*)d_ws;
  size_t off = 0;
  float* Z    = ws + off; off += (size_t)NB*SENC*DD + 4*DD;  /* X/Z in place + slack */
  float* ZSQ  = ws + off; off += (size_t)NB*SENC*2 + 8;      /* + prefetch slack */
  float* av   = ws + off; off += (size_t)NB*AA*DD;
  /* gates [B*SENC][AA] f32 (8MB) aliases Kr+P16 (both written after avscan);
     gates prefetch slack spills into V16 region — also written after avscan */
  float* Kr   = ws + off; float* gates = Kr; off += (size_t)NB*AA*DD;
  unsigned int* P16 = (unsigned int*)(ws + off); off += (size_t)NB*AA*DD/2;
  unsigned int* V16 = (unsigned int*)(ws + off); off += (size_t)NB*AA*DD/2;
  float* Qa   = ws + off; off += (size_t)AA*DD;
  float* Menc = ws + off; off += (size_t)AA*DD;
  float* cenc = ws + off; off += AA;
  float* cdec = ws + off; off += (size_t)NB*AA;
  float* zfin = ws + off; off += (size_t)NB*DD;
  float2* lsp = (float2*)(ws + off); off += 512;
  int*  flag  = (int*)(ws + off); off += 1;

  qa_kernel     <<<AA, 512, 0, stream>>>(enc_key_W, enc_Wq, enc_bq, Qa);
  menc_kernel   <<<AA, 512, 0, stream>>>(Qa, enc_Wk, Menc);
  dotb_kernel   <<<AA/4, 256, 0, stream>>>(Qa, enc_bk, cenc);
  flag_kernel   <<<1, 512, 0, stream>>>(n1g, n1b, flag);
  xgather_kernel<<<NB*SENC/4, 256, 0, stream>>>(toks, emb_in, Z);
  zscan_kernel  <<<NB, 64, 0, stream>>>(Z, n1g, n1b, flag, ZSQ);
  gates_kernel  <<<NB*SENC/64, 256, 0, stream>>>(Z, Menc, cenc, gates);
  avscan_kernel <<<256, 512, 0, stream>>>(Z, ZSQ, gates, n1g, n1b, flag, av);
  gemm_nt_kernel<<<dim3(NB*AA/64, DD/64), 256, 0, stream>>>(av, rdr_Wk, rdr_bk, Kr, 0);
  gemm_nn_kernel<<<dim3(NB*AA/64, DD/64), 256, 0, stream>>>(Kr, rdr_Wq, P16);
  gemm_nt_kernel<<<dim3(NB*AA/64, DD/64), 256, 0, stream>>>(av, rdr_Wv, rdr_bv, V16, 1);
  dotb_kernel   <<<NB*AA/4, 256, 0, stream>>>(Kr, rdr_bq, cdec);
  dec_kernel    <<<NB, 256, 0, stream>>>(Z, P16, V16, cdec, n2g, n2b, zfin);
  logits_kernel <<<VOUT/128, 256, 0, stream>>>(zfin, vocW, vocb, outp);
  lsm1_kernel   <<<NB*8, 256, 0, stream>>>(outp, lsp);
  lsm2_kernel   <<<NB*8, 256, 0, stream>>>(outp, lsp);
}

// Round 7
// 1198.912 us; speedup vs baseline: 2.2117x; 1.0429x over previous
//
#include <hip/hip_runtime.h>
#include <math.h>

#define DD 512
#define AA 64
#define NB 32
#define SENC 1024
#define SDEC 256
#define VOUT 32000
#define EPSL 1e-6f
#define SCALE 0.044194173824159216f   /* 1/sqrt(512) */
#define SQRTD 22.627416997969522f     /* sqrt(512) */

typedef _Float16 h2 __attribute__((ext_vector_type(2)));
typedef float f32x2 __attribute__((ext_vector_type(2)));

/* ---------------- DPP wave reduction helpers (VALU-only) ----------------------- */
template<int C, int R>
__device__ __forceinline__ float dppz(float v){   /* old=0, bound_ctrl=1 */
  return __int_as_float(__builtin_amdgcn_update_dpp(0, __float_as_int(v), C, R, 0xf, true));
}
template<int C, int R>
__device__ __forceinline__ float dppself(float v){ /* old=self, bound_ctrl=0 */
  return __int_as_float(__builtin_amdgcn_update_dpp(__float_as_int(v), __float_as_int(v), C, R, 0xf, false));
}
__device__ __forceinline__ float rlane63(float v){
  return __int_as_float(__builtin_amdgcn_readlane(__float_as_int(v), 63));
}
__device__ __forceinline__ void wred2(float &a, float &b){
  a += dppz<0x111,0xf>(a); b += dppz<0x111,0xf>(b);
  a += dppz<0x112,0xf>(a); b += dppz<0x112,0xf>(b);
  a += dppz<0x114,0xf>(a); b += dppz<0x114,0xf>(b);
  a += dppz<0x118,0xf>(a); b += dppz<0x118,0xf>(b);
  a += dppz<0x142,0xa>(a); b += dppz<0x142,0xa>(b);
  a += dppz<0x143,0xc>(a); b += dppz<0x143,0xc>(b);
  a = rlane63(a); b = rlane63(b);
}
__device__ __forceinline__ float wredsum(float a){
  a += dppz<0x111,0xf>(a); a += dppz<0x112,0xf>(a);
  a += dppz<0x114,0xf>(a); a += dppz<0x118,0xf>(a);
  a += dppz<0x142,0xa>(a); a += dppz<0x143,0xc>(a);
  return rlane63(a);
}
__device__ __forceinline__ float wredmax(float a){
  a = fmaxf(a, dppself<0x111,0xf>(a));
  a = fmaxf(a, dppself<0x112,0xf>(a));
  a = fmaxf(a, dppself<0x114,0xf>(a));
  a = fmaxf(a, dppself<0x118,0xf>(a));
  a = fmaxf(a, dppself<0x142,0xa>(a));
  a = fmaxf(a, dppself<0x143,0xc>(a));
  return rlane63(a);
}
__device__ __forceinline__ unsigned int pk16(float x, float y){
  return __builtin_bit_cast(unsigned int, __builtin_amdgcn_cvt_pkrtz(x, y));
}
__device__ __forceinline__ float fd2(unsigned int a, unsigned int b, float c){
#if __has_builtin(__builtin_amdgcn_fdot2)
  return __builtin_amdgcn_fdot2(__builtin_bit_cast(h2, a), __builtin_bit_cast(h2, b), c, false);
#else
  h2 x = __builtin_bit_cast(h2, a), y = __builtin_bit_cast(h2, b);
  return c + (float)x[0]*(float)y[0] + (float)x[1]*(float)y[1];
#endif
}
/* fast transcendentals: ~1ulp HW ops */
__device__ __forceinline__ float frcp(float x){ float r; asm("v_rcp_f32 %0, %1" : "=v"(r) : "v"(x)); return r; }
__device__ __forceinline__ float fsqrt_f(float x){ float r; asm("v_sqrt_f32 %0, %1" : "=v"(r) : "v"(x)); return r; }
__device__ __forceinline__ f32x2 pkfma(f32x2 a, f32x2 b, f32x2 c){
  return __builtin_elementwise_fma(a, b, c);
}

/* ---------------- Qa = enc_key_W @ enc_Wq^T + enc_bq  [64,512] ---------------- */
__global__ void __launch_bounds__(512) qa_kernel(const float* __restrict__ keyW,
    const float* __restrict__ Wq, const float* __restrict__ bq, float* __restrict__ Qa){
  int a = blockIdx.x, i = threadIdx.x;
  __shared__ float key[DD];
  key[i] = keyW[a*DD + i];
  __syncthreads();
  const float4* w4 = (const float4*)(Wq + (size_t)i*DD);
  const float4* k4 = (const float4*)key;
  float s = 0.f;
  #pragma unroll 4
  for (int j = 0; j < DD/4; j++){
    float4 w = w4[j], k = k4[j];
    s = fmaf(w.x,k.x, fmaf(w.y,k.y, fmaf(w.z,k.z, fmaf(w.w,k.w, s))));
  }
  Qa[a*DD + i] = s + bq[i];
}

/* ------------- Menc = Qa @ enc_Wk  [64,512] ----------------------------------- */
__global__ void __launch_bounds__(512) menc_kernel(const float* __restrict__ Qa,
    const float* __restrict__ Wk, float* __restrict__ Menc){
  int a = blockIdx.x, j = threadIdx.x;
  __shared__ float qa[DD];
  qa[j] = Qa[a*DD + j];
  __syncthreads();
  float s = 0.f;
  #pragma unroll 4
  for (int i = 0; i < DD; i++) s = fmaf(qa[i], Wk[(size_t)i*DD + j], s);
  Menc[a*DD + j] = s;
}

/* ------------- out[m] = X[m,:] . v  (4 rows per block) ------------------------- */
__global__ void __launch_bounds__(256) dotb_kernel(const float* __restrict__ X,
    const float* __restrict__ v, float* __restrict__ out){
  int m = blockIdx.x*4 + (threadIdx.x >> 6);
  int lane = threadIdx.x & 63;
  const float4* x4 = (const float4*)(X + (size_t)m*DD + lane*8);
  const float4* v4 = (const float4*)(v + lane*8);
  float4 a = x4[0], b4 = x4[1], c = v4[0], d = v4[1];
  float s = a.x*c.x;
  s = fmaf(a.y,c.y, s); s = fmaf(a.z,c.z, s); s = fmaf(a.w,c.w, s);
  s = fmaf(b4.x,d.x, s); s = fmaf(b4.y,d.y, s); s = fmaf(b4.z,d.z, s); s = fmaf(b4.w,d.w, s);
  s = wredsum(s);
  if (lane == 0) out[m] = s;
}

/* ------------- flag = all(n1g==1) && all(n1b==0) ------------------------------- */
__global__ void __launch_bounds__(512) flag_kernel(const float* __restrict__ g,
    const float* __restrict__ b, int* __restrict__ flag){
  __shared__ int s;
  if (threadIdx.x == 0) s = 1;
  __syncthreads();
  bool ok = (g[threadIdx.x] == 1.0f) && (b[threadIdx.x] == 0.0f);
  if (!ok) atomicAnd(&s, 0);
  __syncthreads();
  if (threadIdx.x == 0) flag[0] = s;
}

/* -------- X[b,t,:] = emb[tok[b,t],:] * sqrtD  (pre-gather, fully parallel) ------ */
__global__ void __launch_bounds__(256) xgather_kernel(const int* __restrict__ toks,
    const float* __restrict__ emb, float* __restrict__ X){
  int row = blockIdx.x*4 + (threadIdx.x >> 6);
  int lane = threadIdx.x & 63;
  int tok = toks[row];
  const float4* src = (const float4*)(emb + (size_t)tok*DD + lane*8);
  float4 a = src[0], b = src[1];
  a.x*=SQRTD; a.y*=SQRTD; a.z*=SQRTD; a.w*=SQRTD;
  b.x*=SQRTD; b.y*=SQRTD; b.z*=SQRTD; b.w*=SQRTD;
  float4* dst = (float4*)(X + (size_t)row*DD + lane*8);
  dst[0] = a; dst[1] = b;
}

/* --------- encoder z-scan: in-place X -> Z, pk-math FAST path ------------------- */
__device__ __forceinline__ void zscan_fast(float* __restrict__ XZ, float* __restrict__ ZSQ){
  int b = blockIdx.x, lane = threadIdx.x;
  int bd = lane*8;
  f32x2 z0 = {0.f,0.f}, z1 = {0.f,0.f}, z2 = {0.f,0.f}, z3 = {0.f,0.f};
  float* xp = XZ + (size_t)b*SENC*DD + bd;
  float2* sqp = (float2*)ZSQ + (size_t)b*SENC;
  float4 xa0 = *(const float4*)(xp       ), xb0 = *(const float4*)(xp        + 4);
  float4 xa1 = *(const float4*)(xp + DD  ), xb1 = *(const float4*)(xp + DD   + 4);
  float4 xa2 = *(const float4*)(xp + 2*DD), xb2 = *(const float4*)(xp + 2*DD + 4);
  float4 xa3 = *(const float4*)(xp + 3*DD), xb3 = *(const float4*)(xp + 3*DD + 4);
  for (int t = 0; t < SENC; t += 4){
#define ZFSTEP(XA, XB, OFS, PFO, TI) {                                             \
    f32x2 y0 = z0 + f32x2{XA.x, XA.y}, y1 = z1 + f32x2{XA.z, XA.w};                \
    f32x2 y2 = z2 + f32x2{XB.x, XB.y}, y3 = z3 + f32x2{XB.z, XB.w};                \
    f32x2 t01 = y0 + y1, t23 = y2 + y3, tv = t01 + t23;                            \
    float s = tv.x + tv.y;                                                         \
    f32x2 q0 = y0*y0, q1 = y1*y1, q2 = y2*y2, q3 = y3*y3;                          \
    f32x2 q01 = q0 + q1, q23 = q2 + q3, qv = q01 + q23;                            \
    float q = qv.x + qv.y;                                                         \
    wred2(s, q);                                                                   \
    float mean = s * (1.f/DD);                                                     \
    float qc2  = fmaf(mean*(-(float)DD), mean, q);                                 \
    float var  = fmaxf(qc2 * (1.f/(DD-1)), 0.f);                                   \
    float r = frcp(fsqrt_f(var) + EPSL);                                           \
    float c3 = -(r*mean);                                                          \
    f32x2 RR = {r,r}, C3 = {c3,c3};                                                \
    z0 = pkfma(RR, y0, C3); z1 = pkfma(RR, y1, C3);                                \
    z2 = pkfma(RR, y2, C3); z3 = pkfma(RR, y3, C3);                                \
    if (lane == 0){ float2 o = {0.f, qc2*r*r}; sqp[TI] = o; }                      \
    float4 o1 = {z0.x,z0.y,z1.x,z1.y}, o2 = {z2.x,z2.y,z3.x,z3.y};                 \
    *(float4*)(xp + OFS) = o1; *(float4*)(xp + OFS + 4) = o2;                      \
    XA = *(const float4*)(xp + PFO); XB = *(const float4*)(xp + PFO + 4); }
    ZFSTEP(xa0, xb0, 0,    4*DD, 0)
    ZFSTEP(xa1, xb1, DD,   5*DD, 1)
    ZFSTEP(xa2, xb2, 2*DD, 6*DD, 2)
    ZFSTEP(xa3, xb3, 3*DD, 7*DD, 3)
#undef ZFSTEP
    xp += 4*DD; sqp += 4;
  }
}

/* general path (n1 not identity) — reference-faithful */
__device__ __forceinline__ void zscan_gen(float* __restrict__ XZ,
    const float* __restrict__ n1g, const float* __restrict__ n1b,
    float* __restrict__ ZSQ){
  int b = blockIdx.x, lane = threadIdx.x;
  int bd = lane*8;
  float z[8], g1[8], b1[8];
  #pragma unroll
  for (int k = 0; k < 8; k++) z[k] = 0.f;
  *(float4*)&g1[0] = *(const float4*)(n1g+bd); *(float4*)&g1[4] = *(const float4*)(n1g+bd+4);
  *(float4*)&b1[0] = *(const float4*)(n1b+bd); *(float4*)&b1[4] = *(const float4*)(n1b+bd+4);
  float* xp = XZ + (size_t)b*SENC*DD + bd;
  float2* sqp = (float2*)ZSQ + (size_t)b*SENC;
  for (int t = 0; t < SENC; t++){
    float4 xa = *(const float4*)xp, xb = *(const float4*)(xp + 4);
    float x[8] = {xa.x,xa.y,xa.z,xa.w,xb.x,xb.y,xb.z,xb.w};
    float y[8], s = 0.f, q = 0.f;
    #pragma unroll
    for (int k = 0; k < 8; k++){ y[k] = z[k] + x[k]; s += y[k]; q = fmaf(y[k], y[k], q); }
    wred2(s, q);
    float mean = s * (1.f/DD);
    float var  = fmaxf((q - (float)DD*mean*mean) * (1.f/(DD-1)), 0.f);
    float r = 1.f/(sqrtf(var) + EPSL);
    float sz = 0.f, qz = 0.f;
    #pragma unroll
    for (int k = 0; k < 8; k++){
      z[k] = fmaf(g1[k]*r, y[k]-mean, b1[k]);
      sz += z[k]; qz = fmaf(z[k], z[k], qz);
    }
    wred2(sz, qz);
    if (lane == 0){ float2 o = {sz, qz}; sqp[t] = o; }
    float4 o1 = {z[0],z[1],z[2],z[3]}, o2 = {z[4],z[5],z[6],z[7]};
    *(float4*)xp = o1; *(float4*)(xp + 4) = o2;
    xp += DD;
  }
}

__global__ void __launch_bounds__(64) zscan_kernel(float* __restrict__ XZ,
    const float* __restrict__ n1g, const float* __restrict__ n1b,
    const int* __restrict__ flag, float* __restrict__ ZSQ){
  if (flag[0]) zscan_fast(XZ, ZSQ);
  else         zscan_gen(XZ, n1g, n1b, ZSQ);
}

/* -------- gates[bt][a] = sigmoid((Z[bt,:].Menc[a,:] + cenc[a])*SCALE) ----------- */
__global__ void __launch_bounds__(256) gates_kernel(const float* __restrict__ Zin,
    const float* __restrict__ Menc, const float* __restrict__ cenc,
    float* __restrict__ gates){
  __shared__ float As[32][64];
  __shared__ float Bs[32][64];
  int tid = threadIdx.x;
  int m0 = blockIdx.x*64;
  int ty = tid >> 4, tx = tid & 15;
  float acc[4][4] = {{0.f}};
  for (int k0 = 0; k0 < 512; k0 += 32){
    #pragma unroll
    for (int p = 0; p < 2; p++){
      int row = (tid>>3) + p*32, col = (tid&7)*4;
      float4 va = *(const float4*)(Zin + (size_t)(m0+row)*512 + k0 + col);
      As[col][row]=va.x; As[col+1][row]=va.y; As[col+2][row]=va.z; As[col+3][row]=va.w;
      float4 vb = *(const float4*)(Menc + (size_t)row*512 + k0 + col);
      Bs[col][row]=vb.x; Bs[col+1][row]=vb.y; Bs[col+2][row]=vb.z; Bs[col+3][row]=vb.w;
    }
    __syncthreads();
    #pragma unroll
    for (int kk = 0; kk < 32; kk++){
      float4 a4 = *(const float4*)&As[kk][ty*4];
      float4 b4 = *(const float4*)&Bs[kk][tx*4];
      float au[4] = {a4.x,a4.y,a4.z,a4.w}, bv[4] = {b4.x,b4.y,b4.z,b4.w};
      #pragma unroll
      for (int u = 0; u < 4; u++)
        #pragma unroll
        for (int v = 0; v < 4; v++) acc[u][v] = fmaf(au[u], bv[v], acc[u][v]);
    }
    __syncthreads();
  }
  float cv[4];
  #pragma unroll
  for (int v = 0; v < 4; v++) cv[v] = cenc[tx*4 + v];
  #pragma unroll
  for (int u = 0; u < 4; u++){
    float4 st;
    st.x = frcp(1.f + __expf(-(acc[u][0]+cv[0])*SCALE));
    st.y = frcp(1.f + __expf(-(acc[u][1]+cv[1])*SCALE));
    st.z = frcp(1.f + __expf(-(acc[u][2]+cv[2])*SCALE));
    st.w = frcp(1.f + __expf(-(acc[u][3]+cv[3])*SCALE));
    *(float4*)(gates + (size_t)(m0+ty*4+u)*AA + tx*4) = st;
  }
}

/* ---- encoder av-scan FAST: pk-math, unroll x2, analytic LN closure ------------- */
__device__ __forceinline__ void avscan_fast(const float* __restrict__ Z,
    const float* __restrict__ ZSQ, const float* __restrict__ gates,
    float* __restrict__ avout){
  int bx = blockIdx.x;
  int b = (bx & 7)*4 + ((bx >> 3) & 3);          /* all blocks of batch b on one XCD */
  int a = ((bx >> 5)<<3) + (threadIdx.x >> 6);
  int lane = threadIdx.x & 63;
  int bd = lane*8;
  f32x2 av0 = {0.f,0.f}, av1 = {0.f,0.f}, av2v = {0.f,0.f}, av3 = {0.f,0.f};
  float Qav = 0.f;
  const float*  zp  = Z + (size_t)b*SENC*DD + bd;
  const float4* sp4 = (const float4*)(ZSQ + (size_t)b*SENC*2);
  const float*  gp  = gates + (size_t)b*SENC*AA + a;
  float4 zc0a = *(const float4*)zp,        zc0b = *(const float4*)(zp + 4);
  float4 zc1a = *(const float4*)(zp + DD), zc1b = *(const float4*)(zp + DD + 4);
  float4 sq01 = sp4[0];
  float g0 = gp[0], g1 = gp[AA];
  for (int t = 0; t < SENC; t += 2){
    /* prefetch t+2, t+3 (slack rows allocated; cross-batch touch never consumed) */
    float4 zn0a = *(const float4*)(zp + 2*DD), zn0b = *(const float4*)(zp + 2*DD + 4);
    float4 zn1a = *(const float4*)(zp + 3*DD), zn1b = *(const float4*)(zp + 3*DD + 4);
    float4 sqn = sp4[1];
    float gn0 = gp[2*AA], gn1 = gp[3*AA];
#define AVSTEP(ZA, ZB, SZT, QZT, G) {                                              \
    f32x2 z0 = {ZA.x, ZA.y}, z1 = {ZA.z, ZA.w};                                    \
    f32x2 z2 = {ZB.x, ZB.y}, z3 = {ZB.z, ZB.w};                                    \
    f32x2 p0 = av0*z0, p1 = av1*z1, p2 = av2v*z2, p3 = av3*z3;                     \
    f32x2 s01 = p0 + p1, s23 = p2 + p3, sv = s01 + s23;                            \
    float cav = wredsum(sv.x + sv.y);                                              \
    float g = (G), omg = 1.f - g;                                                  \
    float mean = (g * (1.f/DD)) * (SZT);                                           \
    float a1s = (omg*omg) * Qav;                                                   \
    float a2s = fmaf((g+g)*omg, cav, a1s);                                         \
    float Qy  = fmaf(g*g, (QZT), a2s);                                             \
    float qc2 = fmaf(mean*(-(float)DD), mean, Qy);                                 \
    float var = fmaxf(qc2 * (1.f/(DD-1)), 0.f);                                    \
    float r = frcp(fsqrt_f(var) + EPSL);                                           \
    float c1 = r*omg, c2s = r*g, c3 = -(r*mean);                                   \
    f32x2 C1 = {c1,c1}, C2 = {c2s,c2s}, C3 = {c3,c3};                              \
    av0  = pkfma(C1, av0,  pkfma(C2, z0, C3));                                     \
    av1  = pkfma(C1, av1,  pkfma(C2, z1, C3));                                     \
    av2v = pkfma(C1, av2v, pkfma(C2, z2, C3));                                     \
    av3  = pkfma(C1, av3,  pkfma(C2, z3, C3));                                     \
    Qav = qc2 * (r*r); }
    AVSTEP(zc0a, zc0b, sq01.x, sq01.y, g0)
    AVSTEP(zc1a, zc1b, sq01.z, sq01.w, g1)
#undef AVSTEP
    zc0a = zn0a; zc0b = zn0b; zc1a = zn1a; zc1b = zn1b;
    sq01 = sqn; g0 = gn0; g1 = gn1;
    zp += 2*DD; sp4 += 1; gp += 2*AA;
  }
  float* o = avout + ((size_t)(b*AA + a))*DD + bd;
  float4 o1 = {av0.x,av0.y,av1.x,av1.y}, o2 = {av2v.x,av2v.y,av3.x,av3.y};
  *(float4*)o = o1; *(float4*)(o+4) = o2;
}

/* general path — reference-faithful */
__device__ __forceinline__ void avscan_gen(const float* __restrict__ Z,
    const float* __restrict__ ZSQ, const float* __restrict__ gates,
    const float* __restrict__ n1g, const float* __restrict__ n1b,
    float* __restrict__ avout){
  int bx = blockIdx.x;
  int b = (bx & 7)*4 + ((bx >> 3) & 3);
  int a = ((bx >> 5)<<3) + (threadIdx.x >> 6);
  int lane = threadIdx.x & 63;
  int bd = lane*8;
  float g1[8], b1[8], av[8];
  *(float4*)&g1[0] = *(const float4*)(n1g+bd); *(float4*)&g1[4] = *(const float4*)(n1g+bd+4);
  *(float4*)&b1[0] = *(const float4*)(n1b+bd); *(float4*)&b1[4] = *(const float4*)(n1b+bd+4);
  #pragma unroll
  for (int k = 0; k < 8; k++) av[k] = 0.f;
  float Sav = 0.f, Qav = 0.f;
  const float*  zp = Z + (size_t)b*SENC*DD + bd;
  const float2* sp = (const float2*)ZSQ + (size_t)b*SENC;
  const float*  gp = gates + (size_t)b*SENC*AA + a;
  for (int t = 0; t < SENC; t++){
    float4 za = *(const float4*)zp, zb = *(const float4*)(zp + 4);
    float z[8] = {za.x,za.y,za.z,za.w,zb.x,zb.y,zb.z,zb.w};
    float2 sq = sp[0];
    float g = gp[0];
    float cav = 0.f;
    #pragma unroll
    for (int k = 0; k < 8; k++) cav = fmaf(av[k], z[k], cav);
    cav = wredsum(cav);
    float omg = 1.f - g;
    float Sy = fmaf(g, sq.x - Sav, Sav);
    float Qy = omg*omg*Qav + 2.f*g*omg*cav + g*g*sq.y;
    float mean = Sy * (1.f/DD);
    float var  = fmaxf((Qy - (float)DD*mean*mean) * (1.f/(DD-1)), 0.f);
    float r = 1.f/(sqrtf(var) + EPSL);
    float sn = 0.f, qn = 0.f;
    #pragma unroll
    for (int k = 0; k < 8; k++){
      float y = fmaf(g, z[k]-av[k], av[k]);
      float nv = fmaf(g1[k]*r, y-mean, b1[k]);
      av[k] = nv; sn += nv; qn = fmaf(nv, nv, qn);
    }
    wred2(sn, qn);
    Sav = sn; Qav = qn;
    zp += DD; sp += 1; gp += AA;
  }
  float* o = avout + ((size_t)(b*AA + a))*DD + bd;
  float4 o1 = {av[0],av[1],av[2],av[3]}, o2 = {av[4],av[5],av[6],av[7]};
  *(float4*)o = o1; *(float4*)(o+4) = o2;
}

__global__ void __launch_bounds__(512) avscan_kernel(const float* __restrict__ Z,
    const float* __restrict__ ZSQ, const float* __restrict__ gates,
    const float* __restrict__ n1g, const float* __restrict__ n1b,
    const int* __restrict__ flag, float* __restrict__ avout){
  if (flag[0]) avscan_fast(Z, ZSQ, gates, avout);
  else         avscan_gen(Z, ZSQ, gates, n1g, n1b, avout);
}

/* ------------- f32 GEMM, C[m,n] = sum_k A[m,k]*Bw[n,k] (+bias[n]) --------------- */
__global__ void __launch_bounds__(256) gemm_nt_kernel(const float* __restrict__ Aa,
    const float* __restrict__ Bw, const float* __restrict__ bias,
    void* __restrict__ Cout, int mode){
  __shared__ float As[32][64];
  __shared__ float Bs[32][64];
  int tid = threadIdx.x;
  int m0 = blockIdx.x*64, n0 = blockIdx.y*64;
  int ty = tid >> 4, tx = tid & 15;
  float acc[4][4] = {{0.f}};
  for (int k0 = 0; k0 < 512; k0 += 32){
    #pragma unroll
    for (int p = 0; p < 2; p++){
      int row = (tid>>3) + p*32, col = (tid&7)*4;
      float4 va = *(const float4*)(Aa + (size_t)(m0+row)*512 + k0 + col);
      As[col][row]=va.x; As[col+1][row]=va.y; As[col+2][row]=va.z; As[col+3][row]=va.w;
      float4 vb = *(const float4*)(Bw + (size_t)(n0+row)*512 + k0 + col);
      Bs[col][row]=vb.x; Bs[col+1][row]=vb.y; Bs[col+2][row]=vb.z; Bs[col+3][row]=vb.w;
    }
    __syncthreads();
    #pragma unroll
    for (int kk = 0; kk < 32; kk++){
      float4 a4 = *(const float4*)&As[kk][ty*4];
      float4 b4 = *(const float4*)&Bs[kk][tx*4];
      float au[4] = {a4.x,a4.y,a4.z,a4.w}, bv[4] = {b4.x,b4.y,b4.z,b4.w};
      #pragma unroll
      for (int u = 0; u < 4; u++)
        #pragma unroll
        for (int v = 0; v < 4; v++) acc[u][v] = fmaf(au[u], bv[v], acc[u][v]);
    }
    __syncthreads();
  }
  float bv4[4];
  #pragma unroll
  for (int v = 0; v < 4; v++) bv4[v] = bias ? bias[n0 + tx*4 + v] : 0.f;
  if (mode == 0){
    float* C = (float*)Cout;
    #pragma unroll
    for (int u = 0; u < 4; u++){
      float4 st = {acc[u][0]+bv4[0], acc[u][1]+bv4[1], acc[u][2]+bv4[2], acc[u][3]+bv4[3]};
      *(float4*)(C + (size_t)(m0+ty*4+u)*512 + n0 + tx*4) = st;
    }
  } else {
    unsigned short* C = (unsigned short*)Cout;
    #pragma unroll
    for (int u = 0; u < 4; u++){
      int mm = m0 + ty*4 + u; int bb = mm >> 6, a2 = mm & 63;
      #pragma unroll
      for (int v = 0; v < 4; v++){
        _Float16 hv = (_Float16)(acc[u][v] + bv4[v]);
        C[((size_t)bb*512 + n0 + tx*4 + v)*64 + a2] = __builtin_bit_cast(unsigned short, hv);
      }
    }
  }
}

/* ------------- P16[m][n] (f16) = sum_k A[m,k]*B[k,n] --------------------------- */
__global__ void __launch_bounds__(256) gemm_nn_kernel(const float* __restrict__ Aa,
    const float* __restrict__ Bw, unsigned int* __restrict__ Cout){
  __shared__ float As[32][64];
  __shared__ float Bs[32][64];
  int tid = threadIdx.x;
  int m0 = blockIdx.x*64, n0 = blockIdx.y*64;
  int ty = tid >> 4, tx = tid & 15;
  float acc[4][4] = {{0.f}};
  for (int k0 = 0; k0 < 512; k0 += 32){
    #pragma unroll
    for (int p = 0; p < 2; p++){
      int row = (tid>>3) + p*32, col = (tid&7)*4;
      float4 va = *(const float4*)(Aa + (size_t)(m0+row)*512 + k0 + col);
      As[col][row]=va.x; As[col+1][row]=va.y; As[col+2][row]=va.z; As[col+3][row]=va.w;
      int brow = (tid>>4) + p*16, bcol = (tid&15)*4;
      float4 vb = *(const float4*)(Bw + (size_t)(k0+brow)*512 + n0 + bcol);
      *(float4*)&Bs[brow][bcol] = vb;
    }
    __syncthreads();
    #pragma unroll
    for (int kk = 0; kk < 32; kk++){
      float4 a4 = *(const float4*)&As[kk][ty*4];
      float4 b4 = *(const float4*)&Bs[kk][tx*4];
      float au[4] = {a4.x,a4.y,a4.z,a4.w}, bv[4] = {b4.x,b4.y,b4.z,b4.w};
      #pragma unroll
      for (int u = 0; u < 4; u++)
        #pragma unroll
        for (int v = 0; v < 4; v++) acc[u][v] = fmaf(au[u], bv[v], acc[u][v]);
    }
    __syncthreads();
  }
  #pragma unroll
  for (int u = 0; u < 4; u++){
    uint2 st = { pk16(acc[u][0], acc[u][1]), pk16(acc[u][2], acc[u][3]) };
    *(uint2*)(Cout + (size_t)(m0+ty*4+u)*256 + (n0 + tx*4)/2) = st;
  }
}

/* ------------------------------- decoder scan ----------------------------------- */
/* P and V fragments REGISTER-RESIDENT (no LDS staging, no bank conflicts).         */
/* lane=anchor, w=d-quarter: P[lane][w*128..] = 16 uint4; d0=2*tid: V rows = 16.    */
/* LDS only for broadcast-read zh/att4h and cross-wave part/red2. 2 barriers/step.  */
__global__ void __launch_bounds__(256, 1) dec_kernel(const float* __restrict__ Z,
    const unsigned int* __restrict__ Pg, const unsigned int* __restrict__ Vg,
    const float* __restrict__ cdec, const float* __restrict__ n2g,
    const float* __restrict__ n2b, float* __restrict__ zfin){
  __shared__ unsigned int zh[256];
  __shared__ float part[AA][5];          /* +1 pad: conflict-free b32 reads */
  __shared__ unsigned int att4h[4][32];
  __shared__ float2 red2[4];
  int b = blockIdx.x, tid = threadIdx.x;
  int lane = tid & 63, w = tid >> 6;
  int d0 = tid*2;

  /* P fragment: anchor=lane, dims w*128..w*128+127 -> u32s [(b*64+lane)*256 + w*64 + j] */
  uint4 pf[16];
  const uint4* Pg4 = (const uint4*)(Pg + ((size_t)(b*AA + lane))*256 + w*64);
  #pragma unroll
  for (int j = 0; j < 16; j++) pf[j] = Pg4[j];
  /* V fragment: rows d0, d0+1 over all 64 anchors -> u32s [(b*512+d)*32 + j] */
  uint4 vf0[8], vf1[8];
  const uint4* Vg40 = (const uint4*)(Vg + ((size_t)b*DD + d0)*32);
  const uint4* Vg41 = (const uint4*)(Vg + ((size_t)b*DD + d0 + 1)*32);
  #pragma unroll
  for (int j = 0; j < 8; j++){ vf0[j] = Vg40[j]; vf1[j] = Vg41[j]; }

  float2 zi = *(const float2*)(Z + ((size_t)b*SENC + SENC-1)*DD + d0);
  float z0r = zi.x, z1r = zi.y;
  zh[tid] = pk16(z0r, z1r);
  float cdv = cdec[b*AA + lane];
  float g2a = n2g[d0], g2b = n2g[d0+1], b2a = n2b[d0], b2b = n2b[d0+1];
  __syncthreads();

  for (int t = 0; t < SDEC; t++){
    /* ph1: logit partial (anchor=lane, d-quarter w): P regs x zh broadcast reads */
    float sA[4] = {0.f,0.f,0.f,0.f};
    #pragma unroll
    for (int j = 0; j < 16; j++){
      uint4 zv = *(const uint4*)&zh[w*64 + j*4];
      sA[j&3] = fd2(pf[j].x, zv.x, sA[j&3]);
      sA[j&3] = fd2(pf[j].y, zv.y, sA[j&3]);
      sA[j&3] = fd2(pf[j].z, zv.z, sA[j&3]);
      sA[j&3] = fd2(pf[j].w, zv.w, sA[j&3]);
    }
    part[lane][w] = (sA[0]+sA[1]) + (sA[2]+sA[3]);
    __syncthreads();                               /* A */
    /* ph2: redundant per-wave softmax over 64 anchors */
    float l = (((part[lane][0] + part[lane][1]) + (part[lane][2] + part[lane][3])) + cdv) * SCALE;
    float mx = wredmax(l);
    float e = __expf(l - mx);
    float se = wredsum(e);
    float attv = e * frcp(se);
    float attn = dppself<0x101,0xf>(attv);         /* row_shl:1 -> lane i gets att[i+1] */
    if ((lane & 1) == 0) att4h[w][lane>>1] = pk16(attv, attn);
    asm volatile("s_waitcnt lgkmcnt(0)" ::: "memory");
    /* ph3: dg2 for d0,d0+1: V regs x att4h broadcast reads */
    float aA0 = 0.f, aA1 = 0.f, aB0 = 0.f, aB1 = 0.f;
    #pragma unroll
    for (int j = 0; j < 8; j++){
      uint4 ah = *(const uint4*)&att4h[w][j*4];
      if (j & 1){
        aA1 = fd2(vf0[j].x, ah.x, aA1); aA1 = fd2(vf0[j].y, ah.y, aA1);
        aA1 = fd2(vf0[j].z, ah.z, aA1); aA1 = fd2(vf0[j].w, ah.w, aA1);
        aB1 = fd2(vf1[j].x, ah.x, aB1); aB1 = fd2(vf1[j].y, ah.y, aB1);
        aB1 = fd2(vf1[j].z, ah.z, aB1); aB1 = fd2(vf1[j].w, ah.w, aB1);
      } else {
        aA0 = fd2(vf0[j].x, ah.x, aA0); aA0 = fd2(vf0[j].y, ah.y, aA0);
        aA0 = fd2(vf0[j].z, ah.z, aA0); aA0 = fd2(vf0[j].w, ah.w, aA0);
        aB0 = fd2(vf1[j].x, ah.x, aB0); aB0 = fd2(vf1[j].y, ah.y, aB0);
        aB0 = fd2(vf1[j].z, ah.z, aB0); aB0 = fd2(vf1[j].w, ah.w, aB0);
      }
    }
    float y0 = z0r + (aA0 + aA1), y1 = z1r + (aB0 + aB1);
    float s2 = y0 + y1, q2 = fmaf(y0, y0, y1*y1);
    wred2(s2, q2);
    if (lane == 0){ float2 o = {s2, q2}; red2[w] = o; }
    __syncthreads();                               /* B */
    float2 rA = red2[0], rB = red2[1], rC = red2[2], rD = red2[3];
    float Sy = (rA.x+rB.x)+(rC.x+rD.x), Qy = (rA.y+rB.y)+(rC.y+rD.y);
    float mean = Sy * (1.f/DD);
    float var  = fmaxf((Qy - (float)DD*mean*mean) * (1.f/(DD-1)), 0.f);
    float r = frcp(fsqrt_f(var) + EPSL);
    z0r = fmaf(g2a*r, y0-mean, b2a);
    z1r = fmaf(g2b*r, y1-mean, b2b);
    zh[tid] = pk16(z0r, z1r);                      /* own-wave consumer only */
    asm volatile("s_waitcnt lgkmcnt(0)" ::: "memory");
  }
  zfin[(size_t)b*DD + d0]     = z0r;
  zfin[(size_t)b*DD + d0 + 1] = z1r;
}

/* ---------------- logits = zfin @ voc_W^T + voc_b ------------------------------- */
__global__ void __launch_bounds__(256) logits_kernel(const float* __restrict__ zfin,
    const float* __restrict__ vocW, const float* __restrict__ vocb, float* __restrict__ out){
  __shared__ float zS[NB*DD];
  int tid = threadIdx.x;
  const float4* src = (const float4*)zfin;
  float4* dst = (float4*)zS;
  #pragma unroll
  for (int i = 0; i < 16; i++) dst[tid + i*256] = src[tid + i*256];
  __syncthreads();
  int w = tid >> 6, lane = tid & 63;
  int kq = lane & 3, rp = lane >> 2;
  int r0 = blockIdx.x*128 + w*32 + rp*2, r1 = r0 + 1;
  float acc0[NB], acc1[NB];
  #pragma unroll
  for (int bq = 0; bq < NB; bq++){ acc0[bq] = 0.f; acc1[bq] = 0.f; }
  const float* w0p = vocW + (size_t)r0*DD;
  const float* w1p = vocW + (size_t)r1*DD;
  for (int ks = 0; ks < 32; ks++){
    int koff = ks*16 + kq*4;
    float4 w0 = *(const float4*)(w0p + koff);
    float4 w1 = *(const float4*)(w1p + koff);
    #pragma unroll
    for (int bq = 0; bq < NB; bq++){
      float4 z4 = *(const float4*)&zS[bq*DD + koff];
      acc0[bq] = fmaf(w0.x,z4.x, fmaf(w0.y,z4.y, fmaf(w0.z,z4.z, fmaf(w0.w,z4.w, acc0[bq]))));
      acc1[bq] = fmaf(w1.x,z4.x, fmaf(w1.y,z4.y, fmaf(w1.z,z4.z, fmaf(w1.w,z4.w, acc1[bq]))));
    }
  }
  #pragma unroll
  for (int bq = 0; bq < NB; bq++){
    acc0[bq] += dppz<0xB1,0xf>(acc0[bq]); acc0[bq] += dppz<0x4E,0xf>(acc0[bq]);
    acc1[bq] += dppz<0xB1,0xf>(acc1[bq]); acc1[bq] += dppz<0x4E,0xf>(acc1[bq]);
  }
  if (kq == 0){
    float vb0 = vocb[r0], vb1 = vocb[r1];
    #pragma unroll
    for (int bq = 0; bq < NB; bq++){
      out[(size_t)bq*VOUT + r0] = acc0[bq] + vb0;
      out[(size_t)bq*VOUT + r1] = acc1[bq] + vb1;
    }
  }
}

/* --------------------------- split log_softmax ---------------------------------- */
__global__ void __launch_bounds__(256) lsm1_kernel(const float* __restrict__ out,
    float2* __restrict__ partb){
  int b = blockIdx.x >> 3, c = blockIdx.x & 7;
  const float* row = out + (size_t)b*VOUT + c*4000;
  int tid = threadIdx.x;
  __shared__ float rm[4]; __shared__ float rs[4];
  float mx = -3.4e38f;
  for (int i = tid; i < 4000; i += 256) mx = fmaxf(mx, row[i]);
  mx = wredmax(mx);
  if ((tid & 63) == 0) rm[tid>>6] = mx;
  __syncthreads();
  mx = fmaxf(fmaxf(rm[0],rm[1]), fmaxf(rm[2],rm[3]));
  float sm = 0.f;
  for (int i = tid; i < 4000; i += 256) sm += __expf(row[i] - mx);
  sm = wredsum(sm);
  if ((tid & 63) == 0) rs[tid>>6] = sm;
  __syncthreads();
  if (tid == 0){ float2 o = {mx, rs[0]+rs[1]+rs[2]+rs[3]}; partb[blockIdx.x] = o; }
}
__global__ void __launch_bounds__(256) lsm2_kernel(float* __restrict__ out,
    const float2* __restrict__ partb){
  int b = blockIdx.x >> 3, c = blockIdx.x & 7;
  float M = -3.4e38f, S = 0.f;
  #pragma unroll
  for (int j = 0; j < 8; j++) M = fmaxf(M, partb[b*8+j].x);
  #pragma unroll
  for (int j = 0; j < 8; j++){ float2 p = partb[b*8+j]; S += p.y * __expf(p.x - M); }
  float cns = M + logf(S);
  float* row = out + (size_t)b*VOUT + c*4000;
  for (int i = threadIdx.x; i < 4000; i += 256) row[i] -= cns;
}

extern "C" void kernel_launch(void* const* d_in, const int* in_sizes, int n_in,
                              void* d_out, int out_size, void* d_ws, size_t ws_size,
                              hipStream_t stream){
  (void)in_sizes; (void)n_in; (void)out_size; (void)ws_size;
  const int*   toks      = (const int*)  d_in[0];
  const float* emb_in    = (const float*)d_in[2];
  const float* enc_key_W = (const float*)d_in[4];
  const float* enc_Wq    = (const float*)d_in[5];
  const float* enc_bq    = (const float*)d_in[6];
  const float* enc_Wk    = (const float*)d_in[7];
  const float* enc_bk    = (const float*)d_in[8];
  const float* n1g       = (const float*)d_in[9];
  const float* n1b       = (const float*)d_in[10];
  const float* rdr_Wq    = (const float*)d_in[12];
  const float* rdr_bq    = (const float*)d_in[13];
  const float* rdr_Wk    = (const float*)d_in[14];
  const float* rdr_bk    = (const float*)d_in[15];
  const float* rdr_Wv    = (const float*)d_in[16];
  const float* rdr_bv    = (const float*)d_in[17];
  const float* n2g       = (const float*)d_in[22];
  const float* n2b       = (const float*)d_in[23];
  const float* vocW      = (const float*)d_in[26];
  const float* vocb      = (const float*)d_in[27];
  float* outp = (float*)d_out;

  float* ws = (float*)d_ws;
  size_t off = 0;
  float* Z    = ws + off; off += (size_t)NB*SENC*DD + 4*DD;  /* X/Z in place + slack */
  float* ZSQ  = ws + off; off += (size_t)NB*SENC*2 + 8;      /* + prefetch slack */
  float* av   = ws + off; off += (size_t)NB*AA*DD;
  /* gates [B*SENC][AA] f32 (8MB) aliases Kr+P16 (both written after avscan);
     gates prefetch slack spills into V16 region — also written after avscan */
  float* Kr   = ws + off; float* gates = Kr; off += (size_t)NB*AA*DD;
  unsigned int* P16 = (unsigned int*)(ws + off); off += (size_t)NB*AA*DD/2;
  unsigned int* V16 = (unsigned int*)(ws + off); off += (size_t)NB*AA*DD/2;
  float* Qa   = ws + off; off += (size_t)AA*DD;
  float* Menc = ws + off; off += (size_t)AA*DD;
  float* cenc = ws + off; off += AA;
  float* cdec = ws + off; off += (size_t)NB*AA;
  float* zfin = ws + off; off += (size_t)NB*DD;
  float2* lsp = (float2*)(ws + off); off += 512;
  int*  flag  = (int*)(ws + off); off += 1;

  qa_kernel     <<<AA, 512, 0, stream>>>(enc_key_W, enc_Wq, enc_bq, Qa);
  menc_kernel   <<<AA, 512, 0, stream>>>(Qa, enc_Wk, Menc);
  dotb_kernel   <<<AA/4, 256, 0, stream>>>(Qa, enc_bk, cenc);
  flag_kernel   <<<1, 512, 0, stream>>>(n1g, n1b, flag);
  xgather_kernel<<<NB*SENC/4, 256, 0, stream>>>(toks, emb_in, Z);
  zscan_kernel  <<<NB, 64, 0, stream>>>(Z, n1g, n1b, flag, ZSQ);
  gates_kernel  <<<NB*SENC/64, 256, 0, stream>>>(Z, Menc, cenc, gates);
  avscan_kernel <<<256, 512, 0, stream>>>(Z, ZSQ, gates, n1g, n1b, flag, av);
  gemm_nt_kernel<<<dim3(NB*AA/64, DD/64), 256, 0, stream>>>(av, rdr_Wk, rdr_bk, Kr, 0);
  gemm_nn_kernel<<<dim3(NB*AA/64, DD/64), 256, 0, stream>>>(Kr, rdr_Wq, P16);
  gemm_nt_kernel<<<dim3(NB*AA/64, DD/64), 256, 0, stream>>>(av, rdr_Wv, rdr_bv, V16, 1);
  dotb_kernel   <<<NB*AA/4, 256, 0, stream>>>(Kr, rdr_bq, cdec);
  dec_kernel    <<<NB, 256, 0, stream>>>(Z, P16, V16, cdec, n2g, n2b, zfin);
  logits_kernel <<<VOUT/128, 256, 0, stream>>>(zfin, vocW, vocb, outp);
  lsm1_kernel   <<<NB*8, 256, 0, stream>>>(outp, lsp);
  lsm2_kernel   <<<NB*8, 256, 0, stream>>>(outp, lsp);
}

// Round 8
// 1198.470 us; speedup vs baseline: 2.2125x; 1.0004x over previous
//
#include <hip/hip_runtime.h>
#include <math.h>

#define DD 512
#define AA 64
#define NB 32
#define SENC 1024
#define SDEC 256
#define VOUT 32000
#define EPSL 1e-6f
#define SCALE 0.044194173824159216f   /* 1/sqrt(512) */
#define SQRTD 22.627416997969522f     /* sqrt(512) */

typedef _Float16 h2 __attribute__((ext_vector_type(2)));
typedef float f32x2 __attribute__((ext_vector_type(2)));

/* ---------------- DPP wave reduction helpers (VALU-only) ----------------------- */
template<int C, int R>
__device__ __forceinline__ float dppz(float v){   /* old=0, bound_ctrl=1 */
  return __int_as_float(__builtin_amdgcn_update_dpp(0, __float_as_int(v), C, R, 0xf, true));
}
template<int C, int R>
__device__ __forceinline__ float dppself(float v){ /* old=self, bound_ctrl=0 */
  return __int_as_float(__builtin_amdgcn_update_dpp(__float_as_int(v), __float_as_int(v), C, R, 0xf, false));
}
__device__ __forceinline__ float rlane63(float v){
  return __int_as_float(__builtin_amdgcn_readlane(__float_as_int(v), 63));
}
__device__ __forceinline__ void wred2(float &a, float &b){
  a += dppz<0x111,0xf>(a); b += dppz<0x111,0xf>(b);
  a += dppz<0x112,0xf>(a); b += dppz<0x112,0xf>(b);
  a += dppz<0x114,0xf>(a); b += dppz<0x114,0xf>(b);
  a += dppz<0x118,0xf>(a); b += dppz<0x118,0xf>(b);
  a += dppz<0x142,0xa>(a); b += dppz<0x142,0xa>(b);
  a += dppz<0x143,0xc>(a); b += dppz<0x143,0xc>(b);
  a = rlane63(a); b = rlane63(b);
}
__device__ __forceinline__ float wredsum(float a){
  a += dppz<0x111,0xf>(a); a += dppz<0x112,0xf>(a);
  a += dppz<0x114,0xf>(a); a += dppz<0x118,0xf>(a);
  a += dppz<0x142,0xa>(a); a += dppz<0x143,0xc>(a);
  return rlane63(a);
}
__device__ __forceinline__ float wredmax(float a){
  a = fmaxf(a, dppself<0x111,0xf>(a));
  a = fmaxf(a, dppself<0x112,0xf>(a));
  a = fmaxf(a, dppself<0x114,0xf>(a));
  a = fmaxf(a, dppself<0x118,0xf>(a));
  a = fmaxf(a, dppself<0x142,0xa>(a));
  a = fmaxf(a, dppself<0x143,0xc>(a));
  return rlane63(a);
}
__device__ __forceinline__ unsigned int pk16(float x, float y){
  return __builtin_bit_cast(unsigned int, __builtin_amdgcn_cvt_pkrtz(x, y));
}
__device__ __forceinline__ float fd2(unsigned int a, unsigned int b, float c){
#if __has_builtin(__builtin_amdgcn_fdot2)
  return __builtin_amdgcn_fdot2(__builtin_bit_cast(h2, a), __builtin_bit_cast(h2, b), c, false);
#else
  h2 x = __builtin_bit_cast(h2, a), y = __builtin_bit_cast(h2, b);
  return c + (float)x[0]*(float)y[0] + (float)x[1]*(float)y[1];
#endif
}
/* fast transcendentals: ~1ulp HW ops */
__device__ __forceinline__ float frcp(float x){ float r; asm("v_rcp_f32 %0, %1" : "=v"(r) : "v"(x)); return r; }
__device__ __forceinline__ float fsqrt_f(float x){ float r; asm("v_sqrt_f32 %0, %1" : "=v"(r) : "v"(x)); return r; }
__device__ __forceinline__ f32x2 pkfma(f32x2 a, f32x2 b, f32x2 c){
  return __builtin_elementwise_fma(a, b, c);
}
/* pin a uint4 into VGPRs: empty asm becomes the defining op, so the compiler
   cannot re-materialize (re-load) the value inside a later loop. */
#define KEEP4(v) asm volatile("" : "+v"((v).x), "+v"((v).y), "+v"((v).z), "+v"((v).w))

/* ---------------- Qa = enc_key_W @ enc_Wq^T + enc_bq  [64,512] ---------------- */
__global__ void __launch_bounds__(512) qa_kernel(const float* __restrict__ keyW,
    const float* __restrict__ Wq, const float* __restrict__ bq, float* __restrict__ Qa){
  int a = blockIdx.x, i = threadIdx.x;
  __shared__ float key[DD];
  key[i] = keyW[a*DD + i];
  __syncthreads();
  const float4* w4 = (const float4*)(Wq + (size_t)i*DD);
  const float4* k4 = (const float4*)key;
  float s = 0.f;
  #pragma unroll 4
  for (int j = 0; j < DD/4; j++){
    float4 w = w4[j], k = k4[j];
    s = fmaf(w.x,k.x, fmaf(w.y,k.y, fmaf(w.z,k.z, fmaf(w.w,k.w, s))));
  }
  Qa[a*DD + i] = s + bq[i];
}

/* ------------- Menc = Qa @ enc_Wk  [64,512] ----------------------------------- */
__global__ void __launch_bounds__(512) menc_kernel(const float* __restrict__ Qa,
    const float* __restrict__ Wk, float* __restrict__ Menc){
  int a = blockIdx.x, j = threadIdx.x;
  __shared__ float qa[DD];
  qa[j] = Qa[a*DD + j];
  __syncthreads();
  float s = 0.f;
  #pragma unroll 4
  for (int i = 0; i < DD; i++) s = fmaf(qa[i], Wk[(size_t)i*DD + j], s);
  Menc[a*DD + j] = s;
}

/* ------------- out[m] = X[m,:] . v  (4 rows per block) ------------------------- */
__global__ void __launch_bounds__(256) dotb_kernel(const float* __restrict__ X,
    const float* __restrict__ v, float* __restrict__ out){
  int m = blockIdx.x*4 + (threadIdx.x >> 6);
  int lane = threadIdx.x & 63;
  const float4* x4 = (const float4*)(X + (size_t)m*DD + lane*8);
  const float4* v4 = (const float4*)(v + lane*8);
  float4 a = x4[0], b4 = x4[1], c = v4[0], d = v4[1];
  float s = a.x*c.x;
  s = fmaf(a.y,c.y, s); s = fmaf(a.z,c.z, s); s = fmaf(a.w,c.w, s);
  s = fmaf(b4.x,d.x, s); s = fmaf(b4.y,d.y, s); s = fmaf(b4.z,d.z, s); s = fmaf(b4.w,d.w, s);
  s = wredsum(s);
  if (lane == 0) out[m] = s;
}

/* ------------- flag = all(n1g==1) && all(n1b==0) ------------------------------- */
__global__ void __launch_bounds__(512) flag_kernel(const float* __restrict__ g,
    const float* __restrict__ b, int* __restrict__ flag){
  __shared__ int s;
  if (threadIdx.x == 0) s = 1;
  __syncthreads();
  bool ok = (g[threadIdx.x] == 1.0f) && (b[threadIdx.x] == 0.0f);
  if (!ok) atomicAnd(&s, 0);
  __syncthreads();
  if (threadIdx.x == 0) flag[0] = s;
}

/* -------- X[b,t,:] = emb[tok[b,t],:] * sqrtD  (pre-gather, fully parallel) ------ */
__global__ void __launch_bounds__(256) xgather_kernel(const int* __restrict__ toks,
    const float* __restrict__ emb, float* __restrict__ X){
  int row = blockIdx.x*4 + (threadIdx.x >> 6);
  int lane = threadIdx.x & 63;
  int tok = toks[row];
  const float4* src = (const float4*)(emb + (size_t)tok*DD + lane*8);
  float4 a = src[0], b = src[1];
  a.x*=SQRTD; a.y*=SQRTD; a.z*=SQRTD; a.w*=SQRTD;
  b.x*=SQRTD; b.y*=SQRTD; b.z*=SQRTD; b.w*=SQRTD;
  float4* dst = (float4*)(X + (size_t)row*DD + lane*8);
  dst[0] = a; dst[1] = b;
}

/* --------- encoder z-scan: in-place X -> Z, pk-math FAST path ------------------- */
__device__ __forceinline__ void zscan_fast(float* __restrict__ XZ, float* __restrict__ ZSQ){
  int b = blockIdx.x, lane = threadIdx.x;
  int bd = lane*8;
  f32x2 z0 = {0.f,0.f}, z1 = {0.f,0.f}, z2 = {0.f,0.f}, z3 = {0.f,0.f};
  float* xp = XZ + (size_t)b*SENC*DD + bd;
  float2* sqp = (float2*)ZSQ + (size_t)b*SENC;
  float4 xa0 = *(const float4*)(xp       ), xb0 = *(const float4*)(xp        + 4);
  float4 xa1 = *(const float4*)(xp + DD  ), xb1 = *(const float4*)(xp + DD   + 4);
  float4 xa2 = *(const float4*)(xp + 2*DD), xb2 = *(const float4*)(xp + 2*DD + 4);
  float4 xa3 = *(const float4*)(xp + 3*DD), xb3 = *(const float4*)(xp + 3*DD + 4);
  for (int t = 0; t < SENC; t += 4){
#define ZFSTEP(XA, XB, OFS, PFO, TI) {                                             \
    f32x2 y0 = z0 + f32x2{XA.x, XA.y}, y1 = z1 + f32x2{XA.z, XA.w};                \
    f32x2 y2 = z2 + f32x2{XB.x, XB.y}, y3 = z3 + f32x2{XB.z, XB.w};                \
    f32x2 t01 = y0 + y1, t23 = y2 + y3, tv = t01 + t23;                            \
    float s = tv.x + tv.y;                                                         \
    f32x2 q0 = y0*y0, q1 = y1*y1, q2 = y2*y2, q3 = y3*y3;                          \
    f32x2 q01 = q0 + q1, q23 = q2 + q3, qv = q01 + q23;                            \
    float q = qv.x + qv.y;                                                         \
    wred2(s, q);                                                                   \
    float mean = s * (1.f/DD);                                                     \
    float qc2  = fmaf(mean*(-(float)DD), mean, q);                                 \
    float var  = fmaxf(qc2 * (1.f/(DD-1)), 0.f);                                   \
    float r = frcp(fsqrt_f(var) + EPSL);                                           \
    float c3 = -(r*mean);                                                          \
    f32x2 RR = {r,r}, C3 = {c3,c3};                                                \
    z0 = pkfma(RR, y0, C3); z1 = pkfma(RR, y1, C3);                                \
    z2 = pkfma(RR, y2, C3); z3 = pkfma(RR, y3, C3);                                \
    if (lane == 0){ float2 o = {0.f, qc2*r*r}; sqp[TI] = o; }                      \
    float4 o1 = {z0.x,z0.y,z1.x,z1.y}, o2 = {z2.x,z2.y,z3.x,z3.y};                 \
    *(float4*)(xp + OFS) = o1; *(float4*)(xp + OFS + 4) = o2;                      \
    XA = *(const float4*)(xp + PFO); XB = *(const float4*)(xp + PFO + 4); }
    ZFSTEP(xa0, xb0, 0,    4*DD, 0)
    ZFSTEP(xa1, xb1, DD,   5*DD, 1)
    ZFSTEP(xa2, xb2, 2*DD, 6*DD, 2)
    ZFSTEP(xa3, xb3, 3*DD, 7*DD, 3)
#undef ZFSTEP
    xp += 4*DD; sqp += 4;
  }
}

/* general path (n1 not identity) — reference-faithful */
__device__ __forceinline__ void zscan_gen(float* __restrict__ XZ,
    const float* __restrict__ n1g, const float* __restrict__ n1b,
    float* __restrict__ ZSQ){
  int b = blockIdx.x, lane = threadIdx.x;
  int bd = lane*8;
  float z[8], g1[8], b1[8];
  #pragma unroll
  for (int k = 0; k < 8; k++) z[k] = 0.f;
  *(float4*)&g1[0] = *(const float4*)(n1g+bd); *(float4*)&g1[4] = *(const float4*)(n1g+bd+4);
  *(float4*)&b1[0] = *(const float4*)(n1b+bd); *(float4*)&b1[4] = *(const float4*)(n1b+bd+4);
  float* xp = XZ + (size_t)b*SENC*DD + bd;
  float2* sqp = (float2*)ZSQ + (size_t)b*SENC;
  for (int t = 0; t < SENC; t++){
    float4 xa = *(const float4*)xp, xb = *(const float4*)(xp + 4);
    float x[8] = {xa.x,xa.y,xa.z,xa.w,xb.x,xb.y,xb.z,xb.w};
    float y[8], s = 0.f, q = 0.f;
    #pragma unroll
    for (int k = 0; k < 8; k++){ y[k] = z[k] + x[k]; s += y[k]; q = fmaf(y[k], y[k], q); }
    wred2(s, q);
    float mean = s * (1.f/DD);
    float var  = fmaxf((q - (float)DD*mean*mean) * (1.f/(DD-1)), 0.f);
    float r = 1.f/(sqrtf(var) + EPSL);
    float sz = 0.f, qz = 0.f;
    #pragma unroll
    for (int k = 0; k < 8; k++){
      z[k] = fmaf(g1[k]*r, y[k]-mean, b1[k]);
      sz += z[k]; qz = fmaf(z[k], z[k], qz);
    }
    wred2(sz, qz);
    if (lane == 0){ float2 o = {sz, qz}; sqp[t] = o; }
    float4 o1 = {z[0],z[1],z[2],z[3]}, o2 = {z[4],z[5],z[6],z[7]};
    *(float4*)xp = o1; *(float4*)(xp + 4) = o2;
    xp += DD;
  }
}

__global__ void __launch_bounds__(64) zscan_kernel(float* __restrict__ XZ,
    const float* __restrict__ n1g, const float* __restrict__ n1b,
    const int* __restrict__ flag, float* __restrict__ ZSQ){
  if (flag[0]) zscan_fast(XZ, ZSQ);
  else         zscan_gen(XZ, n1g, n1b, ZSQ);
}

/* -------- gates[bt][a] = sigmoid((Z[bt,:].Menc[a,:] + cenc[a])*SCALE) ----------- */
__global__ void __launch_bounds__(256) gates_kernel(const float* __restrict__ Zin,
    const float* __restrict__ Menc, const float* __restrict__ cenc,
    float* __restrict__ gates){
  __shared__ float As[32][64];
  __shared__ float Bs[32][64];
  int tid = threadIdx.x;
  int m0 = blockIdx.x*64;
  int ty = tid >> 4, tx = tid & 15;
  float acc[4][4] = {{0.f}};
  for (int k0 = 0; k0 < 512; k0 += 32){
    #pragma unroll
    for (int p = 0; p < 2; p++){
      int row = (tid>>3) + p*32, col = (tid&7)*4;
      float4 va = *(const float4*)(Zin + (size_t)(m0+row)*512 + k0 + col);
      As[col][row]=va.x; As[col+1][row]=va.y; As[col+2][row]=va.z; As[col+3][row]=va.w;
      float4 vb = *(const float4*)(Menc + (size_t)row*512 + k0 + col);
      Bs[col][row]=vb.x; Bs[col+1][row]=vb.y; Bs[col+2][row]=vb.z; Bs[col+3][row]=vb.w;
    }
    __syncthreads();
    #pragma unroll
    for (int kk = 0; kk < 32; kk++){
      float4 a4 = *(const float4*)&As[kk][ty*4];
      float4 b4 = *(const float4*)&Bs[kk][tx*4];
      float au[4] = {a4.x,a4.y,a4.z,a4.w}, bv[4] = {b4.x,b4.y,b4.z,b4.w};
      #pragma unroll
      for (int u = 0; u < 4; u++)
        #pragma unroll
        for (int v = 0; v < 4; v++) acc[u][v] = fmaf(au[u], bv[v], acc[u][v]);
    }
    __syncthreads();
  }
  float cv[4];
  #pragma unroll
  for (int v = 0; v < 4; v++) cv[v] = cenc[tx*4 + v];
  #pragma unroll
  for (int u = 0; u < 4; u++){
    float4 st;
    st.x = frcp(1.f + __expf(-(acc[u][0]+cv[0])*SCALE));
    st.y = frcp(1.f + __expf(-(acc[u][1]+cv[1])*SCALE));
    st.z = frcp(1.f + __expf(-(acc[u][2]+cv[2])*SCALE));
    st.w = frcp(1.f + __expf(-(acc[u][3]+cv[3])*SCALE));
    *(float4*)(gates + (size_t)(m0+ty*4+u)*AA + tx*4) = st;
  }
}

/* ---- encoder av-scan FAST: pk-math, unroll x2, analytic LN closure ------------- */
__device__ __forceinline__ void avscan_fast(const float* __restrict__ Z,
    const float* __restrict__ ZSQ, const float* __restrict__ gates,
    float* __restrict__ avout){
  int bx = blockIdx.x;
  int b = (bx & 7)*4 + ((bx >> 3) & 3);          /* all blocks of batch b on one XCD */
  int a = ((bx >> 5)<<3) + (threadIdx.x >> 6);
  int lane = threadIdx.x & 63;
  int bd = lane*8;
  f32x2 av0 = {0.f,0.f}, av1 = {0.f,0.f}, av2v = {0.f,0.f}, av3 = {0.f,0.f};
  float Qav = 0.f;
  const float*  zp  = Z + (size_t)b*SENC*DD + bd;
  const float4* sp4 = (const float4*)(ZSQ + (size_t)b*SENC*2);
  const float*  gp  = gates + (size_t)b*SENC*AA + a;
  float4 zc0a = *(const float4*)zp,        zc0b = *(const float4*)(zp + 4);
  float4 zc1a = *(const float4*)(zp + DD), zc1b = *(const float4*)(zp + DD + 4);
  float4 sq01 = sp4[0];
  float g0 = gp[0], g1 = gp[AA];
  for (int t = 0; t < SENC; t += 2){
    /* prefetch t+2, t+3 (slack rows allocated; cross-batch touch never consumed) */
    float4 zn0a = *(const float4*)(zp + 2*DD), zn0b = *(const float4*)(zp + 2*DD + 4);
    float4 zn1a = *(const float4*)(zp + 3*DD), zn1b = *(const float4*)(zp + 3*DD + 4);
    float4 sqn = sp4[1];
    float gn0 = gp[2*AA], gn1 = gp[3*AA];
#define AVSTEP(ZA, ZB, SZT, QZT, G) {                                              \
    f32x2 z0 = {ZA.x, ZA.y}, z1 = {ZA.z, ZA.w};                                    \
    f32x2 z2 = {ZB.x, ZB.y}, z3 = {ZB.z, ZB.w};                                    \
    f32x2 p0 = av0*z0, p1 = av1*z1, p2 = av2v*z2, p3 = av3*z3;                     \
    f32x2 s01 = p0 + p1, s23 = p2 + p3, sv = s01 + s23;                            \
    float cav = wredsum(sv.x + sv.y);                                              \
    float g = (G), omg = 1.f - g;                                                  \
    float mean = (g * (1.f/DD)) * (SZT);                                           \
    float a1s = (omg*omg) * Qav;                                                   \
    float a2s = fmaf((g+g)*omg, cav, a1s);                                         \
    float Qy  = fmaf(g*g, (QZT), a2s);                                             \
    float qc2 = fmaf(mean*(-(float)DD), mean, Qy);                                 \
    float var = fmaxf(qc2 * (1.f/(DD-1)), 0.f);                                    \
    float r = frcp(fsqrt_f(var) + EPSL);                                           \
    float c1 = r*omg, c2s = r*g, c3 = -(r*mean);                                   \
    f32x2 C1 = {c1,c1}, C2 = {c2s,c2s}, C3 = {c3,c3};                              \
    av0  = pkfma(C1, av0,  pkfma(C2, z0, C3));                                     \
    av1  = pkfma(C1, av1,  pkfma(C2, z1, C3));                                     \
    av2v = pkfma(C1, av2v, pkfma(C2, z2, C3));                                     \
    av3  = pkfma(C1, av3,  pkfma(C2, z3, C3));                                     \
    Qav = qc2 * (r*r); }
    AVSTEP(zc0a, zc0b, sq01.x, sq01.y, g0)
    AVSTEP(zc1a, zc1b, sq01.z, sq01.w, g1)
#undef AVSTEP
    zc0a = zn0a; zc0b = zn0b; zc1a = zn1a; zc1b = zn1b;
    sq01 = sqn; g0 = gn0; g1 = gn1;
    zp += 2*DD; sp4 += 1; gp += 2*AA;
  }
  float* o = avout + ((size_t)(b*AA + a))*DD + bd;
  float4 o1 = {av0.x,av0.y,av1.x,av1.y}, o2 = {av2v.x,av2v.y,av3.x,av3.y};
  *(float4*)o = o1; *(float4*)(o+4) = o2;
}

/* general path — reference-faithful */
__device__ __forceinline__ void avscan_gen(const float* __restrict__ Z,
    const float* __restrict__ ZSQ, const float* __restrict__ gates,
    const float* __restrict__ n1g, const float* __restrict__ n1b,
    float* __restrict__ avout){
  int bx = blockIdx.x;
  int b = (bx & 7)*4 + ((bx >> 3) & 3);
  int a = ((bx >> 5)<<3) + (threadIdx.x >> 6);
  int lane = threadIdx.x & 63;
  int bd = lane*8;
  float g1[8], b1[8], av[8];
  *(float4*)&g1[0] = *(const float4*)(n1g+bd); *(float4*)&g1[4] = *(const float4*)(n1g+bd+4);
  *(float4*)&b1[0] = *(const float4*)(n1b+bd); *(float4*)&b1[4] = *(const float4*)(n1b+bd+4);
  #pragma unroll
  for (int k = 0; k < 8; k++) av[k] = 0.f;
  float Sav = 0.f, Qav = 0.f;
  const float*  zp = Z + (size_t)b*SENC*DD + bd;
  const float2* sp = (const float2*)ZSQ + (size_t)b*SENC;
  const float*  gp = gates + (size_t)b*SENC*AA + a;
  for (int t = 0; t < SENC; t++){
    float4 za = *(const float4*)zp, zb = *(const float4*)(zp + 4);
    float z[8] = {za.x,za.y,za.z,za.w,zb.x,zb.y,zb.z,zb.w};
    float2 sq = sp[0];
    float g = gp[0];
    float cav = 0.f;
    #pragma unroll
    for (int k = 0; k < 8; k++) cav = fmaf(av[k], z[k], cav);
    cav = wredsum(cav);
    float omg = 1.f - g;
    float Sy = fmaf(g, sq.x - Sav, Sav);
    float Qy = omg*omg*Qav + 2.f*g*omg*cav + g*g*sq.y;
    float mean = Sy * (1.f/DD);
    float var  = fmaxf((Qy - (float)DD*mean*mean) * (1.f/(DD-1)), 0.f);
    float r = 1.f/(sqrtf(var) + EPSL);
    float sn = 0.f, qn = 0.f;
    #pragma unroll
    for (int k = 0; k < 8; k++){
      float y = fmaf(g, z[k]-av[k], av[k]);
      float nv = fmaf(g1[k]*r, y-mean, b1[k]);
      av[k] = nv; sn += nv; qn = fmaf(nv, nv, qn);
    }
    wred2(sn, qn);
    Sav = sn; Qav = qn;
    zp += DD; sp += 1; gp += AA;
  }
  float* o = avout + ((size_t)(b*AA + a))*DD + bd;
  float4 o1 = {av[0],av[1],av[2],av[3]}, o2 = {av[4],av[5],av[6],av[7]};
  *(float4*)o = o1; *(float4*)(o+4) = o2;
}

__global__ void __launch_bounds__(512) avscan_kernel(const float* __restrict__ Z,
    const float* __restrict__ ZSQ, const float* __restrict__ gates,
    const float* __restrict__ n1g, const float* __restrict__ n1b,
    const int* __restrict__ flag, float* __restrict__ avout){
  if (flag[0]) avscan_fast(Z, ZSQ, gates, avout);
  else         avscan_gen(Z, ZSQ, gates, n1g, n1b, avout);
}

/* ------------- f32 GEMM, C[m,n] = sum_k A[m,k]*Bw[n,k] (+bias[n]) --------------- */
__global__ void __launch_bounds__(256) gemm_nt_kernel(const float* __restrict__ Aa,
    const float* __restrict__ Bw, const float* __restrict__ bias,
    void* __restrict__ Cout, int mode){
  __shared__ float As[32][64];
  __shared__ float Bs[32][64];
  int tid = threadIdx.x;
  int m0 = blockIdx.x*64, n0 = blockIdx.y*64;
  int ty = tid >> 4, tx = tid & 15;
  float acc[4][4] = {{0.f}};
  for (int k0 = 0; k0 < 512; k0 += 32){
    #pragma unroll
    for (int p = 0; p < 2; p++){
      int row = (tid>>3) + p*32, col = (tid&7)*4;
      float4 va = *(const float4*)(Aa + (size_t)(m0+row)*512 + k0 + col);
      As[col][row]=va.x; As[col+1][row]=va.y; As[col+2][row]=va.z; As[col+3][row]=va.w;
      float4 vb = *(const float4*)(Bw + (size_t)(n0+row)*512 + k0 + col);
      Bs[col][row]=vb.x; Bs[col+1][row]=vb.y; Bs[col+2][row]=vb.z; Bs[col+3][row]=vb.w;
    }
    __syncthreads();
    #pragma unroll
    for (int kk = 0; kk < 32; kk++){
      float4 a4 = *(const float4*)&As[kk][ty*4];
      float4 b4 = *(const float4*)&Bs[kk][tx*4];
      float au[4] = {a4.x,a4.y,a4.z,a4.w}, bv[4] = {b4.x,b4.y,b4.z,b4.w};
      #pragma unroll
      for (int u = 0; u < 4; u++)
        #pragma unroll
        for (int v = 0; v < 4; v++) acc[u][v] = fmaf(au[u], bv[v], acc[u][v]);
    }
    __syncthreads();
  }
  float bv4[4];
  #pragma unroll
  for (int v = 0; v < 4; v++) bv4[v] = bias ? bias[n0 + tx*4 + v] : 0.f;
  if (mode == 0){
    float* C = (float*)Cout;
    #pragma unroll
    for (int u = 0; u < 4; u++){
      float4 st = {acc[u][0]+bv4[0], acc[u][1]+bv4[1], acc[u][2]+bv4[2], acc[u][3]+bv4[3]};
      *(float4*)(C + (size_t)(m0+ty*4+u)*512 + n0 + tx*4) = st;
    }
  } else {
    unsigned short* C = (unsigned short*)Cout;
    #pragma unroll
    for (int u = 0; u < 4; u++){
      int mm = m0 + ty*4 + u; int bb = mm >> 6, a2 = mm & 63;
      #pragma unroll
      for (int v = 0; v < 4; v++){
        _Float16 hv = (_Float16)(acc[u][v] + bv4[v]);
        C[((size_t)bb*512 + n0 + tx*4 + v)*64 + a2] = __builtin_bit_cast(unsigned short, hv);
      }
    }
  }
}

/* ------------- P16[m][n] (f16) = sum_k A[m,k]*B[k,n] --------------------------- */
__global__ void __launch_bounds__(256) gemm_nn_kernel(const float* __restrict__ Aa,
    const float* __restrict__ Bw, unsigned int* __restrict__ Cout){
  __shared__ float As[32][64];
  __shared__ float Bs[32][64];
  int tid = threadIdx.x;
  int m0 = blockIdx.x*64, n0 = blockIdx.y*64;
  int ty = tid >> 4, tx = tid & 15;
  float acc[4][4] = {{0.f}};
  for (int k0 = 0; k0 < 512; k0 += 32){
    #pragma unroll
    for (int p = 0; p < 2; p++){
      int row = (tid>>3) + p*32, col = (tid&7)*4;
      float4 va = *(const float4*)(Aa + (size_t)(m0+row)*512 + k0 + col);
      As[col][row]=va.x; As[col+1][row]=va.y; As[col+2][row]=va.z; As[col+3][row]=va.w;
      int brow = (tid>>4) + p*16, bcol = (tid&15)*4;
      float4 vb = *(const float4*)(Bw + (size_t)(k0+brow)*512 + n0 + bcol);
      *(float4*)&Bs[brow][bcol] = vb;
    }
    __syncthreads();
    #pragma unroll
    for (int kk = 0; kk < 32; kk++){
      float4 a4 = *(const float4*)&As[kk][ty*4];
      float4 b4 = *(const float4*)&Bs[kk][tx*4];
      float au[4] = {a4.x,a4.y,a4.z,a4.w}, bv[4] = {b4.x,b4.y,b4.z,b4.w};
      #pragma unroll
      for (int u = 0; u < 4; u++)
        #pragma unroll
        for (int v = 0; v < 4; v++) acc[u][v] = fmaf(au[u], bv[v], acc[u][v]);
    }
    __syncthreads();
  }
  #pragma unroll
  for (int u = 0; u < 4; u++){
    uint2 st = { pk16(acc[u][0], acc[u][1]), pk16(acc[u][2], acc[u][3]) };
    *(uint2*)(Cout + (size_t)(m0+ty*4+u)*256 + (n0 + tx*4)/2) = st;
  }
}

/* ------------------------------- decoder scan ----------------------------------- */
/* P and V fragments register-resident, PINNED via KEEP4 (R7 showed the compiler    */
/* sank the loads back into the loop: VGPR_Count=84 < the 128 regs needed).         */
__global__ void __launch_bounds__(256, 1) dec_kernel(const float* __restrict__ Z,
    const unsigned int* __restrict__ Pg, const unsigned int* __restrict__ Vg,
    const float* __restrict__ cdec, const float* __restrict__ n2g,
    const float* __restrict__ n2b, float* __restrict__ zfin){
  __shared__ unsigned int zh[256];
  __shared__ float part[AA][5];          /* +1 pad: conflict-free b32 reads */
  __shared__ unsigned int att4h[4][32];
  __shared__ float2 red2[4];
  int b = blockIdx.x, tid = threadIdx.x;
  int lane = tid & 63, w = tid >> 6;
  int d0 = tid*2;

  /* P fragment: anchor=lane, dims w*128..w*128+127 -> u32s [(b*64+lane)*256 + w*64 + j] */
  uint4 pf[16];
  const uint4* Pg4 = (const uint4*)(Pg + ((size_t)(b*AA + lane))*256 + w*64);
  #pragma unroll
  for (int j = 0; j < 16; j++) pf[j] = Pg4[j];
  /* V fragment: rows d0, d0+1 over all 64 anchors -> u32s [(b*512+d)*32 + j] */
  uint4 vf0[8], vf1[8];
  const uint4* Vg40 = (const uint4*)(Vg + ((size_t)b*DD + d0)*32);
  const uint4* Vg41 = (const uint4*)(Vg + ((size_t)b*DD + d0 + 1)*32);
  #pragma unroll
  for (int j = 0; j < 8; j++){ vf0[j] = Vg40[j]; vf1[j] = Vg41[j]; }
  /* pin all fragments into VGPRs (defeat load re-materialization) */
  #pragma unroll
  for (int j = 0; j < 16; j++){ KEEP4(pf[j]); }
  #pragma unroll
  for (int j = 0; j < 8; j++){ KEEP4(vf0[j]); KEEP4(vf1[j]); }

  float2 zi = *(const float2*)(Z + ((size_t)b*SENC + SENC-1)*DD + d0);
  float z0r = zi.x, z1r = zi.y;
  zh[tid] = pk16(z0r, z1r);
  float cdv = cdec[b*AA + lane];
  float g2a = n2g[d0], g2b = n2g[d0+1], b2a = n2b[d0], b2b = n2b[d0+1];
  __syncthreads();

  for (int t = 0; t < SDEC; t++){
    /* ph1: logit partial (anchor=lane, d-quarter w): P regs x zh broadcast reads */
    float sA[4] = {0.f,0.f,0.f,0.f};
    #pragma unroll
    for (int j = 0; j < 16; j++){
      uint4 zv = *(const uint4*)&zh[w*64 + j*4];
      sA[j&3] = fd2(pf[j].x, zv.x, sA[j&3]);
      sA[j&3] = fd2(pf[j].y, zv.y, sA[j&3]);
      sA[j&3] = fd2(pf[j].z, zv.z, sA[j&3]);
      sA[j&3] = fd2(pf[j].w, zv.w, sA[j&3]);
    }
    part[lane][w] = (sA[0]+sA[1]) + (sA[2]+sA[3]);
    __syncthreads();                               /* A */
    /* ph2: redundant per-wave softmax over 64 anchors */
    float l = (((part[lane][0] + part[lane][1]) + (part[lane][2] + part[lane][3])) + cdv) * SCALE;
    float mx = wredmax(l);
    float e = __expf(l - mx);
    float se = wredsum(e);
    float attv = e * frcp(se);
    float attn = dppself<0x101,0xf>(attv);         /* row_shl:1 -> lane i gets att[i+1] */
    if ((lane & 1) == 0) att4h[w][lane>>1] = pk16(attv, attn);
    asm volatile("s_waitcnt lgkmcnt(0)" ::: "memory");
    /* ph3: dg2 for d0,d0+1: V regs x att4h broadcast reads */
    float aA0 = 0.f, aA1 = 0.f, aB0 = 0.f, aB1 = 0.f;
    #pragma unroll
    for (int j = 0; j < 8; j++){
      uint4 ah = *(const uint4*)&att4h[w][j*4];
      if (j & 1){
        aA1 = fd2(vf0[j].x, ah.x, aA1); aA1 = fd2(vf0[j].y, ah.y, aA1);
        aA1 = fd2(vf0[j].z, ah.z, aA1); aA1 = fd2(vf0[j].w, ah.w, aA1);
        aB1 = fd2(vf1[j].x, ah.x, aB1); aB1 = fd2(vf1[j].y, ah.y, aB1);
        aB1 = fd2(vf1[j].z, ah.z, aB1); aB1 = fd2(vf1[j].w, ah.w, aB1);
      } else {
        aA0 = fd2(vf0[j].x, ah.x, aA0); aA0 = fd2(vf0[j].y, ah.y, aA0);
        aA0 = fd2(vf0[j].z, ah.z, aA0); aA0 = fd2(vf0[j].w, ah.w, aA0);
        aB0 = fd2(vf1[j].x, ah.x, aB0); aB0 = fd2(vf1[j].y, ah.y, aB0);
        aB0 = fd2(vf1[j].w, ah.w, aB0); aB0 = fd2(vf1[j].z, ah.z, aB0);
      }
    }
    float y0 = z0r + (aA0 + aA1), y1 = z1r + (aB0 + aB1);
    float s2 = y0 + y1, q2 = fmaf(y0, y0, y1*y1);
    wred2(s2, q2);
    if (lane == 0){ float2 o = {s2, q2}; red2[w] = o; }
    __syncthreads();                               /* B */
    float2 rA = red2[0], rB = red2[1], rC = red2[2], rD = red2[3];
    float Sy = (rA.x+rB.x)+(rC.x+rD.x), Qy = (rA.y+rB.y)+(rC.y+rD.y);
    float mean = Sy * (1.f/DD);
    float var  = fmaxf((Qy - (float)DD*mean*mean) * (1.f/(DD-1)), 0.f);
    float r = frcp(fsqrt_f(var) + EPSL);
    z0r = fmaf(g2a*r, y0-mean, b2a);
    z1r = fmaf(g2b*r, y1-mean, b2b);
    zh[tid] = pk16(z0r, z1r);                      /* own-wave consumer only */
    asm volatile("s_waitcnt lgkmcnt(0)" ::: "memory");
  }
  zfin[(size_t)b*DD + d0]     = z0r;
  zfin[(size_t)b*DD + d0 + 1] = z1r;
}

/* ---------------- logits = zfin @ voc_W^T + voc_b ------------------------------- */
__global__ void __launch_bounds__(256) logits_kernel(const float* __restrict__ zfin,
    const float* __restrict__ vocW, const float* __restrict__ vocb, float* __restrict__ out){
  __shared__ float zS[NB*DD];
  int tid = threadIdx.x;
  const float4* src = (const float4*)zfin;
  float4* dst = (float4*)zS;
  #pragma unroll
  for (int i = 0; i < 16; i++) dst[tid + i*256] = src[tid + i*256];
  __syncthreads();
  int w = tid >> 6, lane = tid & 63;
  int kq = lane & 3, rp = lane >> 2;
  int r0 = blockIdx.x*128 + w*32 + rp*2, r1 = r0 + 1;
  float acc0[NB], acc1[NB];
  #pragma unroll
  for (int bq = 0; bq < NB; bq++){ acc0[bq] = 0.f; acc1[bq] = 0.f; }
  const float* w0p = vocW + (size_t)r0*DD;
  const float* w1p = vocW + (size_t)r1*DD;
  for (int ks = 0; ks < 32; ks++){
    int koff = ks*16 + kq*4;
    float4 w0 = *(const float4*)(w0p + koff);
    float4 w1 = *(const float4*)(w1p + koff);
    #pragma unroll
    for (int bq = 0; bq < NB; bq++){
      float4 z4 = *(const float4*)&zS[bq*DD + koff];
      acc0[bq] = fmaf(w0.x,z4.x, fmaf(w0.y,z4.y, fmaf(w0.z,z4.z, fmaf(w0.w,z4.w, acc0[bq]))));
      acc1[bq] = fmaf(w1.x,z4.x, fmaf(w1.y,z4.y, fmaf(w1.z,z4.z, fmaf(w1.w,z4.w, acc1[bq]))));
    }
  }
  #pragma unroll
  for (int bq = 0; bq < NB; bq++){
    acc0[bq] += dppz<0xB1,0xf>(acc0[bq]); acc0[bq] += dppz<0x4E,0xf>(acc0[bq]);
    acc1[bq] += dppz<0xB1,0xf>(acc1[bq]); acc1[bq] += dppz<0x4E,0xf>(acc1[bq]);
  }
  if (kq == 0){
    float vb0 = vocb[r0], vb1 = vocb[r1];
    #pragma unroll
    for (int bq = 0; bq < NB; bq++){
      out[(size_t)bq*VOUT + r0] = acc0[bq] + vb0;
      out[(size_t)bq*VOUT + r1] = acc1[bq] + vb1;
    }
  }
}

/* --------------------------- split log_softmax ---------------------------------- */
__global__ void __launch_bounds__(256) lsm1_kernel(const float* __restrict__ out,
    float2* __restrict__ partb){
  int b = blockIdx.x >> 3, c = blockIdx.x & 7;
  const float* row = out + (size_t)b*VOUT + c*4000;
  int tid = threadIdx.x;
  __shared__ float rm[4]; __shared__ float rs[4];
  float mx = -3.4e38f;
  for (int i = tid; i < 4000; i += 256) mx = fmaxf(mx, row[i]);
  mx = wredmax(mx);
  if ((tid & 63) == 0) rm[tid>>6] = mx;
  __syncthreads();
  mx = fmaxf(fmaxf(rm[0],rm[1]), fmaxf(rm[2],rm[3]));
  float sm = 0.f;
  for (int i = tid; i < 4000; i += 256) sm += __expf(row[i] - mx);
  sm = wredsum(sm);
  if ((tid & 63) == 0) rs[tid>>6] = sm;
  __syncthreads();
  if (tid == 0){ float2 o = {mx, rs[0]+rs[1]+rs[2]+rs[3]}; partb[blockIdx.x] = o; }
}
__global__ void __launch_bounds__(256) lsm2_kernel(float* __restrict__ out,
    const float2* __restrict__ partb){
  int b = blockIdx.x >> 3, c = blockIdx.x & 7;
  float M = -3.4e38f, S = 0.f;
  #pragma unroll
  for (int j = 0; j < 8; j++) M = fmaxf(M, partb[b*8+j].x);
  #pragma unroll
  for (int j = 0; j < 8; j++){ float2 p = partb[b*8+j]; S += p.y * __expf(p.x - M); }
  float cns = M + logf(S);
  float* row = out + (size_t)b*VOUT + c*4000;
  for (int i = threadIdx.x; i < 4000; i += 256) row[i] -= cns;
}

extern "C" void kernel_launch(void* const* d_in, const int* in_sizes, int n_in,
                              void* d_out, int out_size, void* d_ws, size_t ws_size,
                              hipStream_t stream){
  (void)in_sizes; (void)n_in; (void)out_size; (void)ws_size;
  const int*   toks      = (const int*)  d_in[0];
  const float* emb_in    = (const float*)d_in[2];
  const float* enc_key_W = (const float*)d_in[4];
  const float* enc_Wq    = (const float*)d_in[5];
  const float* enc_bq    = (const float*)d_in[6];
  const float* enc_Wk    = (const float*)d_in[7];
  const float* enc_bk    = (const float*)d_in[8];
  const float* n1g       = (const float*)d_in[9];
  const float* n1b       = (const float*)d_in[10];
  const float* rdr_Wq    = (const float*)d_in[12];
  const float* rdr_bq    = (const float*)d_in[13];
  const float* rdr_Wk    = (const float*)d_in[14];
  const float* rdr_bk    = (const float*)d_in[15];
  const float* rdr_Wv    = (const float*)d_in[16];
  const float* rdr_bv    = (const float*)d_in[17];
  const float* n2g       = (const float*)d_in[22];
  const float* n2b       = (const float*)d_in[23];
  const float* vocW      = (const float*)d_in[26];
  const float* vocb      = (const float*)d_in[27];
  float* outp = (float*)d_out;

  float* ws = (float*)d_ws;
  size_t off = 0;
  float* Z    = ws + off; off += (size_t)NB*SENC*DD + 4*DD;  /* X/Z in place + slack */
  float* ZSQ  = ws + off; off += (size_t)NB*SENC*2 + 8;      /* + prefetch slack */
  float* av   = ws + off; off += (size_t)NB*AA*DD;
  /* gates [B*SENC][AA] f32 (8MB) aliases Kr+P16 (both written after avscan);
     gates prefetch slack spills into V16 region — also written after avscan */
  float* Kr   = ws + off; float* gates = Kr; off += (size_t)NB*AA*DD;
  unsigned int* P16 = (unsigned int*)(ws + off); off += (size_t)NB*AA*DD/2;
  unsigned int* V16 = (unsigned int*)(ws + off); off += (size_t)NB*AA*DD/2;
  float* Qa   = ws + off; off += (size_t)AA*DD;
  float* Menc = ws + off; off += (size_t)AA*DD;
  float* cenc = ws + off; off += AA;
  float* cdec = ws + off; off += (size_t)NB*AA;
  float* zfin = ws + off; off += (size_t)NB*DD;
  float2* lsp = (float2*)(ws + off); off += 512;
  int*  flag  = (int*)(ws + off); off += 1;

  qa_kernel     <<<AA, 512, 0, stream>>>(enc_key_W, enc_Wq, enc_bq, Qa);
  menc_kernel   <<<AA, 512, 0, stream>>>(Qa, enc_Wk, Menc);
  dotb_kernel   <<<AA/4, 256, 0, stream>>>(Qa, enc_bk, cenc);
  flag_kernel   <<<1, 512, 0, stream>>>(n1g, n1b, flag);
  xgather_kernel<<<NB*SENC/4, 256, 0, stream>>>(toks, emb_in, Z);
  zscan_kernel  <<<NB, 64, 0, stream>>>(Z, n1g, n1b, flag, ZSQ);
  gates_kernel  <<<NB*SENC/64, 256, 0, stream>>>(Z, Menc, cenc, gates);
  avscan_kernel <<<256, 512, 0, stream>>>(Z, ZSQ, gates, n1g, n1b, flag, av);
  gemm_nt_kernel<<<dim3(NB*AA/64, DD/64), 256, 0, stream>>>(av, rdr_Wk, rdr_bk, Kr, 0);
  gemm_nn_kernel<<<dim3(NB*AA/64, DD/64), 256, 0, stream>>>(Kr, rdr_Wq, P16);
  gemm_nt_kernel<<<dim3(NB*AA/64, DD/64), 256, 0, stream>>>(av, rdr_Wv, rdr_bv, V16, 1);
  dotb_kernel   <<<NB*AA/4, 256, 0, stream>>>(Kr, rdr_bq, cdec);
  dec_kernel    <<<NB, 256, 0, stream>>>(Z, P16, V16, cdec, n2g, n2b, zfin);
  logits_kernel <<<VOUT/128, 256, 0, stream>>>(zfin, vocW, vocb, outp);
  lsm1_kernel   <<<NB*8, 256, 0, stream>>>(outp, lsp);
  lsm2_kernel   <<<NB*8, 256, 0, stream>>>(outp, lsp);
}

// Round 9
// 1196.260 us; speedup vs baseline: 2.2166x; 1.0018x over previous
//
#include <hip/hip_runtime.h>
#include <math.h>

#define DD 512
#define AA 64
#define NB 32
#define SENC 1024
#define SDEC 256
#define VOUT 32000
#define EPSL 1e-6f
#define SCALE 0.044194173824159216f   /* 1/sqrt(512) */
#define SQRTD 22.627416997969522f     /* sqrt(512) */

typedef _Float16 h2 __attribute__((ext_vector_type(2)));
typedef float f32x2 __attribute__((ext_vector_type(2)));

/* ---------------- DPP wave reduction helpers (VALU-only) ----------------------- */
template<int C, int R>
__device__ __forceinline__ float dppz(float v){   /* old=0, bound_ctrl=1 */
  return __int_as_float(__builtin_amdgcn_update_dpp(0, __float_as_int(v), C, R, 0xf, true));
}
template<int C, int R>
__device__ __forceinline__ float dppself(float v){ /* old=self, bound_ctrl=0 */
  return __int_as_float(__builtin_amdgcn_update_dpp(__float_as_int(v), __float_as_int(v), C, R, 0xf, false));
}
__device__ __forceinline__ float rlane63(float v){
  return __int_as_float(__builtin_amdgcn_readlane(__float_as_int(v), 63));
}
__device__ __forceinline__ void wred2(float &a, float &b){
  a += dppz<0x111,0xf>(a); b += dppz<0x111,0xf>(b);
  a += dppz<0x112,0xf>(a); b += dppz<0x112,0xf>(b);
  a += dppz<0x114,0xf>(a); b += dppz<0x114,0xf>(b);
  a += dppz<0x118,0xf>(a); b += dppz<0x118,0xf>(b);
  a += dppz<0x142,0xa>(a); b += dppz<0x142,0xa>(b);
  a += dppz<0x143,0xc>(a); b += dppz<0x143,0xc>(b);
  a = rlane63(a); b = rlane63(b);
}
__device__ __forceinline__ float wredsum(float a){
  a += dppz<0x111,0xf>(a); a += dppz<0x112,0xf>(a);
  a += dppz<0x114,0xf>(a); a += dppz<0x118,0xf>(a);
  a += dppz<0x142,0xa>(a); a += dppz<0x143,0xc>(a);
  return rlane63(a);
}
__device__ __forceinline__ float wredmax(float a){
  a = fmaxf(a, dppself<0x111,0xf>(a));
  a = fmaxf(a, dppself<0x112,0xf>(a));
  a = fmaxf(a, dppself<0x114,0xf>(a));
  a = fmaxf(a, dppself<0x118,0xf>(a));
  a = fmaxf(a, dppself<0x142,0xa>(a));
  a = fmaxf(a, dppself<0x143,0xc>(a));
  return rlane63(a);
}
__device__ __forceinline__ unsigned int pk16(float x, float y){
  return __builtin_bit_cast(unsigned int, __builtin_amdgcn_cvt_pkrtz(x, y));
}
__device__ __forceinline__ float fd2(unsigned int a, unsigned int b, float c){
#if __has_builtin(__builtin_amdgcn_fdot2)
  return __builtin_amdgcn_fdot2(__builtin_bit_cast(h2, a), __builtin_bit_cast(h2, b), c, false);
#else
  h2 x = __builtin_bit_cast(h2, a), y = __builtin_bit_cast(h2, b);
  return c + (float)x[0]*(float)y[0] + (float)x[1]*(float)y[1];
#endif
}
/* fast transcendentals: ~1ulp HW ops */
__device__ __forceinline__ float frcp(float x){ float r; asm("v_rcp_f32 %0, %1" : "=v"(r) : "v"(x)); return r; }
__device__ __forceinline__ float fsqrt_f(float x){ float r; asm("v_sqrt_f32 %0, %1" : "=v"(r) : "v"(x)); return r; }
__device__ __forceinline__ f32x2 pkfma(f32x2 a, f32x2 b, f32x2 c){
  return __builtin_elementwise_fma(a, b, c);
}
/* pin a uint4 into VGPRs: empty asm becomes the defining op, so the compiler
   cannot re-materialize (re-load) the value inside a later loop. */
#define KEEP4(v) asm volatile("" : "+v"((v).x), "+v"((v).y), "+v"((v).z), "+v"((v).w))

/* ---------------- Qa = enc_key_W @ enc_Wq^T + enc_bq  [64,512] ---------------- */
__global__ void __launch_bounds__(512) qa_kernel(const float* __restrict__ keyW,
    const float* __restrict__ Wq, const float* __restrict__ bq, float* __restrict__ Qa){
  int a = blockIdx.x, i = threadIdx.x;
  __shared__ float key[DD];
  key[i] = keyW[a*DD + i];
  __syncthreads();
  const float4* w4 = (const float4*)(Wq + (size_t)i*DD);
  const float4* k4 = (const float4*)key;
  float s = 0.f;
  #pragma unroll 4
  for (int j = 0; j < DD/4; j++){
    float4 w = w4[j], k = k4[j];
    s = fmaf(w.x,k.x, fmaf(w.y,k.y, fmaf(w.z,k.z, fmaf(w.w,k.w, s))));
  }
  Qa[a*DD + i] = s + bq[i];
}

/* ------------- Menc = Qa @ enc_Wk  [64,512] ----------------------------------- */
__global__ void __launch_bounds__(512) menc_kernel(const float* __restrict__ Qa,
    const float* __restrict__ Wk, float* __restrict__ Menc){
  int a = blockIdx.x, j = threadIdx.x;
  __shared__ float qa[DD];
  qa[j] = Qa[a*DD + j];
  __syncthreads();
  float s = 0.f;
  #pragma unroll 4
  for (int i = 0; i < DD; i++) s = fmaf(qa[i], Wk[(size_t)i*DD + j], s);
  Menc[a*DD + j] = s;
}

/* ------------- out[m] = X[m,:] . v  (4 rows per block) ------------------------- */
__global__ void __launch_bounds__(256) dotb_kernel(const float* __restrict__ X,
    const float* __restrict__ v, float* __restrict__ out){
  int m = blockIdx.x*4 + (threadIdx.x >> 6);
  int lane = threadIdx.x & 63;
  const float4* x4 = (const float4*)(X + (size_t)m*DD + lane*8);
  const float4* v4 = (const float4*)(v + lane*8);
  float4 a = x4[0], b4 = x4[1], c = v4[0], d = v4[1];
  float s = a.x*c.x;
  s = fmaf(a.y,c.y, s); s = fmaf(a.z,c.z, s); s = fmaf(a.w,c.w, s);
  s = fmaf(b4.x,d.x, s); s = fmaf(b4.y,d.y, s); s = fmaf(b4.z,d.z, s); s = fmaf(b4.w,d.w, s);
  s = wredsum(s);
  if (lane == 0) out[m] = s;
}

/* ------------- flag = all(n1g==1) && all(n1b==0) ------------------------------- */
__global__ void __launch_bounds__(512) flag_kernel(const float* __restrict__ g,
    const float* __restrict__ b, int* __restrict__ flag){
  __shared__ int s;
  if (threadIdx.x == 0) s = 1;
  __syncthreads();
  bool ok = (g[threadIdx.x] == 1.0f) && (b[threadIdx.x] == 0.0f);
  if (!ok) atomicAnd(&s, 0);
  __syncthreads();
  if (threadIdx.x == 0) flag[0] = s;
}

/* -------- X[b,t,:] = emb[tok[b,t],:] * sqrtD  (pre-gather, fully parallel) ------ */
__global__ void __launch_bounds__(256) xgather_kernel(const int* __restrict__ toks,
    const float* __restrict__ emb, float* __restrict__ X){
  int row = blockIdx.x*4 + (threadIdx.x >> 6);
  int lane = threadIdx.x & 63;
  int tok = toks[row];
  const float4* src = (const float4*)(emb + (size_t)tok*DD + lane*8);
  float4 a = src[0], b = src[1];
  a.x*=SQRTD; a.y*=SQRTD; a.z*=SQRTD; a.w*=SQRTD;
  b.x*=SQRTD; b.y*=SQRTD; b.z*=SQRTD; b.w*=SQRTD;
  float4* dst = (float4*)(X + (size_t)row*DD + lane*8);
  dst[0] = a; dst[1] = b;
}

/* --------- encoder z-scan: in-place X -> Z, pk-math FAST path ------------------- */
__device__ __forceinline__ void zscan_fast(float* __restrict__ XZ, float* __restrict__ ZSQ){
  int b = blockIdx.x, lane = threadIdx.x;
  int bd = lane*8;
  f32x2 z0 = {0.f,0.f}, z1 = {0.f,0.f}, z2 = {0.f,0.f}, z3 = {0.f,0.f};
  float* xp = XZ + (size_t)b*SENC*DD + bd;
  float2* sqp = (float2*)ZSQ + (size_t)b*SENC;
  float4 xa0 = *(const float4*)(xp       ), xb0 = *(const float4*)(xp        + 4);
  float4 xa1 = *(const float4*)(xp + DD  ), xb1 = *(const float4*)(xp + DD   + 4);
  float4 xa2 = *(const float4*)(xp + 2*DD), xb2 = *(const float4*)(xp + 2*DD + 4);
  float4 xa3 = *(const float4*)(xp + 3*DD), xb3 = *(const float4*)(xp + 3*DD + 4);
  for (int t = 0; t < SENC; t += 4){
#define ZFSTEP(XA, XB, OFS, PFO, TI) {                                             \
    f32x2 y0 = z0 + f32x2{XA.x, XA.y}, y1 = z1 + f32x2{XA.z, XA.w};                \
    f32x2 y2 = z2 + f32x2{XB.x, XB.y}, y3 = z3 + f32x2{XB.z, XB.w};                \
    f32x2 t01 = y0 + y1, t23 = y2 + y3, tv = t01 + t23;                            \
    float s = tv.x + tv.y;                                                         \
    f32x2 q0 = y0*y0, q1 = y1*y1, q2 = y2*y2, q3 = y3*y3;                          \
    f32x2 q01 = q0 + q1, q23 = q2 + q3, qv = q01 + q23;                            \
    float q = qv.x + qv.y;                                                         \
    wred2(s, q);                                                                   \
    float mean = s * (1.f/DD);                                                     \
    float qc2  = fmaf(mean*(-(float)DD), mean, q);                                 \
    float var  = fmaxf(qc2 * (1.f/(DD-1)), 0.f);                                   \
    float r = frcp(fsqrt_f(var) + EPSL);                                           \
    float c3 = -(r*mean);                                                          \
    f32x2 RR = {r,r}, C3 = {c3,c3};                                                \
    z0 = pkfma(RR, y0, C3); z1 = pkfma(RR, y1, C3);                                \
    z2 = pkfma(RR, y2, C3); z3 = pkfma(RR, y3, C3);                                \
    if (lane == 0){ float2 o = {0.f, qc2*r*r}; sqp[TI] = o; }                      \
    float4 o1 = {z0.x,z0.y,z1.x,z1.y}, o2 = {z2.x,z2.y,z3.x,z3.y};                 \
    *(float4*)(xp + OFS) = o1; *(float4*)(xp + OFS + 4) = o2;                      \
    XA = *(const float4*)(xp + PFO); XB = *(const float4*)(xp + PFO + 4); }
    ZFSTEP(xa0, xb0, 0,    4*DD, 0)
    ZFSTEP(xa1, xb1, DD,   5*DD, 1)
    ZFSTEP(xa2, xb2, 2*DD, 6*DD, 2)
    ZFSTEP(xa3, xb3, 3*DD, 7*DD, 3)
#undef ZFSTEP
    xp += 4*DD; sqp += 4;
  }
}

/* general path (n1 not identity) — reference-faithful */
__device__ __forceinline__ void zscan_gen(float* __restrict__ XZ,
    const float* __restrict__ n1g, const float* __restrict__ n1b,
    float* __restrict__ ZSQ){
  int b = blockIdx.x, lane = threadIdx.x;
  int bd = lane*8;
  float z[8], g1[8], b1[8];
  #pragma unroll
  for (int k = 0; k < 8; k++) z[k] = 0.f;
  *(float4*)&g1[0] = *(const float4*)(n1g+bd); *(float4*)&g1[4] = *(const float4*)(n1g+bd+4);
  *(float4*)&b1[0] = *(const float4*)(n1b+bd); *(float4*)&b1[4] = *(const float4*)(n1b+bd+4);
  float* xp = XZ + (size_t)b*SENC*DD + bd;
  float2* sqp = (float2*)ZSQ + (size_t)b*SENC;
  for (int t = 0; t < SENC; t++){
    float4 xa = *(const float4*)xp, xb = *(const float4*)(xp + 4);
    float x[8] = {xa.x,xa.y,xa.z,xa.w,xb.x,xb.y,xb.z,xb.w};
    float y[8], s = 0.f, q = 0.f;
    #pragma unroll
    for (int k = 0; k < 8; k++){ y[k] = z[k] + x[k]; s += y[k]; q = fmaf(y[k], y[k], q); }
    wred2(s, q);
    float mean = s * (1.f/DD);
    float var  = fmaxf((q - (float)DD*mean*mean) * (1.f/(DD-1)), 0.f);
    float r = 1.f/(sqrtf(var) + EPSL);
    float sz = 0.f, qz = 0.f;
    #pragma unroll
    for (int k = 0; k < 8; k++){
      z[k] = fmaf(g1[k]*r, y[k]-mean, b1[k]);
      sz += z[k]; qz = fmaf(z[k], z[k], qz);
    }
    wred2(sz, qz);
    if (lane == 0){ float2 o = {sz, qz}; sqp[t] = o; }
    float4 o1 = {z[0],z[1],z[2],z[3]}, o2 = {z[4],z[5],z[6],z[7]};
    *(float4*)xp = o1; *(float4*)(xp + 4) = o2;
    xp += DD;
  }
}

__global__ void __launch_bounds__(64) zscan_kernel(float* __restrict__ XZ,
    const float* __restrict__ n1g, const float* __restrict__ n1b,
    const int* __restrict__ flag, float* __restrict__ ZSQ){
  if (flag[0]) zscan_fast(XZ, ZSQ);
  else         zscan_gen(XZ, n1g, n1b, ZSQ);
}

/* -------- gates[bt][a] = sigmoid((Z[bt,:].Menc[a,:] + cenc[a])*SCALE) ----------- */
__global__ void __launch_bounds__(256) gates_kernel(const float* __restrict__ Zin,
    const float* __restrict__ Menc, const float* __restrict__ cenc,
    float* __restrict__ gates){
  __shared__ float As[32][64];
  __shared__ float Bs[32][64];
  int tid = threadIdx.x;
  int m0 = blockIdx.x*64;
  int ty = tid >> 4, tx = tid & 15;
  float acc[4][4] = {{0.f}};
  for (int k0 = 0; k0 < 512; k0 += 32){
    #pragma unroll
    for (int p = 0; p < 2; p++){
      int row = (tid>>3) + p*32, col = (tid&7)*4;
      float4 va = *(const float4*)(Zin + (size_t)(m0+row)*512 + k0 + col);
      As[col][row]=va.x; As[col+1][row]=va.y; As[col+2][row]=va.z; As[col+3][row]=va.w;
      float4 vb = *(const float4*)(Menc + (size_t)row*512 + k0 + col);
      Bs[col][row]=vb.x; Bs[col+1][row]=vb.y; Bs[col+2][row]=vb.z; Bs[col+3][row]=vb.w;
    }
    __syncthreads();
    #pragma unroll
    for (int kk = 0; kk < 32; kk++){
      float4 a4 = *(const float4*)&As[kk][ty*4];
      float4 b4 = *(const float4*)&Bs[kk][tx*4];
      float au[4] = {a4.x,a4.y,a4.z,a4.w}, bv[4] = {b4.x,b4.y,b4.z,b4.w};
      #pragma unroll
      for (int u = 0; u < 4; u++)
        #pragma unroll
        for (int v = 0; v < 4; v++) acc[u][v] = fmaf(au[u], bv[v], acc[u][v]);
    }
    __syncthreads();
  }
  float cv[4];
  #pragma unroll
  for (int v = 0; v < 4; v++) cv[v] = cenc[tx*4 + v];
  #pragma unroll
  for (int u = 0; u < 4; u++){
    float4 st;
    st.x = frcp(1.f + __expf(-(acc[u][0]+cv[0])*SCALE));
    st.y = frcp(1.f + __expf(-(acc[u][1]+cv[1])*SCALE));
    st.z = frcp(1.f + __expf(-(acc[u][2]+cv[2])*SCALE));
    st.w = frcp(1.f + __expf(-(acc[u][3]+cv[3])*SCALE));
    *(float4*)(gates + (size_t)(m0+ty*4+u)*AA + tx*4) = st;
  }
}

/* ---- encoder av-scan FAST: pk-math, unroll x2, analytic LN closure ------------- */
__device__ __forceinline__ void avscan_fast(const float* __restrict__ Z,
    const float* __restrict__ ZSQ, const float* __restrict__ gates,
    float* __restrict__ avout){
  int bx = blockIdx.x;
  int b = (bx & 7)*4 + ((bx >> 3) & 3);          /* all blocks of batch b on one XCD */
  int a = ((bx >> 5)<<3) + (threadIdx.x >> 6);
  int lane = threadIdx.x & 63;
  int bd = lane*8;
  f32x2 av0 = {0.f,0.f}, av1 = {0.f,0.f}, av2v = {0.f,0.f}, av3 = {0.f,0.f};
  float Qav = 0.f;
  const float*  zp  = Z + (size_t)b*SENC*DD + bd;
  const float4* sp4 = (const float4*)(ZSQ + (size_t)b*SENC*2);
  const float*  gp  = gates + (size_t)b*SENC*AA + a;
  float4 zc0a = *(const float4*)zp,        zc0b = *(const float4*)(zp + 4);
  float4 zc1a = *(const float4*)(zp + DD), zc1b = *(const float4*)(zp + DD + 4);
  float4 sq01 = sp4[0];
  float g0 = gp[0], g1 = gp[AA];
  for (int t = 0; t < SENC; t += 2){
    /* prefetch t+2, t+3 (slack rows allocated; cross-batch touch never consumed) */
    float4 zn0a = *(const float4*)(zp + 2*DD), zn0b = *(const float4*)(zp + 2*DD + 4);
    float4 zn1a = *(const float4*)(zp + 3*DD), zn1b = *(const float4*)(zp + 3*DD + 4);
    float4 sqn = sp4[1];
    float gn0 = gp[2*AA], gn1 = gp[3*AA];
#define AVSTEP(ZA, ZB, SZT, QZT, G) {                                              \
    f32x2 z0 = {ZA.x, ZA.y}, z1 = {ZA.z, ZA.w};                                    \
    f32x2 z2 = {ZB.x, ZB.y}, z3 = {ZB.z, ZB.w};                                    \
    f32x2 p0 = av0*z0, p1 = av1*z1, p2 = av2v*z2, p3 = av3*z3;                     \
    f32x2 s01 = p0 + p1, s23 = p2 + p3, sv = s01 + s23;                            \
    float cav = wredsum(sv.x + sv.y);                                              \
    float g = (G), omg = 1.f - g;                                                  \
    float mean = (g * (1.f/DD)) * (SZT);                                           \
    float a1s = (omg*omg) * Qav;                                                   \
    float a2s = fmaf((g+g)*omg, cav, a1s);                                         \
    float Qy  = fmaf(g*g, (QZT), a2s);                                             \
    float qc2 = fmaf(mean*(-(float)DD), mean, Qy);                                 \
    float var = fmaxf(qc2 * (1.f/(DD-1)), 0.f);                                    \
    float r = frcp(fsqrt_f(var) + EPSL);                                           \
    float c1 = r*omg, c2s = r*g, c3 = -(r*mean);                                   \
    f32x2 C1 = {c1,c1}, C2 = {c2s,c2s}, C3 = {c3,c3};                              \
    av0  = pkfma(C1, av0,  pkfma(C2, z0, C3));                                     \
    av1  = pkfma(C1, av1,  pkfma(C2, z1, C3));                                     \
    av2v = pkfma(C1, av2v, pkfma(C2, z2, C3));                                     \
    av3  = pkfma(C1, av3,  pkfma(C2, z3, C3));                                     \
    Qav = qc2 * (r*r); }
    AVSTEP(zc0a, zc0b, sq01.x, sq01.y, g0)
    AVSTEP(zc1a, zc1b, sq01.z, sq01.w, g1)
#undef AVSTEP
    zc0a = zn0a; zc0b = zn0b; zc1a = zn1a; zc1b = zn1b;
    sq01 = sqn; g0 = gn0; g1 = gn1;
    zp += 2*DD; sp4 += 1; gp += 2*AA;
  }
  float* o = avout + ((size_t)(b*AA + a))*DD + bd;
  float4 o1 = {av0.x,av0.y,av1.x,av1.y}, o2 = {av2v.x,av2v.y,av3.x,av3.y};
  *(float4*)o = o1; *(float4*)(o+4) = o2;
}

/* general path — reference-faithful */
__device__ __forceinline__ void avscan_gen(const float* __restrict__ Z,
    const float* __restrict__ ZSQ, const float* __restrict__ gates,
    const float* __restrict__ n1g, const float* __restrict__ n1b,
    float* __restrict__ avout){
  int bx = blockIdx.x;
  int b = (bx & 7)*4 + ((bx >> 3) & 3);
  int a = ((bx >> 5)<<3) + (threadIdx.x >> 6);
  int lane = threadIdx.x & 63;
  int bd = lane*8;
  float g1[8], b1[8], av[8];
  *(float4*)&g1[0] = *(const float4*)(n1g+bd); *(float4*)&g1[4] = *(const float4*)(n1g+bd+4);
  *(float4*)&b1[0] = *(const float4*)(n1b+bd); *(float4*)&b1[4] = *(const float4*)(n1b+bd+4);
  #pragma unroll
  for (int k = 0; k < 8; k++) av[k] = 0.f;
  float Sav = 0.f, Qav = 0.f;
  const float*  zp = Z + (size_t)b*SENC*DD + bd;
  const float2* sp = (const float2*)ZSQ + (size_t)b*SENC;
  const float*  gp = gates + (size_t)b*SENC*AA + a;
  for (int t = 0; t < SENC; t++){
    float4 za = *(const float4*)zp, zb = *(const float4*)(zp + 4);
    float z[8] = {za.x,za.y,za.z,za.w,zb.x,zb.y,zb.z,zb.w};
    float2 sq = sp[0];
    float g = gp[0];
    float cav = 0.f;
    #pragma unroll
    for (int k = 0; k < 8; k++) cav = fmaf(av[k], z[k], cav);
    cav = wredsum(cav);
    float omg = 1.f - g;
    float Sy = fmaf(g, sq.x - Sav, Sav);
    float Qy = omg*omg*Qav + 2.f*g*omg*cav + g*g*sq.y;
    float mean = Sy * (1.f/DD);
    float var  = fmaxf((Qy - (float)DD*mean*mean) * (1.f/(DD-1)), 0.f);
    float r = 1.f/(sqrtf(var) + EPSL);
    float sn = 0.f, qn = 0.f;
    #pragma unroll
    for (int k = 0; k < 8; k++){
      float y = fmaf(g, z[k]-av[k], av[k]);
      float nv = fmaf(g1[k]*r, y-mean, b1[k]);
      av[k] = nv; sn += nv; qn = fmaf(nv, nv, qn);
    }
    wred2(sn, qn);
    Sav = sn; Qav = qn;
    zp += DD; sp += 1; gp += AA;
  }
  float* o = avout + ((size_t)(b*AA + a))*DD + bd;
  float4 o1 = {av[0],av[1],av[2],av[3]}, o2 = {av[4],av[5],av[6],av[7]};
  *(float4*)o = o1; *(float4*)(o+4) = o2;
}

__global__ void __launch_bounds__(512) avscan_kernel(const float* __restrict__ Z,
    const float* __restrict__ ZSQ, const float* __restrict__ gates,
    const float* __restrict__ n1g, const float* __restrict__ n1b,
    const int* __restrict__ flag, float* __restrict__ avout){
  if (flag[0]) avscan_fast(Z, ZSQ, gates, avout);
  else         avscan_gen(Z, ZSQ, gates, n1g, n1b, avout);
}

/* ------------- f32 GEMM, C[m,n] = sum_k A[m,k]*Bw[n,k] (+bias[n]) --------------- */
__global__ void __launch_bounds__(256) gemm_nt_kernel(const float* __restrict__ Aa,
    const float* __restrict__ Bw, const float* __restrict__ bias,
    void* __restrict__ Cout, int mode){
  __shared__ float As[32][64];
  __shared__ float Bs[32][64];
  int tid = threadIdx.x;
  int m0 = blockIdx.x*64, n0 = blockIdx.y*64;
  int ty = tid >> 4, tx = tid & 15;
  float acc[4][4] = {{0.f}};
  for (int k0 = 0; k0 < 512; k0 += 32){
    #pragma unroll
    for (int p = 0; p < 2; p++){
      int row = (tid>>3) + p*32, col = (tid&7)*4;
      float4 va = *(const float4*)(Aa + (size_t)(m0+row)*512 + k0 + col);
      As[col][row]=va.x; As[col+1][row]=va.y; As[col+2][row]=va.z; As[col+3][row]=va.w;
      float4 vb = *(const float4*)(Bw + (size_t)(n0+row)*512 + k0 + col);
      Bs[col][row]=vb.x; Bs[col+1][row]=vb.y; Bs[col+2][row]=vb.z; Bs[col+3][row]=vb.w;
    }
    __syncthreads();
    #pragma unroll
    for (int kk = 0; kk < 32; kk++){
      float4 a4 = *(const float4*)&As[kk][ty*4];
      float4 b4 = *(const float4*)&Bs[kk][tx*4];
      float au[4] = {a4.x,a4.y,a4.z,a4.w}, bv[4] = {b4.x,b4.y,b4.z,b4.w};
      #pragma unroll
      for (int u = 0; u < 4; u++)
        #pragma unroll
        for (int v = 0; v < 4; v++) acc[u][v] = fmaf(au[u], bv[v], acc[u][v]);
    }
    __syncthreads();
  }
  float bv4[4];
  #pragma unroll
  for (int v = 0; v < 4; v++) bv4[v] = bias ? bias[n0 + tx*4 + v] : 0.f;
  if (mode == 0){
    float* C = (float*)Cout;
    #pragma unroll
    for (int u = 0; u < 4; u++){
      float4 st = {acc[u][0]+bv4[0], acc[u][1]+bv4[1], acc[u][2]+bv4[2], acc[u][3]+bv4[3]};
      *(float4*)(C + (size_t)(m0+ty*4+u)*512 + n0 + tx*4) = st;
    }
  } else {
    unsigned short* C = (unsigned short*)Cout;
    #pragma unroll
    for (int u = 0; u < 4; u++){
      int mm = m0 + ty*4 + u; int bb = mm >> 6, a2 = mm & 63;
      #pragma unroll
      for (int v = 0; v < 4; v++){
        _Float16 hv = (_Float16)(acc[u][v] + bv4[v]);
        C[((size_t)bb*512 + n0 + tx*4 + v)*64 + a2] = __builtin_bit_cast(unsigned short, hv);
      }
    }
  }
}

/* ------------- P16[m][n] (f16) = sum_k A[m,k]*B[k,n] --------------------------- */
__global__ void __launch_bounds__(256) gemm_nn_kernel(const float* __restrict__ Aa,
    const float* __restrict__ Bw, unsigned int* __restrict__ Cout){
  __shared__ float As[32][64];
  __shared__ float Bs[32][64];
  int tid = threadIdx.x;
  int m0 = blockIdx.x*64, n0 = blockIdx.y*64;
  int ty = tid >> 4, tx = tid & 15;
  float acc[4][4] = {{0.f}};
  for (int k0 = 0; k0 < 512; k0 += 32){
    #pragma unroll
    for (int p = 0; p < 2; p++){
      int row = (tid>>3) + p*32, col = (tid&7)*4;
      float4 va = *(const float4*)(Aa + (size_t)(m0+row)*512 + k0 + col);
      As[col][row]=va.x; As[col+1][row]=va.y; As[col+2][row]=va.z; As[col+3][row]=va.w;
      int brow = (tid>>4) + p*16, bcol = (tid&15)*4;
      float4 vb = *(const float4*)(Bw + (size_t)(k0+brow)*512 + n0 + bcol);
      *(float4*)&Bs[brow][bcol] = vb;
    }
    __syncthreads();
    #pragma unroll
    for (int kk = 0; kk < 32; kk++){
      float4 a4 = *(const float4*)&As[kk][ty*4];
      float4 b4 = *(const float4*)&Bs[kk][tx*4];
      float au[4] = {a4.x,a4.y,a4.z,a4.w}, bv[4] = {b4.x,b4.y,b4.z,b4.w};
      #pragma unroll
      for (int u = 0; u < 4; u++)
        #pragma unroll
        for (int v = 0; v < 4; v++) acc[u][v] = fmaf(au[u], bv[v], acc[u][v]);
    }
    __syncthreads();
  }
  #pragma unroll
  for (int u = 0; u < 4; u++){
    uint2 st = { pk16(acc[u][0], acc[u][1]), pk16(acc[u][2], acc[u][3]) };
    *(uint2*)(Cout + (size_t)(m0+ty*4+u)*256 + (n0 + tx*4)/2) = st;
  }
}

/* ------------------------------- decoder scan ----------------------------------- */
/* P and V fragments register-resident. R8 lesson: __launch_bounds__(256,1) sets    */
/* only the MIN waves/EU; the allocator still targeted ~6 waves/EU (VGPR cap 84)    */
/* and spilled the fragments. amdgpu_waves_per_eu(1,1) pins min AND max -> full     */
/* 512-VGPR budget.                                                                 */
__global__ void __launch_bounds__(256)
__attribute__((amdgpu_waves_per_eu(1, 1)))
dec_kernel(const float* __restrict__ Z,
    const unsigned int* __restrict__ Pg, const unsigned int* __restrict__ Vg,
    const float* __restrict__ cdec, const float* __restrict__ n2g,
    const float* __restrict__ n2b, float* __restrict__ zfin){
  __shared__ unsigned int zh[256];
  __shared__ float part[AA][5];          /* +1 pad: conflict-free b32 reads */
  __shared__ unsigned int att4h[4][32];
  __shared__ float2 red2[4];
  int b = blockIdx.x, tid = threadIdx.x;
  int lane = tid & 63, w = tid >> 6;
  int d0 = tid*2;

  /* P fragment: anchor=lane, dims w*128..w*128+127 -> u32s [(b*64+lane)*256 + w*64 + j] */
  uint4 pf[16];
  const uint4* Pg4 = (const uint4*)(Pg + ((size_t)(b*AA + lane))*256 + w*64);
  #pragma unroll
  for (int j = 0; j < 16; j++) pf[j] = Pg4[j];
  /* V fragment: rows d0, d0+1 over all 64 anchors -> u32s [(b*512+d)*32 + j] */
  uint4 vf0[8], vf1[8];
  const uint4* Vg40 = (const uint4*)(Vg + ((size_t)b*DD + d0)*32);
  const uint4* Vg41 = (const uint4*)(Vg + ((size_t)b*DD + d0 + 1)*32);
  #pragma unroll
  for (int j = 0; j < 8; j++){ vf0[j] = Vg40[j]; vf1[j] = Vg41[j]; }
  /* pin all fragments into VGPRs (defeat load re-materialization) */
  #pragma unroll
  for (int j = 0; j < 16; j++){ KEEP4(pf[j]); }
  #pragma unroll
  for (int j = 0; j < 8; j++){ KEEP4(vf0[j]); KEEP4(vf1[j]); }

  float2 zi = *(const float2*)(Z + ((size_t)b*SENC + SENC-1)*DD + d0);
  float z0r = zi.x, z1r = zi.y;
  zh[tid] = pk16(z0r, z1r);
  float cdv = cdec[b*AA + lane];
  float g2a = n2g[d0], g2b = n2g[d0+1], b2a = n2b[d0], b2b = n2b[d0+1];
  __syncthreads();

  for (int t = 0; t < SDEC; t++){
    /* ph1: logit partial (anchor=lane, d-quarter w): P regs x zh broadcast reads */
    float sA[4] = {0.f,0.f,0.f,0.f};
    #pragma unroll
    for (int j = 0; j < 16; j++){
      uint4 zv = *(const uint4*)&zh[w*64 + j*4];
      sA[j&3] = fd2(pf[j].x, zv.x, sA[j&3]);
      sA[j&3] = fd2(pf[j].y, zv.y, sA[j&3]);
      sA[j&3] = fd2(pf[j].z, zv.z, sA[j&3]);
      sA[j&3] = fd2(pf[j].w, zv.w, sA[j&3]);
    }
    part[lane][w] = (sA[0]+sA[1]) + (sA[2]+sA[3]);
    __syncthreads();                               /* A */
    /* ph2: redundant per-wave softmax over 64 anchors */
    float l = (((part[lane][0] + part[lane][1]) + (part[lane][2] + part[lane][3])) + cdv) * SCALE;
    float mx = wredmax(l);
    float e = __expf(l - mx);
    float se = wredsum(e);
    float attv = e * frcp(se);
    float attn = dppself<0x101,0xf>(attv);         /* row_shl:1 -> lane i gets att[i+1] */
    if ((lane & 1) == 0) att4h[w][lane>>1] = pk16(attv, attn);
    asm volatile("s_waitcnt lgkmcnt(0)" ::: "memory");
    /* ph3: dg2 for d0,d0+1: V regs x att4h broadcast reads */
    float aA0 = 0.f, aA1 = 0.f, aB0 = 0.f, aB1 = 0.f;
    #pragma unroll
    for (int j = 0; j < 8; j++){
      uint4 ah = *(const uint4*)&att4h[w][j*4];
      if (j & 1){
        aA1 = fd2(vf0[j].x, ah.x, aA1); aA1 = fd2(vf0[j].y, ah.y, aA1);
        aA1 = fd2(vf0[j].z, ah.z, aA1); aA1 = fd2(vf0[j].w, ah.w, aA1);
        aB1 = fd2(vf1[j].x, ah.x, aB1); aB1 = fd2(vf1[j].y, ah.y, aB1);
        aB1 = fd2(vf1[j].z, ah.z, aB1); aB1 = fd2(vf1[j].w, ah.w, aB1);
      } else {
        aA0 = fd2(vf0[j].x, ah.x, aA0); aA0 = fd2(vf0[j].y, ah.y, aA0);
        aA0 = fd2(vf0[j].z, ah.z, aA0); aA0 = fd2(vf0[j].w, ah.w, aA0);
        aB0 = fd2(vf1[j].x, ah.x, aB0); aB0 = fd2(vf1[j].y, ah.y, aB0);
        aB0 = fd2(vf1[j].z, ah.z, aB0); aB0 = fd2(vf1[j].w, ah.w, aB0);
      }
    }
    float y0 = z0r + (aA0 + aA1), y1 = z1r + (aB0 + aB1);
    float s2 = y0 + y1, q2 = fmaf(y0, y0, y1*y1);
    wred2(s2, q2);
    if (lane == 0){ float2 o = {s2, q2}; red2[w] = o; }
    __syncthreads();                               /* B */
    float2 rA = red2[0], rB = red2[1], rC = red2[2], rD = red2[3];
    float Sy = (rA.x+rB.x)+(rC.x+rD.x), Qy = (rA.y+rB.y)+(rC.y+rD.y);
    float mean = Sy * (1.f/DD);
    float var  = fmaxf((Qy - (float)DD*mean*mean) * (1.f/(DD-1)), 0.f);
    float r = frcp(fsqrt_f(var) + EPSL);
    z0r = fmaf(g2a*r, y0-mean, b2a);
    z1r = fmaf(g2b*r, y1-mean, b2b);
    zh[tid] = pk16(z0r, z1r);                      /* own-wave consumer only */
    asm volatile("s_waitcnt lgkmcnt(0)" ::: "memory");
  }
  zfin[(size_t)b*DD + d0]     = z0r;
  zfin[(size_t)b*DD + d0 + 1] = z1r;
}

/* ---------------- logits = zfin @ voc_W^T + voc_b ------------------------------- */
__global__ void __launch_bounds__(256) logits_kernel(const float* __restrict__ zfin,
    const float* __restrict__ vocW, const float* __restrict__ vocb, float* __restrict__ out){
  __shared__ float zS[NB*DD];
  int tid = threadIdx.x;
  const float4* src = (const float4*)zfin;
  float4* dst = (float4*)zS;
  #pragma unroll
  for (int i = 0; i < 16; i++) dst[tid + i*256] = src[tid + i*256];
  __syncthreads();
  int w = tid >> 6, lane = tid & 63;
  int kq = lane & 3, rp = lane >> 2;
  int r0 = blockIdx.x*128 + w*32 + rp*2, r1 = r0 + 1;
  float acc0[NB], acc1[NB];
  #pragma unroll
  for (int bq = 0; bq < NB; bq++){ acc0[bq] = 0.f; acc1[bq] = 0.f; }
  const float* w0p = vocW + (size_t)r0*DD;
  const float* w1p = vocW + (size_t)r1*DD;
  for (int ks = 0; ks < 32; ks++){
    int koff = ks*16 + kq*4;
    float4 w0 = *(const float4*)(w0p + koff);
    float4 w1 = *(const float4*)(w1p + koff);
    #pragma unroll
    for (int bq = 0; bq < NB; bq++){
      float4 z4 = *(const float4*)&zS[bq*DD + koff];
      acc0[bq] = fmaf(w0.x,z4.x, fmaf(w0.y,z4.y, fmaf(w0.z,z4.z, fmaf(w0.w,z4.w, acc0[bq]))));
      acc1[bq] = fmaf(w1.x,z4.x, fmaf(w1.y,z4.y, fmaf(w1.z,z4.z, fmaf(w1.w,z4.w, acc1[bq]))));
    }
  }
  #pragma unroll
  for (int bq = 0; bq < NB; bq++){
    acc0[bq] += dppz<0xB1,0xf>(acc0[bq]); acc0[bq] += dppz<0x4E,0xf>(acc0[bq]);
    acc1[bq] += dppz<0xB1,0xf>(acc1[bq]); acc1[bq] += dppz<0x4E,0xf>(acc1[bq]);
  }
  if (kq == 0){
    float vb0 = vocb[r0], vb1 = vocb[r1];
    #pragma unroll
    for (int bq = 0; bq < NB; bq++){
      out[(size_t)bq*VOUT + r0] = acc0[bq] + vb0;
      out[(size_t)bq*VOUT + r1] = acc1[bq] + vb1;
    }
  }
}

/* --------------------------- split log_softmax ---------------------------------- */
__global__ void __launch_bounds__(256) lsm1_kernel(const float* __restrict__ out,
    float2* __restrict__ partb){
  int b = blockIdx.x >> 3, c = blockIdx.x & 7;
  const float* row = out + (size_t)b*VOUT + c*4000;
  int tid = threadIdx.x;
  __shared__ float rm[4]; __shared__ float rs[4];
  float mx = -3.4e38f;
  for (int i = tid; i < 4000; i += 256) mx = fmaxf(mx, row[i]);
  mx = wredmax(mx);
  if ((tid & 63) == 0) rm[tid>>6] = mx;
  __syncthreads();
  mx = fmaxf(fmaxf(rm[0],rm[1]), fmaxf(rm[2],rm[3]));
  float sm = 0.f;
  for (int i = tid; i < 4000; i += 256) sm += __expf(row[i] - mx);
  sm = wredsum(sm);
  if ((tid & 63) == 0) rs[tid>>6] = sm;
  __syncthreads();
  if (tid == 0){ float2 o = {mx, rs[0]+rs[1]+rs[2]+rs[3]}; partb[blockIdx.x] = o; }
}
__global__ void __launch_bounds__(256) lsm2_kernel(float* __restrict__ out,
    const float2* __restrict__ partb){
  int b = blockIdx.x >> 3, c = blockIdx.x & 7;
  float M = -3.4e38f, S = 0.f;
  #pragma unroll
  for (int j = 0; j < 8; j++) M = fmaxf(M, partb[b*8+j].x);
  #pragma unroll
  for (int j = 0; j < 8; j++){ float2 p = partb[b*8+j]; S += p.y * __expf(p.x - M); }
  float cns = M + logf(S);
  float* row = out + (size_t)b*VOUT + c*4000;
  for (int i = threadIdx.x; i < 4000; i += 256) row[i] -= cns;
}

extern "C" void kernel_launch(void* const* d_in, const int* in_sizes, int n_in,
                              void* d_out, int out_size, void* d_ws, size_t ws_size,
                              hipStream_t stream){
  (void)in_sizes; (void)n_in; (void)out_size; (void)ws_size;
  const int*   toks      = (const int*)  d_in[0];
  const float* emb_in    = (const float*)d_in[2];
  const float* enc_key_W = (const float*)d_in[4];
  const float* enc_Wq    = (const float*)d_in[5];
  const float* enc_bq    = (const float*)d_in[6];
  const float* enc_Wk    = (const float*)d_in[7];
  const float* enc_bk    = (const float*)d_in[8];
  const float* n1g       = (const float*)d_in[9];
  const float* n1b       = (const float*)d_in[10];
  const float* rdr_Wq    = (const float*)d_in[12];
  const float* rdr_bq    = (const float*)d_in[13];
  const float* rdr_Wk    = (const float*)d_in[14];
  const float* rdr_bk    = (const float*)d_in[15];
  const float* rdr_Wv    = (const float*)d_in[16];
  const float* rdr_bv    = (const float*)d_in[17];
  const float* n2g       = (const float*)d_in[22];
  const float* n2b       = (const float*)d_in[23];
  const float* vocW      = (const float*)d_in[26];
  const float* vocb      = (const float*)d_in[27];
  float* outp = (float*)d_out;

  float* ws = (float*)d_ws;
  size_t off = 0;
  float* Z    = ws + off; off += (size_t)NB*SENC*DD + 4*DD;  /* X/Z in place + slack */
  float* ZSQ  = ws + off; off += (size_t)NB*SENC*2 + 8;      /* + prefetch slack */
  float* av   = ws + off; off += (size_t)NB*AA*DD;
  /* gates [B*SENC][AA] f32 (8MB) aliases Kr+P16 (both written after avscan);
     gates prefetch slack spills into V16 region — also written after avscan */
  float* Kr   = ws + off; float* gates = Kr; off += (size_t)NB*AA*DD;
  unsigned int* P16 = (unsigned int*)(ws + off); off += (size_t)NB*AA*DD/2;
  unsigned int* V16 = (unsigned int*)(ws + off); off += (size_t)NB*AA*DD/2;
  float* Qa   = ws + off; off += (size_t)AA*DD;
  float* Menc = ws + off; off += (size_t)AA*DD;
  float* cenc = ws + off; off += AA;
  float* cdec = ws + off; off += (size_t)NB*AA;
  float* zfin = ws + off; off += (size_t)NB*DD;
  float2* lsp = (float2*)(ws + off); off += 512;
  int*  flag  = (int*)(ws + off); off += 1;

  qa_kernel     <<<AA, 512, 0, stream>>>(enc_key_W, enc_Wq, enc_bq, Qa);
  menc_kernel   <<<AA, 512, 0, stream>>>(Qa, enc_Wk, Menc);
  dotb_kernel   <<<AA/4, 256, 0, stream>>>(Qa, enc_bk, cenc);
  flag_kernel   <<<1, 512, 0, stream>>>(n1g, n1b, flag);
  xgather_kernel<<<NB*SENC/4, 256, 0, stream>>>(toks, emb_in, Z);
  zscan_kernel  <<<NB, 64, 0, stream>>>(Z, n1g, n1b, flag, ZSQ);
  gates_kernel  <<<NB*SENC/64, 256, 0, stream>>>(Z, Menc, cenc, gates);
  avscan_kernel <<<256, 512, 0, stream>>>(Z, ZSQ, gates, n1g, n1b, flag, av);
  gemm_nt_kernel<<<dim3(NB*AA/64, DD/64), 256, 0, stream>>>(av, rdr_Wk, rdr_bk, Kr, 0);
  gemm_nn_kernel<<<dim3(NB*AA/64, DD/64), 256, 0, stream>>>(Kr, rdr_Wq, P16);
  gemm_nt_kernel<<<dim3(NB*AA/64, DD/64), 256, 0, stream>>>(av, rdr_Wv, rdr_bv, V16, 1);
  dotb_kernel   <<<NB*AA/4, 256, 0, stream>>>(Kr, rdr_bq, cdec);
  dec_kernel    <<<NB, 256, 0, stream>>>(Z, P16, V16, cdec, n2g, n2b, zfin);
  logits_kernel <<<VOUT/128, 256, 0, stream>>>(zfin, vocW, vocb, outp);
  lsm1_kernel   <<<NB*8, 256, 0, stream>>>(outp, lsp);
  lsm2_kernel   <<<NB*8, 256, 0, stream>>>(outp, lsp);
}